// Round 4
// baseline (512.917 us; speedup 1.0000x reference)
//
#include <hip/hip_runtime.h>
#include <hip/hip_bf16.h>
#include <math.h>

#define NN   100000
#define EE   1600000
#define ETOT 1700000   // EE + NN self loops
#define MM   40
#define HID  128
#define LAT  64
#define NB   391       // ceil(NN/256) buckets of 256 nodes
#define CHUNK 4096     // edges per bin_pass block

typedef unsigned short u16;
typedef unsigned int   u32;
typedef unsigned long long u64;

typedef __attribute__((ext_vector_type(8))) short bf16x8;
typedef __attribute__((ext_vector_type(4))) float f32x4;
typedef __attribute__((ext_vector_type(2))) float f32x2;

__device__ __forceinline__ float bf2f(u16 a) {
    return __uint_as_float(((u32)a) << 16);
}
__device__ __forceinline__ u16 f2bf(float f) {
    u32 u = __float_as_uint(f);
    u32 r = (u + 0x7fffu + ((u >> 16) & 1u)) >> 16;
    return (u16)r;
}
__device__ __forceinline__ f32x2 unpk(u32 u) {
    f32x2 r;
    r.x = __uint_as_float(u << 16);
    r.y = __uint_as_float(u & 0xffff0000u);
    return r;
}
// tanh-form GELU via sigmoid: x * sigmoid(1.595769x + 0.0713548x^3); |err vs exact| <= ~3e-4
__device__ __forceinline__ float gelu_t(float x) {
    float x2 = x * x;
    float y = x * fmaf(0.0713548162726f, x2, 1.59576912161f);
    return x / (1.f + __expf(-y));
}

// f32 vector pack offsets (floats)
#define Vbp   0
#define Vatt1 128
#define Vb1   256
#define Vg1   384
#define Vbe1  512
#define Vatt2 640
#define Vb2   768
#define Vg2   896
#define Vbe2  1024
#define Vbo   1152
#define VTOT  1216

// bf16 transposed weight pack offsets (u16 elements)
#define BWp   0        // [128][64]  (K=40 zero-padded to 64)
#define BW1l  8192     // [128][128]
#define BW1r  24576    // adjacent to BW1l (gridDim.y=2 panel trick)
#define BW2l  40960
#define BW2r  57344
#define BWo   73728    // [64][128], padded to 128 rows (zeros)
#define BTOT  90112

// ---------------- dtype sniff ----------------
__global__ void sniff_kernel(const u32* __restrict__ ei_raw, const u32* __restrict__ x_raw,
                             int* __restrict__ flags) {
    if (threadIdx.x != 0 || blockIdx.x != 0) return;
    int allz = 1;
    for (int i = 1; i < 256; i += 2) allz &= (ei_raw[i] == 0u);
    flags[0] = allz;
    int bf_like = 0;
    for (int i = 0; i < 64; i++) {
        u16 lo = (u16)(x_raw[i] & 0xffffu);
        int e = (lo >> 7) & 0xFF;
        if (e >= 118 && e <= 133) bf_like++;
    }
    flags[1] = (bf_like >= 48) ? 1 : 0;
}

__device__ __forceinline__ void edge_decode(const int* __restrict__ ei, int is64, int e,
                                            int& src, int& dst) {
    if (e < EE) {
        src = is64 ? ei[2 * e] : ei[e];
        int idx = EE + e;
        dst = is64 ? ei[2 * idx] : ei[idx];
    } else {
        src = e - EE; dst = src;
    }
}

// ---------------- normalize x -> bf16 ----------------
__global__ void normx_kernel(const void* __restrict__ in, u16* __restrict__ out, int n,
                             const int* __restrict__ flags) {
    int i = blockIdx.x * 256 + threadIdx.x;
    if (i >= n) return;
    out[i] = flags[1] ? ((const u16*)in)[i] : f2bf(((const float*)in)[i]);
}

// ---------------- pack small vectors to f32 ----------------
__global__ void norm_vec_kernel(
    const void* p0, const void* p1, const void* p2, const void* p3, const void* p4,
    const void* p5, const void* p6, const void* p7, const void* p8, const void* p9,
    float* __restrict__ out, const int* __restrict__ flags)
{
    int i = blockIdx.x * 256 + threadIdx.x;
    if (i >= VTOT) return;
    const int offs[11] = {Vbp, Vatt1, Vb1, Vg1, Vbe1, Vatt2, Vb2, Vg2, Vbe2, Vbo, VTOT};
    const void* ps[10] = {p0,p1,p2,p3,p4,p5,p6,p7,p8,p9};
    int s = 0;
#pragma unroll
    for (int k = 1; k < 10; k++) s += (i >= offs[k]) ? 1 : 0;
    int j = i - offs[s];
    const void* p = ps[s];
    out[i] = flags[1] ? bf2f(((const u16*)p)[j]) : ((const float*)p)[j];
}

// ---------------- transpose weights to bf16 Wt[n][k] ----------------
__global__ void norm_wt_kernel(
    const void* w0, const void* w1, const void* w2, const void* w3, const void* w4,
    const void* w5, u16* __restrict__ out, const int* __restrict__ flags)
{
    int i = blockIdx.x * 256 + threadIdx.x;
    if (i >= BTOT) return;
    const int offs[7] = {BWp, BW1l, BW1r, BW2l, BW2r, BWo, BTOT};
    const int Ks[6]   = {40, 128, 128, 128, 128, 128};
    const int Ncs[6]  = {128, 128, 128, 128, 128, 64};
    const int Kps[6]  = {64, 128, 128, 128, 128, 128};
    const void* ps[6] = {w0,w1,w2,w3,w4,w5};
    int s = 0;
#pragma unroll
    for (int k = 1; k < 6; k++) s += (i >= offs[k]) ? 1 : 0;
    int j = i - offs[s];
    int Kp = Kps[s];
    int n = j / Kp, k = j % Kp;
    u16 v = 0;
    if (k < Ks[s] && n < Ncs[s]) {
        const void* p = ps[s];
        int src = k * Ncs[s] + n;
        v = flags[1] ? ((const u16*)p)[src] : f2bf(((const float*)p)[src]);
    }
    out[i] = v;
}

// ---------------- CSR build: 2-pass LDS-binned counting sort ----------------
__global__ __launch_bounds__(256) void bucket_hist_kernel(
    const int* __restrict__ ei, const int* __restrict__ flags, u32* __restrict__ gbucket)
{
    __shared__ u32 h[512];
    int t = threadIdx.x;
    h[t] = 0; h[t + 256] = 0;
    __syncthreads();
    int is64 = flags[0];
    int base = blockIdx.x * CHUNK;
#pragma unroll
    for (int j = 0; j < CHUNK / 256; j++) {
        int e = base + j * 256 + t;
        if (e < ETOT) {
            int src, dst;
            edge_decode(ei, is64, e, src, dst);
            atomicAdd(&h[dst >> 8], 1u);
        }
    }
    __syncthreads();
    if (h[t])       atomicAdd(&gbucket[t], h[t]);
    if (h[t + 256]) atomicAdd(&gbucket[t + 256], h[t + 256]);
}

__global__ __launch_bounds__(256) void bucket_scan_kernel(
    const u32* __restrict__ gbucket, u32* __restrict__ bbase, u32* __restrict__ bcursor)
{
    __shared__ u32 ts[256];
    int t = threadIdx.x;
    u32 s0 = (2 * t     < NB) ? gbucket[2 * t]     : 0;
    u32 s1 = (2 * t + 1 < NB) ? gbucket[2 * t + 1] : 0;
    u32 tsum = s0 + s1;
    ts[t] = tsum; __syncthreads();
    for (int d = 1; d < 256; d <<= 1) {
        u32 v = (t >= d) ? ts[t - d] : 0;
        __syncthreads();
        ts[t] += v;
        __syncthreads();
    }
    u32 excl = ts[t] - tsum;
    bbase[2 * t] = excl;          bcursor[2 * t] = excl;
    bbase[2 * t + 1] = excl + s0; bcursor[2 * t + 1] = excl + s0;
    if (2 * t == NB - 1 || 2 * t + 1 == NB - 1) bbase[NB] = ETOT;
}

__global__ __launch_bounds__(256) void bin_pass_kernel(
    const int* __restrict__ ei, const int* __restrict__ flags,
    u32* __restrict__ bcursor, u64* __restrict__ pairs)
{
    __shared__ u32 bh[512];
    __shared__ u32 boff[512];
    __shared__ u32 bbs[512];
    __shared__ u32 bcur[512];
    __shared__ u64 stage[CHUNK];
    __shared__ u32 ts[256];

    int t = threadIdx.x;
    bh[t] = 0; bh[t + 256] = 0;
    __syncthreads();
    int is64 = flags[0];
    int base = blockIdx.x * CHUNK;
    int chunk_n = ETOT - base; if (chunk_n > CHUNK) chunk_n = CHUNK;

#pragma unroll
    for (int j = 0; j < CHUNK / 256; j++) {
        int e = base + j * 256 + t;
        if (e < ETOT) {
            int src, dst;
            edge_decode(ei, is64, e, src, dst);
            atomicAdd(&bh[dst >> 8], 1u);
        }
    }
    __syncthreads();
    u32 s0 = bh[2 * t], s1 = bh[2 * t + 1];
    u32 tsum = s0 + s1;
    ts[t] = tsum; __syncthreads();
    for (int d = 1; d < 256; d <<= 1) {
        u32 v = (t >= d) ? ts[t - d] : 0;
        __syncthreads();
        ts[t] += v;
        __syncthreads();
    }
    u32 excl = ts[t] - tsum;
    boff[2 * t] = excl; boff[2 * t + 1] = excl + s0;
    bcur[2 * t] = excl; bcur[2 * t + 1] = excl + s0;
    __syncthreads();
    if (t < NB && bh[t]) bbs[t] = atomicAdd(&bcursor[t], bh[t]);
    if (t + 256 < NB && bh[t + 256]) bbs[t + 256] = atomicAdd(&bcursor[t + 256], bh[t + 256]);
    __syncthreads();
#pragma unroll
    for (int j = 0; j < CHUNK / 256; j++) {
        int e = base + j * 256 + t;
        if (e < ETOT) {
            int src, dst;
            edge_decode(ei, is64, e, src, dst);
            u32 pos = atomicAdd(&bcur[dst >> 8], 1u);
            stage[pos] = (u64)src | ((u64)dst << 32);
        }
    }
    __syncthreads();
    for (int i = t; i < chunk_n; i += 256) {
        u64 pr = stage[i];
        u32 b = (u32)(pr >> 32) >> 8;
        pairs[(size_t)bbs[b] + (i - boff[b])] = pr;
    }
}

// sort within bucket + write CSR offs + degree histogram (fused)
__global__ __launch_bounds__(256) void sort_pass_kernel(
    const u64* __restrict__ pairs, const u32* __restrict__ bbase,
    int* __restrict__ srcs, int* __restrict__ offs, u32* __restrict__ dcnt)
{
    __shared__ u32 nh[256];
    __shared__ u32 ns[256];
    __shared__ u32 ncur[256];
    __shared__ u32 dh[64];
    int t = threadIdx.x;
    int b = blockIdx.x;
    u32 beg = bbase[b], endp = bbase[b + 1];
    nh[t] = 0;
    if (t < 64) dh[t] = 0;
    __syncthreads();
    for (u32 i = beg + t; i < endp; i += 256) {
        u32 dst = (u32)(pairs[i] >> 32);
        atomicAdd(&nh[dst & 255], 1u);
    }
    __syncthreads();
    u32 cnt = nh[t];
    ns[t] = cnt; __syncthreads();
    for (int d = 1; d < 256; d <<= 1) {
        u32 v = (t >= d) ? ns[t - d] : 0;
        __syncthreads();
        ns[t] += v;
        __syncthreads();
    }
    u32 excl = ns[t] - cnt;
    int id = b * 256 + t;
    if (id <= NN) offs[id] = (int)(beg + excl);
    if (id < NN) atomicAdd(&dh[cnt < 63u ? cnt : 63u], 1u);
    ncur[t] = excl;
    __syncthreads();
    if (t < 64 && dh[t]) atomicAdd(&dcnt[t], dh[t]);
    for (u32 i = beg + t; i < endp; i += 256) {
        u64 pr = pairs[i];
        u32 loc = ((u32)(pr >> 32)) & 255;
        u32 p = atomicAdd(&ncur[loc], 1u);
        srcs[beg + p] = (int)(u32)pr;
    }
}

// ---------------- degree-balance permutation ----------------
// Heaviest degree first: waves see near-equal-degree dsts -> max(deg)~deg.
__global__ void deg_scan_kernel(const u32* __restrict__ dcnt, u32* __restrict__ dcur)
{
    int t = threadIdx.x;  // 64 threads, one wave
    u32 v = dcnt[t];
    u32 x = v;
    // inclusive suffix scan (descending-degree layout: bucket 63 starts at 0)
#pragma unroll
    for (int off = 1; off < 64; off <<= 1) {
        u32 y = __shfl_down(x, off);
        if (t + off < 64) x += y;
    }
    dcur[t] = x - v;   // exclusive suffix sum = base of bucket t
}

__global__ __launch_bounds__(256) void deg_scatter_kernel(
    const int* __restrict__ offs, u32* __restrict__ dcur, int* __restrict__ perm)
{
    __shared__ u32 cnt[64];
    __shared__ u32 base[64];
    int t = threadIdx.x;
    if (t < 64) cnt[t] = 0;
    __syncthreads();
    int i = blockIdx.x * 256 + t;
    int d = 0; u32 r = 0;
    bool ok = (i < NN);
    if (ok) {
        d = offs[i + 1] - offs[i];
        if (d > 63) d = 63;
        r = atomicAdd(&cnt[d], 1u);
    }
    __syncthreads();
    if (t < 64 && cnt[t]) base[t] = atomicAdd(&dcur[t], cnt[t]);
    __syncthreads();
    if (ok) perm[base[d] + r] = i;
}

// ---------------- MFMA GEMM ----------------
__global__ __launch_bounds__(256) void mfma_gemm(
    const u16* __restrict__ A, int lda,
    const u16* __restrict__ Bt, int ldb,
    const float* __restrict__ bias,
    int nrows, int ksteps, int ncols,
    float* __restrict__ outF, u16* __restrict__ outB, u16* __restrict__ outB2, int ldo,
    int mode, const int* __restrict__ flags)
{
    int lane = threadIdx.x & 63;
    int wv = threadIdx.x >> 6;
    int wx = wv & 1, wy = wv >> 1;
    int l16 = lane & 15, quad = lane >> 4;
    int r0 = blockIdx.x * 128 + wx * 64;
    int n0 = wy * 64;

    Bt += (size_t)blockIdx.y * 128 * ldb;
    if (blockIdx.y) outB = outB2;

    f32x4 acc[4][4];
#pragma unroll
    for (int m = 0; m < 4; m++)
#pragma unroll
        for (int n = 0; n < 4; n++) acc[m][n] = (f32x4){0.f, 0.f, 0.f, 0.f};

    const u16* Ap = A + (size_t)(r0 + l16) * lda + quad * 8;
    const u16* Bp = Bt + (size_t)(n0 + l16) * ldb + quad * 8;

    for (int k = 0; k < ksteps; ++k) {
        bf16x8 af[4], bfr[4];
#pragma unroll
        for (int m = 0; m < 4; m++)
            af[m] = *(const bf16x8*)(Ap + (size_t)m * 16 * lda + k * 32);
#pragma unroll
        for (int n = 0; n < 4; n++)
            bfr[n] = *(const bf16x8*)(Bp + (size_t)n * 16 * ldb + k * 32);
#pragma unroll
        for (int m = 0; m < 4; m++)
#pragma unroll
            for (int n = 0; n < 4; n++)
                acc[m][n] = __builtin_amdgcn_mfma_f32_16x16x32_bf16(af[m], bfr[n], acc[m][n], 0, 0, 0);
    }

    int mk = mode;
    if (mk < 0) mk = flags[1] ? 2 : 1;

#pragma unroll
    for (int m = 0; m < 4; m++) {
#pragma unroll
        for (int n = 0; n < 4; n++) {
            int col = n0 + n * 16 + l16;
            float bb = (bias != nullptr && col < ncols) ? bias[col] : 0.f;
#pragma unroll
            for (int reg = 0; reg < 4; reg++) {
                int row = r0 + m * 16 + quad * 4 + reg;
                if (row < nrows && col < ncols) {
                    float v = acc[m][n][reg] + bb;
                    if (mk & 1) outF[(size_t)row * ldo + col] = v;
                    if (mk & 2) outB[(size_t)row * ldo + col] = f2bf(v);
                }
            }
        }
    }
}

// ---------------- fused GATv2 agg + bias + GELU + residual + LayerNorm ----------------
// 2 dst per wave (sub = lane>>5), 32 lanes per dst, lane owns 4 ch (8B row slice).
// 4 edges in flight per dst (distance-1 over a 4-edge body = ~2x latency cover),
// VGPR kept < 64 (occupancy cliff). dsts via degree-sorted perm.
__global__ __launch_bounds__(256) void gat_agg_kernel(
    const u16* __restrict__ hl, const u16* __restrict__ hr, const u16* __restrict__ hresb,
    const float* __restrict__ att, const float* __restrict__ bias,
    const float* __restrict__ gamma, const float* __restrict__ beta,
    const int* __restrict__ offs, const int* __restrict__ srcs,
    const int* __restrict__ perm,
    u16* __restrict__ outb)
{
    int lane = threadIdx.x & 63;
    int sub = lane >> 5;                 // 2 dsts per wave
    int l = lane & 31;                   // 32 lanes per dst
    u32 co = (u32)(l * 4);               // this lane's 4 channels
    int id = (blockIdx.x * 4 + (threadIdx.x >> 6)) * 2 + sub;   // grid = NN/8 blocks
    int dst = perm[id];

    int start = offs[dst];
    int deg = offs[dst + 1] - start;     // >= 1 (self loop)
    int dm = deg - 1;
    const int* sp = srcs + start;

    f32x2 hr0, hr1, av0, av1;
    {
        uint2 q = *(const uint2*)(hr + (((u32)dst << 7) + co));
        hr0 = unpk(q.x); hr1 = unpk(q.y);
        float4 a = *(const float4*)&att[co];
        av0 = (f32x2){a.x, a.y}; av1 = (f32x2){a.z, a.w};
    }

    // wave-uniform bound = max deg over the 2 sub-groups (~deg after perm)
    int md = max(deg, __shfl_xor(deg, 32));

    f32x2 acc0 = (f32x2){0.f, 0.f};
    f32x2 acc1 = (f32x2){0.f, 0.f};
    float s = 0.f;

    // prologue: rows for edges 0..3; srcs for edges 4..7
    int S0 = sp[0];
    int S1 = sp[min(1, dm)];
    int S2 = sp[min(2, dm)];
    int S3 = sp[min(3, dm)];
    uint2 R0 = *(const uint2*)(hl + (((u32)S0 << 7) + co));
    uint2 R1 = *(const uint2*)(hl + (((u32)S1 << 7) + co));
    uint2 R2 = *(const uint2*)(hl + (((u32)S2 << 7) + co));
    uint2 R3 = *(const uint2*)(hl + (((u32)S3 << 7) + co));
    S0 = sp[min(4, dm)];
    S1 = sp[min(5, dm)];
    S2 = sp[min(6, dm)];
    S3 = sp[min(7, dm)];

    for (int e0 = 0; e0 < md; e0 += 4) {
        // srcs for edges e0+8..e0+11 (used as rows two iterations ahead)
        int T0 = sp[min(e0 + 8, dm)];
        int T1 = sp[min(e0 + 9, dm)];
        int T2 = sp[min(e0 + 10, dm)];
        int T3 = sp[min(e0 + 11, dm)];
        // rows for edges e0+4..e0+7 (in flight across this body)
        uint2 P0 = *(const uint2*)(hl + (((u32)S0 << 7) + co));
        uint2 P1 = *(const uint2*)(hl + (((u32)S1 << 7) + co));
        uint2 P2 = *(const uint2*)(hl + (((u32)S2 << 7) + co));
        uint2 P3 = *(const uint2*)(hl + (((u32)S3 << 7) + co));

        // body: edges e0..e0+3 in two ILP pairs
#define EDGE_PAIR(Ra, Rb, ea, eb)                                              \
        {                                                                      \
            f32x2 ha0 = unpk(Ra.x), ha1 = unpk(Ra.y);                          \
            f32x2 hb0 = unpk(Rb.x), hb1 = unpk(Rb.y);                          \
            f32x2 za0 = ha0 + hr0, za1 = ha1 + hr1;                            \
            f32x2 zb0 = hb0 + hr0, zb1 = hb1 + hr1;                            \
            f32x2 la0 = __builtin_elementwise_max(za0, za0 * 0.2f);            \
            f32x2 la1 = __builtin_elementwise_max(za1, za1 * 0.2f);            \
            f32x2 lb0 = __builtin_elementwise_max(zb0, zb0 * 0.2f);            \
            f32x2 lb1 = __builtin_elementwise_max(zb1, zb1 * 0.2f);            \
            f32x2 pa = __builtin_elementwise_fma(av0, la0,                     \
                       __builtin_elementwise_fma(av1, la1, (f32x2){0.f,0.f})); \
            f32x2 pb = __builtin_elementwise_fma(av0, lb0,                     \
                       __builtin_elementwise_fma(av1, lb1, (f32x2){0.f,0.f})); \
            float pea = pa.x + pa.y;                                           \
            float peb = pb.x + pb.y;                                           \
            pea += __shfl_xor(pea, 1); peb += __shfl_xor(peb, 1);              \
            pea += __shfl_xor(pea, 2); peb += __shfl_xor(peb, 2);              \
            pea += __shfl_xor(pea, 4); peb += __shfl_xor(peb, 4);              \
            float wa = ((ea) < deg) ? __expf(pea) : 0.f;                       \
            float wb = ((eb) < deg) ? __expf(peb) : 0.f;                       \
            s += wa + wb;                                                      \
            f32x2 wa2 = (f32x2){wa, wa};                                       \
            f32x2 wb2 = (f32x2){wb, wb};                                       \
            acc0 = __builtin_elementwise_fma(wa2, ha0,                         \
                   __builtin_elementwise_fma(wb2, hb0, acc0));                 \
            acc1 = __builtin_elementwise_fma(wa2, ha1,                         \
                   __builtin_elementwise_fma(wb2, hb1, acc1));                 \
        }

        EDGE_PAIR(R0, R1, e0, e0 + 1)
        EDGE_PAIR(R2, R3, e0 + 2, e0 + 3)
#undef EDGE_PAIR

        R0 = P0; R1 = P1; R2 = P2; R3 = P3;
        S0 = T0; S1 = T1; S2 = T2; S3 = T3;
    }

    float inv = 1.f / s;
    float v0, v1, v2, v3;
    {
        float4 bb = *(const float4*)&bias[co];
        uint2 qr = *(const uint2*)(hresb + (((u32)dst << 7) + co));
        f32x2 rr0 = unpk(qr.x), rr1 = unpk(qr.y);
        v0 = gelu_t(fmaf(acc0.x, inv, bb.x)) + rr0.x;
        v1 = gelu_t(fmaf(acc0.y, inv, bb.y)) + rr0.y;
        v2 = gelu_t(fmaf(acc1.x, inv, bb.z)) + rr1.x;
        v3 = gelu_t(fmaf(acc1.y, inv, bb.w)) + rr1.y;
    }

    // LayerNorm over 128 ch = 32 lanes of this sub-group (offsets 1..16 stay in-group)
    float s1 = v0 + v1 + v2 + v3;
    float s2 = fmaf(v0, v0, fmaf(v1, v1, fmaf(v2, v2, v3 * v3)));
#pragma unroll
    for (int off = 1; off < 32; off <<= 1) {
        s1 += __shfl_xor(s1, off);
        s2 += __shfl_xor(s2, off);
    }
    float mu  = s1 * (1.f / 128.f);
    float var = s2 * (1.f / 128.f) - mu * mu;
    float rstd = rsqrtf(var + 1e-5f);

    float4 gg = *(const float4*)&gamma[co];
    float4 eb = *(const float4*)&beta[co];
    float o0 = fmaf((v0 - mu) * rstd, gg.x, eb.x);
    float o1 = fmaf((v1 - mu) * rstd, gg.y, eb.y);
    float o2 = fmaf((v2 - mu) * rstd, gg.z, eb.z);
    float o3 = fmaf((v3 - mu) * rstd, gg.w, eb.w);
    uint2 pk;
    pk.x = (u32)f2bf(o0) | ((u32)f2bf(o1) << 16);
    pk.y = (u32)f2bf(o2) | ((u32)f2bf(o3) << 16);
    *(uint2*)(outb + (((u32)dst << 7) + co)) = pk;
}

// ---------------- launch ----------------
extern "C" void kernel_launch(void* const* d_in, const int* in_sizes, int n_in,
                              void* d_out, int out_size, void* d_ws, size_t ws_size,
                              hipStream_t stream) {
    const void* x  = d_in[0];
    const int*  ei = (const int*)d_in[1];

    char* ws = (char*)d_ws;
    size_t off = 0;
    auto alloc = [&](size_t bytes) -> void* {
        void* p = ws + off;
        off = (off + bytes + 511) & ~(size_t)511;
        return p;
    };
    u16*   xb      = (u16*)  alloc(((size_t)NN * MM + 8192) * 2);
    float* wv      = (float*)alloc((size_t)VTOT * 4);
    u16*   wbf     = (u16*)  alloc((size_t)BTOT * 2);
    u16*   h0b     = (u16*)  alloc((size_t)(NN + 64) * HID * 2);
    u16*   h1b     = (u16*)  alloc((size_t)(NN + 64) * HID * 2);
    u16*   hlb     = (u16*)  alloc((size_t)NN * HID * 2);
    u16*   hrb     = (u16*)  alloc((size_t)NN * HID * 2);
    int*   offs    = (int*)  alloc((size_t)(NN + 1) * 4);
    u32*   gbucket = (u32*)  alloc(512 * 4);
    u32*   bbase   = (u32*)  alloc(520 * 4);
    u32*   bcursor = (u32*)  alloc(520 * 4);
    int*   flags   = (int*)  alloc(512);
    int*   srcs    = (int*)  alloc(((size_t)ETOT + 64) * 4);
    u64*   pairs   = (u64*)  alloc((size_t)ETOT * 8);
    u32*   dcnt    = (u32*)  alloc(64 * 4);
    u32*   dcur    = (u32*)  alloc(64 * 4);
    int*   perm    = (int*)  alloc((size_t)NN * 4);

    hipMemsetAsync(gbucket, 0, 512 * 4, stream);
    hipMemsetAsync(dcnt, 0, 64 * 4, stream);

    sniff_kernel<<<1, 64, 0, stream>>>((const u32*)ei, (const u32*)x, flags);

    normx_kernel<<<(NN * MM + 255) / 256, 256, 0, stream>>>(x, xb, NN * MM, flags);
    norm_vec_kernel<<<(VTOT + 255) / 256, 256, 0, stream>>>(
        d_in[3], d_in[6], d_in[7], d_in[12], d_in[13], d_in[10], d_in[11], d_in[14], d_in[15], d_in[17],
        wv, flags);
    norm_wt_kernel<<<(BTOT + 255) / 256, 256, 0, stream>>>(
        d_in[2], d_in[4], d_in[5], d_in[8], d_in[9], d_in[16], wbf, flags);

    const int EB = (ETOT + CHUNK - 1) / CHUNK;  // 416
    bucket_hist_kernel<<<EB, 256, 0, stream>>>(ei, flags, gbucket);
    bucket_scan_kernel<<<1, 256, 0, stream>>>(gbucket, bbase, bcursor);
    bin_pass_kernel<<<EB, 256, 0, stream>>>(ei, flags, bcursor, pairs);
    sort_pass_kernel<<<NB, 256, 0, stream>>>(pairs, bbase, srcs, offs, dcnt);

    // degree-balance permutation (heaviest degree first)
    deg_scan_kernel<<<1, 64, 0, stream>>>(dcnt, dcur);
    deg_scatter_kernel<<<NB, 256, 0, stream>>>(offs, dcur, perm);

    const int GB = (NN + 127) / 128;  // 782
    const int AB = NN / 8;            // 12500 blocks, 2 dst/wave x 4 waves

    // proj: h0b = bf16(x @ Wp + bp)   (K=40 padded to 64)
    mfma_gemm<<<dim3(GB, 1), 256, 0, stream>>>(xb, MM, wbf + BWp, 64, wv + Vbp,
                                               NN, 2, HID, nullptr, h0b, nullptr, HID, 2, flags);

    // layer 1: hl/hr in one dispatch
    mfma_gemm<<<dim3(GB, 2), 256, 0, stream>>>(h0b, HID, wbf + BW1l, HID, nullptr,
                                               NN, 4, HID, nullptr, hlb, hrb, HID, 2, flags);
    gat_agg_kernel<<<AB, 256, 0, stream>>>(hlb, hrb, h0b, wv + Vatt1, wv + Vb1,
                                           wv + Vg1, wv + Vbe1, offs, srcs, perm, h1b);

    // layer 2
    mfma_gemm<<<dim3(GB, 2), 256, 0, stream>>>(h1b, HID, wbf + BW2l, HID, nullptr,
                                               NN, 4, HID, nullptr, hlb, hrb, HID, 2, flags);
    gat_agg_kernel<<<AB, 256, 0, stream>>>(hlb, hrb, h1b, wv + Vatt2, wv + Vb2,
                                           wv + Vg2, wv + Vbe2, offs, srcs, perm, h0b);

    // final: out = h @ Wo + bo (dtype per flags)
    mfma_gemm<<<dim3(GB, 1), 256, 0, stream>>>(h0b, HID, wbf + BWo, HID, wv + Vbo,
                                               NN, 4, LAT, (float*)d_out, (u16*)d_out, nullptr, LAT, -1, flags);
}

// Round 5
// 478.865 us; speedup vs baseline: 1.0711x; 1.0711x over previous
//
#include <hip/hip_runtime.h>
#include <hip/hip_bf16.h>
#include <math.h>

#define NN   100000
#define EE   1600000
#define ETOT 1700000   // EE + NN self loops
#define MM   40
#define HID  128
#define LAT  64
#define NB   391       // ceil(NN/256) buckets of 256 nodes
#define CHUNK 4096     // edges per bin_pass block

typedef unsigned short u16;
typedef unsigned int   u32;
typedef unsigned long long u64;

typedef __attribute__((ext_vector_type(8))) short bf16x8;
typedef __attribute__((ext_vector_type(4))) float f32x4;
typedef __attribute__((ext_vector_type(2))) float f32x2;

__device__ __forceinline__ float bf2f(u16 a) {
    return __uint_as_float(((u32)a) << 16);
}
__device__ __forceinline__ u16 f2bf(float f) {
    u32 u = __float_as_uint(f);
    u32 r = (u + 0x7fffu + ((u >> 16) & 1u)) >> 16;
    return (u16)r;
}
__device__ __forceinline__ f32x2 unpk(u32 u) {
    f32x2 r;
    r.x = __uint_as_float(u << 16);
    r.y = __uint_as_float(u & 0xffff0000u);
    return r;
}
// bare v_exp_f32: D = 2^S0 (input pre-scaled by log2(e) where e^x is wanted)
__device__ __forceinline__ float exp2_hw(float x) {
    float d;
    asm("v_exp_f32 %0, %1" : "=v"(d) : "v"(x));
    return d;
}
// tanh-form GELU via sigmoid: x * sigmoid(1.595769x + 0.0713548x^3); |err vs exact| <= ~3e-4
__device__ __forceinline__ float gelu_t(float x) {
    float x2 = x * x;
    float y = x * fmaf(0.0713548162726f, x2, 1.59576912161f);
    return x / (1.f + __expf(-y));
}

// f32 vector pack offsets (floats)
#define Vbp   0
#define Vatt1 128
#define Vb1   256
#define Vg1   384
#define Vbe1  512
#define Vatt2 640
#define Vb2   768
#define Vg2   896
#define Vbe2  1024
#define Vbo   1152
#define VTOT  1216

// bf16 transposed weight pack offsets (u16 elements)
#define BWp   0        // [128][64]  (K=40 zero-padded to 64)
#define BW1l  8192     // [128][128]
#define BW1r  24576    // adjacent to BW1l (gridDim.y=2 panel trick)
#define BW2l  40960
#define BW2r  57344
#define BWo   73728    // [64][128], padded to 128 rows (zeros)
#define BTOT  90112

// prep_kernel block-range sizes
#define NXB   15625    // (NN*MM)/256 exactly
#define NVB   5        // ceil(VTOT/256)
#define NWB   352      // BTOT/256 exactly

// per-wave bf16-ness sniff (identical predicate to original sniff_kernel)
__device__ __forceinline__ int sniff_bf_wave(const u32* __restrict__ x_raw) {
    int lane = threadIdx.x & 63;
    u32 w = x_raw[lane];              // first 64 u32 of x
    u16 lo = (u16)(w & 0xffffu);
    int e = (lo >> 7) & 0xFF;
    int ok = (e >= 118 && e <= 133) ? 1 : 0;
    u64 b = __ballot(ok);
    return (__popcll(b) >= 48) ? 1 : 0;
}

__device__ __forceinline__ void edge_decode(const int* __restrict__ ei, int is64, int e,
                                            int& src, int& dst) {
    if (e < EE) {
        src = is64 ? ei[2 * e] : ei[e];
        int idx = EE + e;
        dst = is64 ? ei[2 * idx] : ei[idx];
    } else {
        src = e - EE; dst = src;
    }
}

// ---------------- fused prep: sniff + zero + normx + norm_vec + norm_wt ----------------
__global__ __launch_bounds__(256) void prep_kernel(
    const void* __restrict__ x, const u32* __restrict__ ei_raw,
    const void* p0, const void* p1, const void* p2, const void* p3, const void* p4,
    const void* p5, const void* p6, const void* p7, const void* p8, const void* p9,
    const void* w0, const void* w1, const void* w2, const void* w3, const void* w4,
    const void* w5,
    u16* __restrict__ xb, float* __restrict__ wv, u16* __restrict__ wbf,
    int* __restrict__ flags, u32* __restrict__ gbucket, u32* __restrict__ dcnt)
{
    const u32* x_raw = (const u32*)x;
    int isbf = sniff_bf_wave(x_raw);
    int t = threadIdx.x;
    int b = blockIdx.x;

    if (b == 0) {
        // is64 sniff: all odd u32 in [1,255] zero -> int64 edge index
        if (t < 64) {
            u32 a = ei_raw[2 * t + 1] | ei_raw[129 + 2 * t];
            u64 nz = __ballot(a != 0u);
            if (t == 0) { flags[0] = (nz == 0uLL) ? 1 : 0; flags[1] = isbf; }
        }
        gbucket[t] = 0; gbucket[t + 256] = 0;
        if (t < 64) dcnt[t] = 0;
        return;
    }
    if (b <= NXB) {
        // normx: x -> bf16
        int i = (b - 1) * 256 + t;   // grid sized exactly: i < NN*MM
        xb[i] = isbf ? ((const u16*)x)[i] : f2bf(((const float*)x)[i]);
        return;
    }
    if (b <= NXB + NVB) {
        int i = (b - 1 - NXB) * 256 + t;
        if (i >= VTOT) return;
        const int offs[11] = {Vbp, Vatt1, Vb1, Vg1, Vbe1, Vatt2, Vb2, Vg2, Vbe2, Vbo, VTOT};
        const void* ps[10] = {p0,p1,p2,p3,p4,p5,p6,p7,p8,p9};
        int s = 0;
#pragma unroll
        for (int k = 1; k < 10; k++) s += (i >= offs[k]) ? 1 : 0;
        int j = i - offs[s];
        const void* p = ps[s];
        wv[i] = isbf ? bf2f(((const u16*)p)[j]) : ((const float*)p)[j];
        return;
    }
    {
        int i = (b - 1 - NXB - NVB) * 256 + t;   // grid sized exactly: i < BTOT
        const int offs[7] = {BWp, BW1l, BW1r, BW2l, BW2r, BWo, BTOT};
        const int Ks[6]   = {40, 128, 128, 128, 128, 128};
        const int Ncs[6]  = {128, 128, 128, 128, 128, 64};
        const int Kps[6]  = {64, 128, 128, 128, 128, 128};
        const void* ps[6] = {w0,w1,w2,w3,w4,w5};
        int s = 0;
#pragma unroll
        for (int k = 1; k < 6; k++) s += (i >= offs[k]) ? 1 : 0;
        int j = i - offs[s];
        int Kp = Kps[s];
        int n = j / Kp, k = j % Kp;
        u16 v = 0;
        if (k < Ks[s] && n < Ncs[s]) {
            const void* p = ps[s];
            int src = k * Ncs[s] + n;
            v = isbf ? ((const u16*)p)[src] : f2bf(((const float*)p)[src]);
        }
        wbf[i] = v;
    }
}

// ---------------- CSR build: 2-pass LDS-binned counting sort ----------------
__global__ __launch_bounds__(256) void bucket_hist_kernel(
    const int* __restrict__ ei, const int* __restrict__ flags, u32* __restrict__ gbucket)
{
    __shared__ u32 h[512];
    int t = threadIdx.x;
    h[t] = 0; h[t + 256] = 0;
    __syncthreads();
    int is64 = flags[0];
    int base = blockIdx.x * CHUNK;
#pragma unroll
    for (int j = 0; j < CHUNK / 256; j++) {
        int e = base + j * 256 + t;
        if (e < ETOT) {
            int src, dst;
            edge_decode(ei, is64, e, src, dst);
            atomicAdd(&h[dst >> 8], 1u);
        }
    }
    __syncthreads();
    if (h[t])       atomicAdd(&gbucket[t], h[t]);
    if (h[t + 256]) atomicAdd(&gbucket[t + 256], h[t + 256]);
}

__global__ __launch_bounds__(256) void bucket_scan_kernel(
    const u32* __restrict__ gbucket, u32* __restrict__ bbase, u32* __restrict__ bcursor)
{
    __shared__ u32 ts[256];
    int t = threadIdx.x;
    u32 s0 = (2 * t     < NB) ? gbucket[2 * t]     : 0;
    u32 s1 = (2 * t + 1 < NB) ? gbucket[2 * t + 1] : 0;
    u32 tsum = s0 + s1;
    ts[t] = tsum; __syncthreads();
    for (int d = 1; d < 256; d <<= 1) {
        u32 v = (t >= d) ? ts[t - d] : 0;
        __syncthreads();
        ts[t] += v;
        __syncthreads();
    }
    u32 excl = ts[t] - tsum;
    bbase[2 * t] = excl;          bcursor[2 * t] = excl;
    bbase[2 * t + 1] = excl + s0; bcursor[2 * t + 1] = excl + s0;
    if (2 * t == NB - 1 || 2 * t + 1 == NB - 1) bbase[NB] = ETOT;
}

__global__ __launch_bounds__(256) void bin_pass_kernel(
    const int* __restrict__ ei, const int* __restrict__ flags,
    u32* __restrict__ bcursor, u64* __restrict__ pairs)
{
    __shared__ u32 bh[512];
    __shared__ u32 boff[512];
    __shared__ u32 bbs[512];
    __shared__ u32 bcur[512];
    __shared__ u64 stage[CHUNK];
    __shared__ u32 ts[256];

    int t = threadIdx.x;
    bh[t] = 0; bh[t + 256] = 0;
    __syncthreads();
    int is64 = flags[0];
    int base = blockIdx.x * CHUNK;
    int chunk_n = ETOT - base; if (chunk_n > CHUNK) chunk_n = CHUNK;

#pragma unroll
    for (int j = 0; j < CHUNK / 256; j++) {
        int e = base + j * 256 + t;
        if (e < ETOT) {
            int src, dst;
            edge_decode(ei, is64, e, src, dst);
            atomicAdd(&bh[dst >> 8], 1u);
        }
    }
    __syncthreads();
    u32 s0 = bh[2 * t], s1 = bh[2 * t + 1];
    u32 tsum = s0 + s1;
    ts[t] = tsum; __syncthreads();
    for (int d = 1; d < 256; d <<= 1) {
        u32 v = (t >= d) ? ts[t - d] : 0;
        __syncthreads();
        ts[t] += v;
        __syncthreads();
    }
    u32 excl = ts[t] - tsum;
    boff[2 * t] = excl; boff[2 * t + 1] = excl + s0;
    bcur[2 * t] = excl; bcur[2 * t + 1] = excl + s0;
    __syncthreads();
    if (t < NB && bh[t]) bbs[t] = atomicAdd(&bcursor[t], bh[t]);
    if (t + 256 < NB && bh[t + 256]) bbs[t + 256] = atomicAdd(&bcursor[t + 256], bh[t + 256]);
    __syncthreads();
#pragma unroll
    for (int j = 0; j < CHUNK / 256; j++) {
        int e = base + j * 256 + t;
        if (e < ETOT) {
            int src, dst;
            edge_decode(ei, is64, e, src, dst);
            u32 pos = atomicAdd(&bcur[dst >> 8], 1u);
            stage[pos] = (u64)src | ((u64)dst << 32);
        }
    }
    __syncthreads();
    for (int i = t; i < chunk_n; i += 256) {
        u64 pr = stage[i];
        u32 b = (u32)(pr >> 32) >> 8;
        pairs[(size_t)bbs[b] + (i - boff[b])] = pr;
    }
}

// sort within bucket + write CSR offs + degree histogram (fused)
__global__ __launch_bounds__(256) void sort_pass_kernel(
    const u64* __restrict__ pairs, const u32* __restrict__ bbase,
    int* __restrict__ srcs, int* __restrict__ offs, u32* __restrict__ dcnt)
{
    __shared__ u32 nh[256];
    __shared__ u32 ns[256];
    __shared__ u32 ncur[256];
    __shared__ u32 dh[64];
    int t = threadIdx.x;
    int b = blockIdx.x;
    u32 beg = bbase[b], endp = bbase[b + 1];
    nh[t] = 0;
    if (t < 64) dh[t] = 0;
    __syncthreads();
    for (u32 i = beg + t; i < endp; i += 256) {
        u32 dst = (u32)(pairs[i] >> 32);
        atomicAdd(&nh[dst & 255], 1u);
    }
    __syncthreads();
    u32 cnt = nh[t];
    ns[t] = cnt; __syncthreads();
    for (int d = 1; d < 256; d <<= 1) {
        u32 v = (t >= d) ? ns[t - d] : 0;
        __syncthreads();
        ns[t] += v;
        __syncthreads();
    }
    u32 excl = ns[t] - cnt;
    int id = b * 256 + t;
    if (id <= NN) offs[id] = (int)(beg + excl);
    if (id < NN) atomicAdd(&dh[cnt < 63u ? cnt : 63u], 1u);
    ncur[t] = excl;
    __syncthreads();
    if (t < 64 && dh[t]) atomicAdd(&dcnt[t], dh[t]);
    for (u32 i = beg + t; i < endp; i += 256) {
        u64 pr = pairs[i];
        u32 loc = ((u32)(pr >> 32)) & 255;
        u32 p = atomicAdd(&ncur[loc], 1u);
        srcs[beg + p] = (int)(u32)pr;
    }
}

// ---------------- degree-balance permutation ----------------
// Heaviest degree first: waves see 4 near-equal-degree dsts -> max(deg)~deg.
__global__ void deg_scan_kernel(const u32* __restrict__ dcnt, u32* __restrict__ dcur)
{
    int t = threadIdx.x;  // 64 threads, one wave
    u32 v = dcnt[t];
    u32 x = v;
    // inclusive suffix scan (descending-degree layout: bucket 63 starts at 0)
#pragma unroll
    for (int off = 1; off < 64; off <<= 1) {
        u32 y = __shfl_down(x, off);
        if (t + off < 64) x += y;
    }
    dcur[t] = x - v;   // exclusive suffix sum = base of bucket t
}

__global__ __launch_bounds__(256) void deg_scatter_kernel(
    const int* __restrict__ offs, u32* __restrict__ dcur, int* __restrict__ perm)
{
    __shared__ u32 cnt[64];
    __shared__ u32 base[64];
    int t = threadIdx.x;
    if (t < 64) cnt[t] = 0;
    __syncthreads();
    int i = blockIdx.x * 256 + t;
    int d = 0; u32 r = 0;
    bool ok = (i < NN);
    if (ok) {
        d = offs[i + 1] - offs[i];
        if (d > 63) d = 63;
        r = atomicAdd(&cnt[d], 1u);
    }
    __syncthreads();
    if (t < 64 && cnt[t]) base[t] = atomicAdd(&dcur[t], cnt[t]);
    __syncthreads();
    if (ok) perm[base[d] + r] = i;
}

// ---------------- MFMA GEMM ----------------
__global__ __launch_bounds__(256) void mfma_gemm(
    const u16* __restrict__ A, int lda,
    const u16* __restrict__ Bt, int ldb,
    const float* __restrict__ bias,
    int nrows, int ksteps, int ncols,
    float* __restrict__ outF, u16* __restrict__ outB, u16* __restrict__ outB2, int ldo,
    int mode, const int* __restrict__ flags)
{
    int lane = threadIdx.x & 63;
    int wv = threadIdx.x >> 6;
    int wx = wv & 1, wy = wv >> 1;
    int l16 = lane & 15, quad = lane >> 4;
    int r0 = blockIdx.x * 128 + wx * 64;
    int n0 = wy * 64;

    Bt += (size_t)blockIdx.y * 128 * ldb;
    if (blockIdx.y) outB = outB2;

    f32x4 acc[4][4];
#pragma unroll
    for (int m = 0; m < 4; m++)
#pragma unroll
        for (int n = 0; n < 4; n++) acc[m][n] = (f32x4){0.f, 0.f, 0.f, 0.f};

    const u16* Ap = A + (size_t)(r0 + l16) * lda + quad * 8;
    const u16* Bp = Bt + (size_t)(n0 + l16) * ldb + quad * 8;

    for (int k = 0; k < ksteps; ++k) {
        bf16x8 af[4], bfr[4];
#pragma unroll
        for (int m = 0; m < 4; m++)
            af[m] = *(const bf16x8*)(Ap + (size_t)m * 16 * lda + k * 32);
#pragma unroll
        for (int n = 0; n < 4; n++)
            bfr[n] = *(const bf16x8*)(Bp + (size_t)n * 16 * ldb + k * 32);
#pragma unroll
        for (int m = 0; m < 4; m++)
#pragma unroll
            for (int n = 0; n < 4; n++)
                acc[m][n] = __builtin_amdgcn_mfma_f32_16x16x32_bf16(af[m], bfr[n], acc[m][n], 0, 0, 0);
    }

    int mk = mode;
    if (mk < 0) mk = flags[1] ? 2 : 1;

#pragma unroll
    for (int m = 0; m < 4; m++) {
#pragma unroll
        for (int n = 0; n < 4; n++) {
            int col = n0 + n * 16 + l16;
            float bb = (bias != nullptr && col < ncols) ? bias[col] : 0.f;
#pragma unroll
            for (int reg = 0; reg < 4; reg++) {
                int row = r0 + m * 16 + quad * 4 + reg;
                if (row < nrows && col < ncols) {
                    float v = acc[m][n][reg] + bb;
                    if (mk & 1) outF[(size_t)row * ldo + col] = v;
                    if (mk & 2) outB[(size_t)row * ldo + col] = f2bf(v);
                }
            }
        }
    }
}

// ---------------- fused GATv2 agg + bias + GELU + residual + LayerNorm ----------------
// 4 dst per wave (sub = lane>>4), lane r = lane&15 owns ch r*8..r*8+7.
// dsts via degree-sorted perm (wave's 4 dsts near-equal degree -> max(deg)~deg).
// Distance-1 prefetch (proven 44-VGPR body). Micro: att pre-scaled by log2(e) so
// exp is a bare v_exp_f32; hl gathers via u32 byte offsets (saddr+voffset form).
__global__ __launch_bounds__(256) void gat_agg_kernel(
    const u16* __restrict__ hl, const u16* __restrict__ hr, const u16* __restrict__ hresb,
    const float* __restrict__ att, const float* __restrict__ bias,
    const float* __restrict__ gamma, const float* __restrict__ beta,
    const int* __restrict__ offs, const int* __restrict__ srcs,
    const int* __restrict__ perm,
    u16* __restrict__ outb)
{
    int lane = threadIdx.x & 63;
    int sub = lane >> 4;
    int r = lane & 15;
    int c0 = r * 8;
    u32 cb = (u32)(r << 4);              // byte offset of this lane's 8 ch (16 B)
    int id = (blockIdx.x * 4 + (threadIdx.x >> 6)) * 4 + sub;   // grid = NN/16 blocks
    int dst = perm[id];

    int start = offs[dst];
    int deg = offs[dst + 1] - start;    // >= 1 (self loop)
    int dm = deg - 1;
    const char* hlc = (const char*)hl;

    f32x2 hr2[4], av2[4];
    {
        uint4 q = *(const uint4*)((const char*)hr + ((u32)dst << 8) + cb);
        hr2[0] = unpk(q.x); hr2[1] = unpk(q.y); hr2[2] = unpk(q.z); hr2[3] = unpk(q.w);
        const float L2E = 1.4426950408889634f;   // logits scaled so exp(x) = exp2(x*L2E)
        float4 a0 = *(const float4*)&att[c0];
        float4 a1 = *(const float4*)&att[c0 + 4];
        av2[0] = (f32x2){L2E * a0.x, L2E * a0.y}; av2[1] = (f32x2){L2E * a0.z, L2E * a0.w};
        av2[2] = (f32x2){L2E * a1.x, L2E * a1.y}; av2[3] = (f32x2){L2E * a1.z, L2E * a1.w};
    }

    // wave-uniform iteration bound = max deg over the 4 sub-groups (~deg after perm)
    int md = deg;
    md = max(md, __shfl_xor(md, 16));
    md = max(md, __shfl_xor(md, 32));

    f32x2 acc2[4];
#pragma unroll
    for (int i = 0; i < 4; i++) acc2[i] = (f32x2){0.f, 0.f};
    float s = 0.f;

    // prefetch: edges 0,1 rows; srcs for edges 2,3
    int sa = srcs[start];
    int sb = srcs[start + (1 < dm ? 1 : dm)];
    uint4 qa = *(const uint4*)(hlc + ((u32)sa << 8) + cb);
    uint4 qb = *(const uint4*)(hlc + ((u32)sb << 8) + cb);
    int sna = srcs[start + (2 < dm ? 2 : dm)];
    int snb = srcs[start + (3 < dm ? 3 : dm)];

    int mi = (md + 1) >> 1;
    for (int j = 0; j < mi; ++j) {
        // srcs for iteration j+2 (edges 2j+4, 2j+5)
        int e4 = 2 * j + 4, e5 = 2 * j + 5;
        int sna2 = srcs[start + min(e4, dm)];
        int snb2 = srcs[start + min(e5, dm)];
        // rows for iteration j+1
        uint4 qna = *(const uint4*)(hlc + ((u32)sna << 8) + cb);
        uint4 qnb = *(const uint4*)(hlc + ((u32)snb << 8) + cb);

        f32x2 ha[4], hb[4];
        ha[0] = unpk(qa.x); ha[1] = unpk(qa.y); ha[2] = unpk(qa.z); ha[3] = unpk(qa.w);
        hb[0] = unpk(qb.x); hb[1] = unpk(qb.y); hb[2] = unpk(qb.z); hb[3] = unpk(qb.w);
        f32x2 pa2 = (f32x2){0.f, 0.f};
        f32x2 pb2 = (f32x2){0.f, 0.f};
#pragma unroll
        for (int i = 0; i < 4; i++) {
            f32x2 za = ha[i] + hr2[i];
            f32x2 zb = hb[i] + hr2[i];
            f32x2 la = __builtin_elementwise_max(za, za * 0.2f);
            f32x2 lb = __builtin_elementwise_max(zb, zb * 0.2f);
            pa2 = __builtin_elementwise_fma(av2[i], la, pa2);
            pb2 = __builtin_elementwise_fma(av2[i], lb, pb2);
        }
        float pa = pa2.x + pa2.y;
        float pb = pb2.x + pb2.y;
        pa += __shfl_xor(pa, 1); pb += __shfl_xor(pb, 1);
        pa += __shfl_xor(pa, 2); pb += __shfl_xor(pb, 2);
        int e0 = 2 * j, e1 = 2 * j + 1;
        float wa = (e0 < deg) ? exp2_hw(pa) : 0.f;
        float wb = (e1 < deg) ? exp2_hw(pb) : 0.f;
        s += wa + wb;
        f32x2 wa2 = (f32x2){wa, wa};
        f32x2 wb2 = (f32x2){wb, wb};
#pragma unroll
        for (int i = 0; i < 4; i++)
            acc2[i] = __builtin_elementwise_fma(wa2, ha[i],
                      __builtin_elementwise_fma(wb2, hb[i], acc2[i]));

        qa = qna; qb = qnb; sna = sna2; snb = snb2;
    }

    float inv = 1.f / s;
    float v[8];
    {
        float4 b0 = *(const float4*)&bias[c0];
        float4 b1 = *(const float4*)&bias[c0 + 4];
        float bb[8] = {b0.x,b0.y,b0.z,b0.w,b1.x,b1.y,b1.z,b1.w};
        uint4 qr = *(const uint4*)((const char*)hresb + ((u32)dst << 8) + cb);
        f32x2 rr2[4] = {unpk(qr.x), unpk(qr.y), unpk(qr.z), unpk(qr.w)};
#pragma unroll
        for (int i = 0; i < 4; i++) {
            float t0 = fmaf(acc2[i].x, inv, bb[2*i]);
            float t1 = fmaf(acc2[i].y, inv, bb[2*i+1]);
            v[2*i]   = gelu_t(t0) + rr2[i].x;
            v[2*i+1] = gelu_t(t1) + rr2[i].y;
        }
    }

    // LayerNorm over 128 ch = 16 lanes of this sub-group (offsets 1..8 stay in-group)
    float s1 = 0.f, s2 = 0.f;
#pragma unroll
    for (int k = 0; k < 8; k++) { s1 += v[k]; s2 = fmaf(v[k], v[k], s2); }
#pragma unroll
    for (int off = 1; off < 16; off <<= 1) {
        s1 += __shfl_xor(s1, off);
        s2 += __shfl_xor(s2, off);
    }
    float mu  = s1 * (1.f / 128.f);
    float var = s2 * (1.f / 128.f) - mu * mu;
    float rstd = rsqrtf(var + 1e-5f);

    float4 g0 = *(const float4*)&gamma[c0];
    float4 g1 = *(const float4*)&gamma[c0 + 4];
    float4 be0 = *(const float4*)&beta[c0];
    float4 be1 = *(const float4*)&beta[c0 + 4];
    float gg[8] = {g0.x,g0.y,g0.z,g0.w,g1.x,g1.y,g1.z,g1.w};
    float eb[8] = {be0.x,be0.y,be0.z,be0.w,be1.x,be1.y,be1.z,be1.w};
    float o[8];
#pragma unroll
    for (int k = 0; k < 8; k++) o[k] = fmaf((v[k] - mu) * rstd, gg[k], eb[k]);
    uint4 pk;
    pk.x = (u32)f2bf(o[0]) | ((u32)f2bf(o[1]) << 16);
    pk.y = (u32)f2bf(o[2]) | ((u32)f2bf(o[3]) << 16);
    pk.z = (u32)f2bf(o[4]) | ((u32)f2bf(o[5]) << 16);
    pk.w = (u32)f2bf(o[6]) | ((u32)f2bf(o[7]) << 16);
    *(uint4*)((char*)outb + ((u32)dst << 8) + cb) = pk;
}

// ---------------- launch ----------------
extern "C" void kernel_launch(void* const* d_in, const int* in_sizes, int n_in,
                              void* d_out, int out_size, void* d_ws, size_t ws_size,
                              hipStream_t stream) {
    const void* x  = d_in[0];
    const int*  ei = (const int*)d_in[1];

    char* ws = (char*)d_ws;
    size_t off = 0;
    auto alloc = [&](size_t bytes) -> void* {
        void* p = ws + off;
        off = (off + bytes + 511) & ~(size_t)511;
        return p;
    };
    u16*   xb      = (u16*)  alloc(((size_t)NN * MM + 8192) * 2);
    float* wv      = (float*)alloc((size_t)VTOT * 4);
    u16*   wbf     = (u16*)  alloc((size_t)BTOT * 2);
    u16*   h0b     = (u16*)  alloc((size_t)(NN + 64) * HID * 2);
    u16*   h1b     = (u16*)  alloc((size_t)(NN + 64) * HID * 2);
    u16*   hlb     = (u16*)  alloc((size_t)NN * HID * 2);
    u16*   hrb     = (u16*)  alloc((size_t)NN * HID * 2);
    int*   offs    = (int*)  alloc((size_t)(NN + 1) * 4);
    u32*   gbucket = (u32*)  alloc(512 * 4);
    u32*   bbase   = (u32*)  alloc(520 * 4);
    u32*   bcursor = (u32*)  alloc(520 * 4);
    int*   flags   = (int*)  alloc(512);
    int*   srcs    = (int*)  alloc(((size_t)ETOT + 64) * 4);
    u64*   pairs   = (u64*)  alloc((size_t)ETOT * 8);
    u32*   dcnt    = (u32*)  alloc(64 * 4);
    u32*   dcur    = (u32*)  alloc(64 * 4);
    int*   perm    = (int*)  alloc((size_t)NN * 4);

    // fused prep: sniff + zero(gbucket,dcnt) + normx + norm_vec + norm_wt
    prep_kernel<<<1 + NXB + NVB + NWB, 256, 0, stream>>>(
        x, (const u32*)ei,
        d_in[3], d_in[6], d_in[7], d_in[12], d_in[13], d_in[10], d_in[11], d_in[14], d_in[15], d_in[17],
        d_in[2], d_in[4], d_in[5], d_in[8], d_in[9], d_in[16],
        xb, wv, wbf, flags, gbucket, dcnt);

    const int EB = (ETOT + CHUNK - 1) / CHUNK;  // 416
    bucket_hist_kernel<<<EB, 256, 0, stream>>>(ei, flags, gbucket);
    bucket_scan_kernel<<<1, 256, 0, stream>>>(gbucket, bbase, bcursor);
    bin_pass_kernel<<<EB, 256, 0, stream>>>(ei, flags, bcursor, pairs);
    sort_pass_kernel<<<NB, 256, 0, stream>>>(pairs, bbase, srcs, offs, dcnt);

    // degree-balance permutation (heaviest degree first)
    deg_scan_kernel<<<1, 64, 0, stream>>>(dcnt, dcur);
    deg_scatter_kernel<<<NB, 256, 0, stream>>>(offs, dcur, perm);

    const int GB = (NN + 127) / 128;  // 782
    const int AB = NN / 16;           // 6250 blocks, 4 dst/wave x 4 waves

    // proj: h0b = bf16(x @ Wp + bp)   (K=40 padded to 64)
    mfma_gemm<<<dim3(GB, 1), 256, 0, stream>>>(xb, MM, wbf + BWp, 64, wv + Vbp,
                                               NN, 2, HID, nullptr, h0b, nullptr, HID, 2, flags);

    // layer 1: hl/hr in one dispatch
    mfma_gemm<<<dim3(GB, 2), 256, 0, stream>>>(h0b, HID, wbf + BW1l, HID, nullptr,
                                               NN, 4, HID, nullptr, hlb, hrb, HID, 2, flags);
    gat_agg_kernel<<<AB, 256, 0, stream>>>(hlb, hrb, h0b, wv + Vatt1, wv + Vb1,
                                           wv + Vg1, wv + Vbe1, offs, srcs, perm, h1b);

    // layer 2
    mfma_gemm<<<dim3(GB, 2), 256, 0, stream>>>(h1b, HID, wbf + BW2l, HID, nullptr,
                                               NN, 4, HID, nullptr, hlb, hrb, HID, 2, flags);
    gat_agg_kernel<<<AB, 256, 0, stream>>>(hlb, hrb, h1b, wv + Vatt2, wv + Vb2,
                                           wv + Vg2, wv + Vbe2, offs, srcs, perm, h0b);

    // final: out = h @ Wo + bo (dtype per flags)
    mfma_gemm<<<dim3(GB, 1), 256, 0, stream>>>(h0b, HID, wbf + BWo, HID, wv + Vbo,
                                               NN, 4, LAT, (float*)d_out, (u16*)d_out, nullptr, LAT, -1, flags);
}

// Round 6
// 474.108 us; speedup vs baseline: 1.0819x; 1.0100x over previous
//
#include <hip/hip_runtime.h>
#include <hip/hip_bf16.h>
#include <math.h>

#define NN   100000
#define EE   1600000
#define ETOT 1700000   // EE + NN self loops
#define MM   40
#define HID  128
#define LAT  64
#define NB   391       // ceil(NN/256) buckets of 256 nodes
#define CHUNK 4096     // edges per bin_pass block

typedef unsigned short u16;
typedef unsigned int   u32;
typedef unsigned long long u64;

typedef __attribute__((ext_vector_type(8))) short bf16x8;
typedef __attribute__((ext_vector_type(4))) float f32x4;
typedef __attribute__((ext_vector_type(2))) float f32x2;

__device__ __forceinline__ float bf2f(u16 a) {
    return __uint_as_float(((u32)a) << 16);
}
__device__ __forceinline__ u16 f2bf(float f) {
    u32 u = __float_as_uint(f);
    u32 r = (u + 0x7fffu + ((u >> 16) & 1u)) >> 16;
    return (u16)r;
}
__device__ __forceinline__ f32x2 unpk(u32 u) {
    f32x2 r;
    r.x = __uint_as_float(u << 16);
    r.y = __uint_as_float(u & 0xffff0000u);
    return r;
}
// bare v_exp_f32: D = 2^S0 (input pre-scaled by log2(e) where e^x is wanted)
__device__ __forceinline__ float exp2_hw(float x) {
    float d;
    asm("v_exp_f32 %0, %1" : "=v"(d) : "v"(x));
    return d;
}
// tanh-form GELU via sigmoid: x * sigmoid(1.595769x + 0.0713548x^3); |err vs exact| <= ~3e-4
__device__ __forceinline__ float gelu_t(float x) {
    float x2 = x * x;
    float y = x * fmaf(0.0713548162726f, x2, 1.59576912161f);
    return x / (1.f + __expf(-y));
}

// f32 vector pack offsets (floats)
#define Vbp   0
#define Vatt1 128
#define Vb1   256
#define Vg1   384
#define Vbe1  512
#define Vatt2 640
#define Vb2   768
#define Vg2   896
#define Vbe2  1024
#define Vbo   1152
#define VTOT  1216

// bf16 transposed weight pack offsets (u16 elements)
#define BWp   0        // [128][64]  (K=40 zero-padded to 64)
#define BW1l  8192     // [128][128]
#define BW1r  24576    // adjacent to BW1l (gridDim.y=2 panel trick)
#define BW2l  40960
#define BW2r  57344
#define BWo   73728    // [64][128], padded to 128 rows (zeros)
#define BTOT  90112

// prep_kernel block-range sizes
#define NXB   15625    // (NN*MM)/256 exactly
#define NVB   5        // ceil(VTOT/256)
#define NWB   352      // BTOT/256 exactly

// per-wave bf16-ness sniff (identical predicate to original sniff_kernel)
__device__ __forceinline__ int sniff_bf_wave(const u32* __restrict__ x_raw) {
    int lane = threadIdx.x & 63;
    u32 w = x_raw[lane];              // first 64 u32 of x
    u16 lo = (u16)(w & 0xffffu);
    int e = (lo >> 7) & 0xFF;
    int ok = (e >= 118 && e <= 133) ? 1 : 0;
    u64 b = __ballot(ok);
    return (__popcll(b) >= 48) ? 1 : 0;
}

__device__ __forceinline__ void edge_decode(const int* __restrict__ ei, int is64, int e,
                                            int& src, int& dst) {
    if (e < EE) {
        src = is64 ? ei[2 * e] : ei[e];
        int idx = EE + e;
        dst = is64 ? ei[2 * idx] : ei[idx];
    } else {
        src = e - EE; dst = src;
    }
}

// ---------------- fused prep: sniff + zero + normx + norm_vec + norm_wt ----------------
__global__ __launch_bounds__(256) void prep_kernel(
    const void* __restrict__ x, const u32* __restrict__ ei_raw,
    const void* p0, const void* p1, const void* p2, const void* p3, const void* p4,
    const void* p5, const void* p6, const void* p7, const void* p8, const void* p9,
    const void* w0, const void* w1, const void* w2, const void* w3, const void* w4,
    const void* w5,
    u16* __restrict__ xb, float* __restrict__ wv, u16* __restrict__ wbf,
    int* __restrict__ flags, u32* __restrict__ gbucket, u32* __restrict__ dcnt,
    u32* __restrict__ gcur, u32* __restrict__ dcur)
{
    const u32* x_raw = (const u32*)x;
    int isbf = sniff_bf_wave(x_raw);
    int t = threadIdx.x;
    int b = blockIdx.x;

    if (b == 0) {
        // is64 sniff: all odd u32 in [1,255] zero -> int64 edge index
        if (t < 64) {
            u32 a = ei_raw[2 * t + 1] | ei_raw[129 + 2 * t];
            u64 nz = __ballot(a != 0u);
            if (t == 0) { flags[0] = (nz == 0uLL) ? 1 : 0; flags[1] = isbf; }
        }
        gbucket[t] = 0; gbucket[t + 256] = 0;
        gcur[t] = 0;    gcur[t + 256] = 0;
        if (t < 64) { dcnt[t] = 0; dcur[t] = 0; }
        return;
    }
    if (b <= NXB) {
        // normx: x -> bf16
        int i = (b - 1) * 256 + t;   // grid sized exactly: i < NN*MM
        xb[i] = isbf ? ((const u16*)x)[i] : f2bf(((const float*)x)[i]);
        return;
    }
    if (b <= NXB + NVB) {
        int i = (b - 1 - NXB) * 256 + t;
        if (i >= VTOT) return;
        const int offs[11] = {Vbp, Vatt1, Vb1, Vg1, Vbe1, Vatt2, Vb2, Vg2, Vbe2, Vbo, VTOT};
        const void* ps[10] = {p0,p1,p2,p3,p4,p5,p6,p7,p8,p9};
        int s = 0;
#pragma unroll
        for (int k = 1; k < 10; k++) s += (i >= offs[k]) ? 1 : 0;
        int j = i - offs[s];
        const void* p = ps[s];
        wv[i] = isbf ? bf2f(((const u16*)p)[j]) : ((const float*)p)[j];
        return;
    }
    {
        int i = (b - 1 - NXB - NVB) * 256 + t;   // grid sized exactly: i < BTOT
        const int offs[7] = {BWp, BW1l, BW1r, BW2l, BW2r, BWo, BTOT};
        const int Ks[6]   = {40, 128, 128, 128, 128, 128};
        const int Ncs[6]  = {128, 128, 128, 128, 128, 64};
        const int Kps[6]  = {64, 128, 128, 128, 128, 128};
        const void* ps[6] = {w0,w1,w2,w3,w4,w5};
        int s = 0;
#pragma unroll
        for (int k = 1; k < 6; k++) s += (i >= offs[k]) ? 1 : 0;
        int j = i - offs[s];
        int Kp = Kps[s];
        int n = j / Kp, k = j % Kp;
        u16 v = 0;
        if (k < Ks[s] && n < Ncs[s]) {
            const void* p = ps[s];
            int src = k * Ncs[s] + n;
            v = isbf ? ((const u16*)p)[src] : f2bf(((const float*)p)[src]);
        }
        wbf[i] = v;
    }
}

// ---------------- CSR build: 2-pass LDS-binned counting sort ----------------
__global__ __launch_bounds__(256) void bucket_hist_kernel(
    const int* __restrict__ ei, const int* __restrict__ flags, u32* __restrict__ gbucket)
{
    __shared__ u32 h[512];
    int t = threadIdx.x;
    h[t] = 0; h[t + 256] = 0;
    __syncthreads();
    int is64 = flags[0];
    int base = blockIdx.x * CHUNK;
#pragma unroll
    for (int j = 0; j < CHUNK / 256; j++) {
        int e = base + j * 256 + t;
        if (e < ETOT) {
            int src, dst;
            edge_decode(ei, is64, e, src, dst);
            atomicAdd(&h[dst >> 8], 1u);
        }
    }
    __syncthreads();
    if (h[t])       atomicAdd(&gbucket[t], h[t]);
    if (h[t + 256]) atomicAdd(&gbucket[t + 256], h[t + 256]);
}

// bin_pass with local gbucket scan (bucket_scan fused away). gcur is zero-init;
// global reservation = local_scan[t] + atomicAdd(&gcur[t], bh[t]).
__global__ __launch_bounds__(256) void bin_pass_kernel(
    const int* __restrict__ ei, const int* __restrict__ flags,
    const u32* __restrict__ gbucket, u32* __restrict__ gcur, u64* __restrict__ pairs)
{
    __shared__ u32 bh[512];
    __shared__ u32 boff[512];
    __shared__ u32 bbs[512];
    __shared__ u32 bcur[512];
    __shared__ u32 bsc[512];
    __shared__ u64 stage[CHUNK];
    __shared__ u32 ts[256];

    int t = threadIdx.x;
    bh[t] = 0; bh[t + 256] = 0;
    __syncthreads();
    int is64 = flags[0];
    int base = blockIdx.x * CHUNK;
    int chunk_n = ETOT - base; if (chunk_n > CHUNK) chunk_n = CHUNK;

#pragma unroll
    for (int j = 0; j < CHUNK / 256; j++) {
        int e = base + j * 256 + t;
        if (e < ETOT) {
            int src, dst;
            edge_decode(ei, is64, e, src, dst);
            atomicAdd(&bh[dst >> 8], 1u);
        }
    }
    __syncthreads();

    // local exclusive scan of gbucket -> bsc (replaces global bucket_scan)
    {
        u32 g0v = (2 * t     < NB) ? gbucket[2 * t]     : 0;
        u32 g1v = (2 * t + 1 < NB) ? gbucket[2 * t + 1] : 0;
        u32 ps = g0v + g1v;
        ts[t] = ps; __syncthreads();
        for (int d = 1; d < 256; d <<= 1) {
            u32 v = (t >= d) ? ts[t - d] : 0;
            __syncthreads();
            ts[t] += v;
            __syncthreads();
        }
        u32 ex = ts[t] - ps;
        bsc[2 * t] = ex; bsc[2 * t + 1] = ex + g0v;
    }
    __syncthreads();

    // local scan of block histogram
    u32 s0 = bh[2 * t], s1 = bh[2 * t + 1];
    u32 tsum = s0 + s1;
    ts[t] = tsum; __syncthreads();
    for (int d = 1; d < 256; d <<= 1) {
        u32 v = (t >= d) ? ts[t - d] : 0;
        __syncthreads();
        ts[t] += v;
        __syncthreads();
    }
    u32 excl = ts[t] - tsum;
    boff[2 * t] = excl; boff[2 * t + 1] = excl + s0;
    bcur[2 * t] = excl; bcur[2 * t + 1] = excl + s0;
    __syncthreads();
    if (t < NB && bh[t]) bbs[t] = bsc[t] + atomicAdd(&gcur[t], bh[t]);
    if (t + 256 < NB && bh[t + 256]) bbs[t + 256] = bsc[t + 256] + atomicAdd(&gcur[t + 256], bh[t + 256]);
    __syncthreads();
#pragma unroll
    for (int j = 0; j < CHUNK / 256; j++) {
        int e = base + j * 256 + t;
        if (e < ETOT) {
            int src, dst;
            edge_decode(ei, is64, e, src, dst);
            u32 pos = atomicAdd(&bcur[dst >> 8], 1u);
            stage[pos] = (u64)src | ((u64)dst << 32);
        }
    }
    __syncthreads();
    for (int i = t; i < chunk_n; i += 256) {
        u64 pr = stage[i];
        u32 b = (u32)(pr >> 32) >> 8;
        pairs[(size_t)bbs[b] + (i - boff[b])] = pr;
    }
}

// sort within bucket + CSR offs + degree histogram; bucket bounds from local scan
__global__ __launch_bounds__(256) void sort_pass_kernel(
    const u64* __restrict__ pairs, const u32* __restrict__ gbucket,
    int* __restrict__ srcs, int* __restrict__ offs, u32* __restrict__ dcnt)
{
    __shared__ u32 nh[256];
    __shared__ u32 ns[256];
    __shared__ u32 ncur[256];
    __shared__ u32 dh[64];
    __shared__ u32 bsc[512];
    int t = threadIdx.x;
    int b = blockIdx.x;

    // local exclusive scan of gbucket
    {
        u32 g0v = (2 * t     < NB) ? gbucket[2 * t]     : 0;
        u32 g1v = (2 * t + 1 < NB) ? gbucket[2 * t + 1] : 0;
        u32 ps = g0v + g1v;
        ns[t] = ps; __syncthreads();
        for (int d = 1; d < 256; d <<= 1) {
            u32 v = (t >= d) ? ns[t - d] : 0;
            __syncthreads();
            ns[t] += v;
            __syncthreads();
        }
        u32 ex = ns[t] - ps;
        bsc[2 * t] = ex; bsc[2 * t + 1] = ex + g0v;
    }
    __syncthreads();
    u32 beg = bsc[b], endp = bsc[b + 1];

    nh[t] = 0;
    if (t < 64) dh[t] = 0;
    __syncthreads();
    for (u32 i = beg + t; i < endp; i += 256) {
        u32 dst = (u32)(pairs[i] >> 32);
        atomicAdd(&nh[dst & 255], 1u);
    }
    __syncthreads();
    u32 cnt = nh[t];
    ns[t] = cnt; __syncthreads();
    for (int d = 1; d < 256; d <<= 1) {
        u32 v = (t >= d) ? ns[t - d] : 0;
        __syncthreads();
        ns[t] += v;
        __syncthreads();
    }
    u32 excl = ns[t] - cnt;
    int id = b * 256 + t;
    if (id <= NN) offs[id] = (int)(beg + excl);
    if (id < NN) atomicAdd(&dh[cnt < 63u ? cnt : 63u], 1u);
    ncur[t] = excl;
    __syncthreads();
    if (t < 64 && dh[t]) atomicAdd(&dcnt[t], dh[t]);
    for (u32 i = beg + t; i < endp; i += 256) {
        u64 pr = pairs[i];
        u32 loc = ((u32)(pr >> 32)) & 255;
        u32 p = atomicAdd(&ncur[loc], 1u);
        srcs[beg + p] = (int)(u32)pr;
    }
}

// ---------------- degree-balance permutation (scan fused, dcur zero-init) ----------------
// Heaviest degree first: waves see 4 near-equal-degree dsts -> max(deg)~deg.
__global__ __launch_bounds__(256) void deg_perm_kernel(
    const int* __restrict__ offs, const u32* __restrict__ dcnt,
    u32* __restrict__ dcur, int* __restrict__ perm)
{
    __shared__ u32 cnt[64];
    __shared__ u32 base[64];
    __shared__ u32 sb[64];
    int t = threadIdx.x;
    if (t < 64) {
        // in-wave suffix scan of dcnt (descending-degree layout)
        u32 v = dcnt[t];
        u32 x = v;
#pragma unroll
        for (int off = 1; off < 64; off <<= 1) {
            u32 y = __shfl_down(x, off);
            if (t + off < 64) x += y;
        }
        sb[t] = x - v;   // exclusive suffix sum = global base of bucket t
        cnt[t] = 0;
    }
    __syncthreads();
    int i = blockIdx.x * 256 + t;
    int d = 0; u32 r = 0;
    bool ok = (i < NN);
    if (ok) {
        d = offs[i + 1] - offs[i];
        if (d > 63) d = 63;
        r = atomicAdd(&cnt[d], 1u);
    }
    __syncthreads();
    if (t < 64 && cnt[t]) base[t] = sb[t] + atomicAdd(&dcur[t], cnt[t]);
    __syncthreads();
    if (ok) perm[base[d] + r] = i;
}

// ---------------- MFMA GEMM ----------------
__global__ __launch_bounds__(256) void mfma_gemm(
    const u16* __restrict__ A, int lda,
    const u16* __restrict__ Bt, int ldb,
    const float* __restrict__ bias,
    int nrows, int ksteps, int ncols,
    float* __restrict__ outF, u16* __restrict__ outB, u16* __restrict__ outB2, int ldo,
    int mode, const int* __restrict__ flags)
{
    int lane = threadIdx.x & 63;
    int wv = threadIdx.x >> 6;
    int wx = wv & 1, wy = wv >> 1;
    int l16 = lane & 15, quad = lane >> 4;
    int r0 = blockIdx.x * 128 + wx * 64;
    int n0 = wy * 64;

    Bt += (size_t)blockIdx.y * 128 * ldb;
    if (blockIdx.y) outB = outB2;

    f32x4 acc[4][4];
#pragma unroll
    for (int m = 0; m < 4; m++)
#pragma unroll
        for (int n = 0; n < 4; n++) acc[m][n] = (f32x4){0.f, 0.f, 0.f, 0.f};

    const u16* Ap = A + (size_t)(r0 + l16) * lda + quad * 8;
    const u16* Bp = Bt + (size_t)(n0 + l16) * ldb + quad * 8;

    for (int k = 0; k < ksteps; ++k) {
        bf16x8 af[4], bfr[4];
#pragma unroll
        for (int m = 0; m < 4; m++)
            af[m] = *(const bf16x8*)(Ap + (size_t)m * 16 * lda + k * 32);
#pragma unroll
        for (int n = 0; n < 4; n++)
            bfr[n] = *(const bf16x8*)(Bp + (size_t)n * 16 * ldb + k * 32);
#pragma unroll
        for (int m = 0; m < 4; m++)
#pragma unroll
            for (int n = 0; n < 4; n++)
                acc[m][n] = __builtin_amdgcn_mfma_f32_16x16x32_bf16(af[m], bfr[n], acc[m][n], 0, 0, 0);
    }

    int mk = mode;
    if (mk < 0) mk = flags[1] ? 2 : 1;

#pragma unroll
    for (int m = 0; m < 4; m++) {
#pragma unroll
        for (int n = 0; n < 4; n++) {
            int col = n0 + n * 16 + l16;
            float bb = (bias != nullptr && col < ncols) ? bias[col] : 0.f;
#pragma unroll
            for (int reg = 0; reg < 4; reg++) {
                int row = r0 + m * 16 + quad * 4 + reg;
                if (row < nrows && col < ncols) {
                    float v = acc[m][n][reg] + bb;
                    if (mk & 1) outF[(size_t)row * ldo + col] = v;
                    if (mk & 2) outB[(size_t)row * ldo + col] = f2bf(v);
                }
            }
        }
    }
}

// ---------------- fused GATv2 agg + bias + GELU + residual + LayerNorm ----------------
// 4 dst per wave (sub = lane>>4), lane r = lane&15 owns ch r*8..r*8+7.
// dsts via degree-sorted perm (wave's 4 dsts near-equal degree -> max(deg)~deg).
// Distance-1 prefetch (proven 44-VGPR body). att pre-scaled by log2(e) so
// exp is a bare v_exp_f32; hl gathers via u32 byte offsets.
__global__ __launch_bounds__(256) void gat_agg_kernel(
    const u16* __restrict__ hl, const u16* __restrict__ hr, const u16* __restrict__ hresb,
    const float* __restrict__ att, const float* __restrict__ bias,
    const float* __restrict__ gamma, const float* __restrict__ beta,
    const int* __restrict__ offs, const int* __restrict__ srcs,
    const int* __restrict__ perm,
    u16* __restrict__ outb)
{
    int lane = threadIdx.x & 63;
    int sub = lane >> 4;
    int r = lane & 15;
    int c0 = r * 8;
    u32 cb = (u32)(r << 4);              // byte offset of this lane's 8 ch (16 B)
    int id = (blockIdx.x * 4 + (threadIdx.x >> 6)) * 4 + sub;   // grid = NN/16 blocks
    int dst = perm[id];

    int start = offs[dst];
    int deg = offs[dst + 1] - start;    // >= 1 (self loop)
    int dm = deg - 1;
    const char* hlc = (const char*)hl;

    f32x2 hr2[4], av2[4];
    {
        uint4 q = *(const uint4*)((const char*)hr + ((u32)dst << 8) + cb);
        hr2[0] = unpk(q.x); hr2[1] = unpk(q.y); hr2[2] = unpk(q.z); hr2[3] = unpk(q.w);
        const float L2E = 1.4426950408889634f;   // logits scaled so exp(x) = exp2(x*L2E)
        float4 a0 = *(const float4*)&att[c0];
        float4 a1 = *(const float4*)&att[c0 + 4];
        av2[0] = (f32x2){L2E * a0.x, L2E * a0.y}; av2[1] = (f32x2){L2E * a0.z, L2E * a0.w};
        av2[2] = (f32x2){L2E * a1.x, L2E * a1.y}; av2[3] = (f32x2){L2E * a1.z, L2E * a1.w};
    }

    // wave-uniform iteration bound = max deg over the 4 sub-groups (~deg after perm)
    int md = deg;
    md = max(md, __shfl_xor(md, 16));
    md = max(md, __shfl_xor(md, 32));

    f32x2 acc2[4];
#pragma unroll
    for (int i = 0; i < 4; i++) acc2[i] = (f32x2){0.f, 0.f};
    float s = 0.f;

    // prefetch: edges 0,1 rows; srcs for edges 2,3
    int sa = srcs[start];
    int sb = srcs[start + (1 < dm ? 1 : dm)];
    uint4 qa = *(const uint4*)(hlc + ((u32)sa << 8) + cb);
    uint4 qb = *(const uint4*)(hlc + ((u32)sb << 8) + cb);
    int sna = srcs[start + (2 < dm ? 2 : dm)];
    int snb = srcs[start + (3 < dm ? 3 : dm)];

    int mi = (md + 1) >> 1;
    for (int j = 0; j < mi; ++j) {
        // srcs for iteration j+2 (edges 2j+4, 2j+5)
        int e4 = 2 * j + 4, e5 = 2 * j + 5;
        int sna2 = srcs[start + min(e4, dm)];
        int snb2 = srcs[start + min(e5, dm)];
        // rows for iteration j+1
        uint4 qna = *(const uint4*)(hlc + ((u32)sna << 8) + cb);
        uint4 qnb = *(const uint4*)(hlc + ((u32)snb << 8) + cb);

        f32x2 ha[4], hb[4];
        ha[0] = unpk(qa.x); ha[1] = unpk(qa.y); ha[2] = unpk(qa.z); ha[3] = unpk(qa.w);
        hb[0] = unpk(qb.x); hb[1] = unpk(qb.y); hb[2] = unpk(qb.z); hb[3] = unpk(qb.w);
        f32x2 pa2 = (f32x2){0.f, 0.f};
        f32x2 pb2 = (f32x2){0.f, 0.f};
#pragma unroll
        for (int i = 0; i < 4; i++) {
            f32x2 za = ha[i] + hr2[i];
            f32x2 zb = hb[i] + hr2[i];
            f32x2 la = __builtin_elementwise_max(za, za * 0.2f);
            f32x2 lb = __builtin_elementwise_max(zb, zb * 0.2f);
            pa2 = __builtin_elementwise_fma(av2[i], la, pa2);
            pb2 = __builtin_elementwise_fma(av2[i], lb, pb2);
        }
        float pa = pa2.x + pa2.y;
        float pb = pb2.x + pb2.y;
        pa += __shfl_xor(pa, 1); pb += __shfl_xor(pb, 1);
        pa += __shfl_xor(pa, 2); pb += __shfl_xor(pb, 2);
        int e0 = 2 * j, e1 = 2 * j + 1;
        float wa = (e0 < deg) ? exp2_hw(pa) : 0.f;
        float wb = (e1 < deg) ? exp2_hw(pb) : 0.f;
        s += wa + wb;
        f32x2 wa2 = (f32x2){wa, wa};
        f32x2 wb2 = (f32x2){wb, wb};
#pragma unroll
        for (int i = 0; i < 4; i++)
            acc2[i] = __builtin_elementwise_fma(wa2, ha[i],
                      __builtin_elementwise_fma(wb2, hb[i], acc2[i]));

        qa = qna; qb = qnb; sna = sna2; snb = snb2;
    }

    float inv = 1.f / s;
    float v[8];
    {
        float4 b0 = *(const float4*)&bias[c0];
        float4 b1 = *(const float4*)&bias[c0 + 4];
        float bb[8] = {b0.x,b0.y,b0.z,b0.w,b1.x,b1.y,b1.z,b1.w};
        uint4 qr = *(const uint4*)((const char*)hresb + ((u32)dst << 8) + cb);
        f32x2 rr2[4] = {unpk(qr.x), unpk(qr.y), unpk(qr.z), unpk(qr.w)};
#pragma unroll
        for (int i = 0; i < 4; i++) {
            float t0 = fmaf(acc2[i].x, inv, bb[2*i]);
            float t1 = fmaf(acc2[i].y, inv, bb[2*i+1]);
            v[2*i]   = gelu_t(t0) + rr2[i].x;
            v[2*i+1] = gelu_t(t1) + rr2[i].y;
        }
    }

    // LayerNorm over 128 ch = 16 lanes of this sub-group (offsets 1..8 stay in-group)
    float s1 = 0.f, s2 = 0.f;
#pragma unroll
    for (int k = 0; k < 8; k++) { s1 += v[k]; s2 = fmaf(v[k], v[k], s2); }
#pragma unroll
    for (int off = 1; off < 16; off <<= 1) {
        s1 += __shfl_xor(s1, off);
        s2 += __shfl_xor(s2, off);
    }
    float mu  = s1 * (1.f / 128.f);
    float var = s2 * (1.f / 128.f) - mu * mu;
    float rstd = rsqrtf(var + 1e-5f);

    float4 g0 = *(const float4*)&gamma[c0];
    float4 g1 = *(const float4*)&gamma[c0 + 4];
    float4 be0 = *(const float4*)&beta[c0];
    float4 be1 = *(const float4*)&beta[c0 + 4];
    float gg[8] = {g0.x,g0.y,g0.z,g0.w,g1.x,g1.y,g1.z,g1.w};
    float eb[8] = {be0.x,be0.y,be0.z,be0.w,be1.x,be1.y,be1.z,be1.w};
    float o[8];
#pragma unroll
    for (int k = 0; k < 8; k++) o[k] = fmaf((v[k] - mu) * rstd, gg[k], eb[k]);
    uint4 pk;
    pk.x = (u32)f2bf(o[0]) | ((u32)f2bf(o[1]) << 16);
    pk.y = (u32)f2bf(o[2]) | ((u32)f2bf(o[3]) << 16);
    pk.z = (u32)f2bf(o[4]) | ((u32)f2bf(o[5]) << 16);
    pk.w = (u32)f2bf(o[6]) | ((u32)f2bf(o[7]) << 16);
    *(uint4*)((char*)outb + ((u32)dst << 8) + cb) = pk;
}

// ---------------- launch ----------------
extern "C" void kernel_launch(void* const* d_in, const int* in_sizes, int n_in,
                              void* d_out, int out_size, void* d_ws, size_t ws_size,
                              hipStream_t stream) {
    const void* x  = d_in[0];
    const int*  ei = (const int*)d_in[1];

    char* ws = (char*)d_ws;
    size_t off = 0;
    auto alloc = [&](size_t bytes) -> void* {
        void* p = ws + off;
        off = (off + bytes + 511) & ~(size_t)511;
        return p;
    };
    u16*   xb      = (u16*)  alloc(((size_t)NN * MM + 8192) * 2);
    float* wv      = (float*)alloc((size_t)VTOT * 4);
    u16*   wbf     = (u16*)  alloc((size_t)BTOT * 2);
    u16*   h0b     = (u16*)  alloc((size_t)(NN + 64) * HID * 2);
    u16*   h1b     = (u16*)  alloc((size_t)(NN + 64) * HID * 2);
    u16*   hlb     = (u16*)  alloc((size_t)NN * HID * 2);
    u16*   hrb     = (u16*)  alloc((size_t)NN * HID * 2);
    int*   offs    = (int*)  alloc((size_t)(NN + 1) * 4);
    u32*   gbucket = (u32*)  alloc(512 * 4);
    u32*   gcur    = (u32*)  alloc(512 * 4);
    int*   flags   = (int*)  alloc(512);
    int*   srcs    = (int*)  alloc(((size_t)ETOT + 64) * 4);
    u64*   pairs   = (u64*)  alloc((size_t)ETOT * 8);
    u32*   dcnt    = (u32*)  alloc(64 * 4);
    u32*   dcur    = (u32*)  alloc(64 * 4);
    int*   perm    = (int*)  alloc((size_t)NN * 4);

    // fused prep: sniff + zero(gbucket,gcur,dcnt,dcur) + normx + norm_vec + norm_wt
    prep_kernel<<<1 + NXB + NVB + NWB, 256, 0, stream>>>(
        x, (const u32*)ei,
        d_in[3], d_in[6], d_in[7], d_in[12], d_in[13], d_in[10], d_in[11], d_in[14], d_in[15], d_in[17],
        d_in[2], d_in[4], d_in[5], d_in[8], d_in[9], d_in[16],
        xb, wv, wbf, flags, gbucket, dcnt, gcur, dcur);

    const int EB = (ETOT + CHUNK - 1) / CHUNK;  // 416
    bucket_hist_kernel<<<EB, 256, 0, stream>>>(ei, flags, gbucket);
    bin_pass_kernel<<<EB, 256, 0, stream>>>(ei, flags, gbucket, gcur, pairs);
    sort_pass_kernel<<<NB, 256, 0, stream>>>(pairs, gbucket, srcs, offs, dcnt);

    // degree-balance permutation (scan fused; heaviest degree first)
    deg_perm_kernel<<<NB, 256, 0, stream>>>(offs, dcnt, dcur, perm);

    const int GB = (NN + 127) / 128;  // 782
    const int AB = NN / 16;           // 6250 blocks, 4 dst/wave x 4 waves

    // proj: h0b = bf16(x @ Wp + bp)   (K=40 padded to 64)
    mfma_gemm<<<dim3(GB, 1), 256, 0, stream>>>(xb, MM, wbf + BWp, 64, wv + Vbp,
                                               NN, 2, HID, nullptr, h0b, nullptr, HID, 2, flags);

    // layer 1: hl/hr in one dispatch
    mfma_gemm<<<dim3(GB, 2), 256, 0, stream>>>(h0b, HID, wbf + BW1l, HID, nullptr,
                                               NN, 4, HID, nullptr, hlb, hrb, HID, 2, flags);
    gat_agg_kernel<<<AB, 256, 0, stream>>>(hlb, hrb, h0b, wv + Vatt1, wv + Vb1,
                                           wv + Vg1, wv + Vbe1, offs, srcs, perm, h1b);

    // layer 2
    mfma_gemm<<<dim3(GB, 2), 256, 0, stream>>>(h1b, HID, wbf + BW2l, HID, nullptr,
                                               NN, 4, HID, nullptr, hlb, hrb, HID, 2, flags);
    gat_agg_kernel<<<AB, 256, 0, stream>>>(hlb, hrb, h1b, wv + Vatt2, wv + Vb2,
                                           wv + Vg2, wv + Vbe2, offs, srcs, perm, h0b);

    // final: out = h @ Wo + bo (dtype per flags)
    mfma_gemm<<<dim3(GB, 1), 256, 0, stream>>>(h0b, HID, wbf + BWo, HID, wv + Vbo,
                                               NN, 4, LAT, (float*)d_out, (u16*)d_out, nullptr, LAT, -1, flags);
}

// Round 7
// 419.220 us; speedup vs baseline: 1.2235x; 1.1309x over previous
//
#include <hip/hip_runtime.h>
#include <hip/hip_bf16.h>
#include <math.h>

#define NN   100000
#define EE   1600000
#define ETOT 1700000   // EE + NN self loops
#define MM   40
#define HID  128
#define LAT  64
#define NB   391       // ceil(NN/256) buckets of 256 nodes
#define CHUNK 4096     // edges per bin_pass block

typedef unsigned short u16;
typedef unsigned int   u32;
typedef unsigned long long u64;

typedef __attribute__((ext_vector_type(8))) short bf16x8;
typedef __attribute__((ext_vector_type(4))) float f32x4;
typedef __attribute__((ext_vector_type(2))) float f32x2;

__device__ __forceinline__ float bf2f(u16 a) {
    return __uint_as_float(((u32)a) << 16);
}
__device__ __forceinline__ u16 f2bf(float f) {
    u32 u = __float_as_uint(f);
    u32 r = (u + 0x7fffu + ((u >> 16) & 1u)) >> 16;
    return (u16)r;
}
__device__ __forceinline__ f32x2 unpk(u32 u) {
    f32x2 r;
    r.x = __uint_as_float(u << 16);
    r.y = __uint_as_float(u & 0xffff0000u);
    return r;
}
// bare v_exp_f32: D = 2^S0 (input pre-scaled by log2(e) where e^x is wanted)
__device__ __forceinline__ float exp2_hw(float x) {
    float d;
    asm("v_exp_f32 %0, %1" : "=v"(d) : "v"(x));
    return d;
}
// async global->LDS, 16B per lane (dest = wave-uniform base + lane*16)
__device__ __forceinline__ void gload_lds16(const void* g, void* l) {
    __builtin_amdgcn_global_load_lds(
        (const __attribute__((address_space(1))) void*)g,
        (__attribute__((address_space(3))) void*)l, 16, 0, 0);
}
// tanh-form GELU via sigmoid: x * sigmoid(1.595769x + 0.0713548x^3); |err vs exact| <= ~3e-4
__device__ __forceinline__ float gelu_t(float x) {
    float x2 = x * x;
    float y = x * fmaf(0.0713548162726f, x2, 1.59576912161f);
    return x / (1.f + __expf(-y));
}

// f32 vector pack offsets (floats)
#define Vbp   0
#define Vatt1 128
#define Vb1   256
#define Vg1   384
#define Vbe1  512
#define Vatt2 640
#define Vb2   768
#define Vg2   896
#define Vbe2  1024
#define Vbo   1152
#define VTOT  1216

// bf16 transposed weight pack offsets (u16 elements)
#define BWp   0        // [128][64]  (K=40 zero-padded to 64)
#define BW1l  8192     // [128][128]
#define BW1r  24576    // adjacent to BW1l -> [256][128] panel for gemm_layer
#define BW2l  40960
#define BW2r  57344
#define BWo   73728    // [64][128], padded to 128 rows (zeros)
#define BTOT  90112

// prep_kernel block-range sizes
#define NXB   15625    // (NN*MM)/256 exactly
#define NVB   5        // ceil(VTOT/256)
#define NWB   352      // BTOT/256 exactly

// per-wave bf16-ness sniff (identical predicate to original sniff_kernel)
__device__ __forceinline__ int sniff_bf_wave(const u32* __restrict__ x_raw) {
    int lane = threadIdx.x & 63;
    u32 w = x_raw[lane];              // first 64 u32 of x
    u16 lo = (u16)(w & 0xffffu);
    int e = (lo >> 7) & 0xFF;
    int ok = (e >= 118 && e <= 133) ? 1 : 0;
    u64 b = __ballot(ok);
    return (__popcll(b) >= 48) ? 1 : 0;
}

__device__ __forceinline__ void edge_decode(const int* __restrict__ ei, int is64, int e,
                                            int& src, int& dst) {
    if (e < EE) {
        src = is64 ? ei[2 * e] : ei[e];
        int idx = EE + e;
        dst = is64 ? ei[2 * idx] : ei[idx];
    } else {
        src = e - EE; dst = src;
    }
}

// ---------------- fused prep: sniff + zero + normx + norm_vec + norm_wt ----------------
__global__ __launch_bounds__(256) void prep_kernel(
    const void* __restrict__ x, const u32* __restrict__ ei_raw,
    const void* p0, const void* p1, const void* p2, const void* p3, const void* p4,
    const void* p5, const void* p6, const void* p7, const void* p8, const void* p9,
    const void* w0, const void* w1, const void* w2, const void* w3, const void* w4,
    const void* w5,
    u16* __restrict__ xb, float* __restrict__ wv, u16* __restrict__ wbf,
    int* __restrict__ flags, u32* __restrict__ gbucket, u32* __restrict__ dcnt,
    u32* __restrict__ gcur, u32* __restrict__ dcur)
{
    const u32* x_raw = (const u32*)x;
    int isbf = sniff_bf_wave(x_raw);
    int t = threadIdx.x;
    int b = blockIdx.x;

    if (b == 0) {
        // is64 sniff: all odd u32 in [1,255] zero -> int64 edge index
        if (t < 64) {
            u32 a = ei_raw[2 * t + 1] | ei_raw[129 + 2 * t];
            u64 nz = __ballot(a != 0u);
            if (t == 0) { flags[0] = (nz == 0uLL) ? 1 : 0; flags[1] = isbf; }
        }
        gbucket[t] = 0; gbucket[t + 256] = 0;
        gcur[t] = 0;    gcur[t + 256] = 0;
        if (t < 64) { dcnt[t] = 0; dcur[t] = 0; }
        return;
    }
    if (b <= NXB) {
        // normx: x -> bf16
        int i = (b - 1) * 256 + t;   // grid sized exactly: i < NN*MM
        xb[i] = isbf ? ((const u16*)x)[i] : f2bf(((const float*)x)[i]);
        return;
    }
    if (b <= NXB + NVB) {
        int i = (b - 1 - NXB) * 256 + t;
        if (i >= VTOT) return;
        const int offs[11] = {Vbp, Vatt1, Vb1, Vg1, Vbe1, Vatt2, Vb2, Vg2, Vbe2, Vbo, VTOT};
        const void* ps[10] = {p0,p1,p2,p3,p4,p5,p6,p7,p8,p9};
        int s = 0;
#pragma unroll
        for (int k = 1; k < 10; k++) s += (i >= offs[k]) ? 1 : 0;
        int j = i - offs[s];
        const void* p = ps[s];
        wv[i] = isbf ? bf2f(((const u16*)p)[j]) : ((const float*)p)[j];
        return;
    }
    {
        int i = (b - 1 - NXB - NVB) * 256 + t;   // grid sized exactly: i < BTOT
        const int offs[7] = {BWp, BW1l, BW1r, BW2l, BW2r, BWo, BTOT};
        const int Ks[6]   = {40, 128, 128, 128, 128, 128};
        const int Ncs[6]  = {128, 128, 128, 128, 128, 64};
        const int Kps[6]  = {64, 128, 128, 128, 128, 128};
        const void* ps[6] = {w0,w1,w2,w3,w4,w5};
        int s = 0;
#pragma unroll
        for (int k = 1; k < 6; k++) s += (i >= offs[k]) ? 1 : 0;
        int j = i - offs[s];
        int Kp = Kps[s];
        int n = j / Kp, k = j % Kp;
        u16 v = 0;
        if (k < Ks[s] && n < Ncs[s]) {
            const void* p = ps[s];
            int src = k * Ncs[s] + n;
            v = isbf ? ((const u16*)p)[src] : f2bf(((const float*)p)[src]);
        }
        wbf[i] = v;
    }
}

// ---------------- CSR build: 2-pass LDS-binned counting sort ----------------
__global__ __launch_bounds__(256) void bucket_hist_kernel(
    const int* __restrict__ ei, const int* __restrict__ flags, u32* __restrict__ gbucket)
{
    __shared__ u32 h[512];
    int t = threadIdx.x;
    h[t] = 0; h[t + 256] = 0;
    __syncthreads();
    int is64 = flags[0];
    int base = blockIdx.x * CHUNK;
#pragma unroll
    for (int j = 0; j < CHUNK / 256; j++) {
        int e = base + j * 256 + t;
        if (e < ETOT) {
            int src, dst;
            edge_decode(ei, is64, e, src, dst);
            atomicAdd(&h[dst >> 8], 1u);
        }
    }
    __syncthreads();
    if (h[t])       atomicAdd(&gbucket[t], h[t]);
    if (h[t + 256]) atomicAdd(&gbucket[t + 256], h[t + 256]);
}

// bin_pass with local gbucket scan (bucket_scan fused away). gcur is zero-init;
// global reservation = local_scan[t] + atomicAdd(&gcur[t], bh[t]).
__global__ __launch_bounds__(256) void bin_pass_kernel(
    const int* __restrict__ ei, const int* __restrict__ flags,
    const u32* __restrict__ gbucket, u32* __restrict__ gcur, u64* __restrict__ pairs)
{
    __shared__ u32 bh[512];
    __shared__ u32 boff[512];
    __shared__ u32 bbs[512];
    __shared__ u32 bcur[512];
    __shared__ u32 bsc[512];
    __shared__ u64 stage[CHUNK];
    __shared__ u32 ts[256];

    int t = threadIdx.x;
    bh[t] = 0; bh[t + 256] = 0;
    __syncthreads();
    int is64 = flags[0];
    int base = blockIdx.x * CHUNK;
    int chunk_n = ETOT - base; if (chunk_n > CHUNK) chunk_n = CHUNK;

#pragma unroll
    for (int j = 0; j < CHUNK / 256; j++) {
        int e = base + j * 256 + t;
        if (e < ETOT) {
            int src, dst;
            edge_decode(ei, is64, e, src, dst);
            atomicAdd(&bh[dst >> 8], 1u);
        }
    }
    __syncthreads();

    // local exclusive scan of gbucket -> bsc (replaces global bucket_scan)
    {
        u32 g0v = (2 * t     < NB) ? gbucket[2 * t]     : 0;
        u32 g1v = (2 * t + 1 < NB) ? gbucket[2 * t + 1] : 0;
        u32 ps = g0v + g1v;
        ts[t] = ps; __syncthreads();
        for (int d = 1; d < 256; d <<= 1) {
            u32 v = (t >= d) ? ts[t - d] : 0;
            __syncthreads();
            ts[t] += v;
            __syncthreads();
        }
        u32 ex = ts[t] - ps;
        bsc[2 * t] = ex; bsc[2 * t + 1] = ex + g0v;
    }
    __syncthreads();

    // local scan of block histogram
    u32 s0 = bh[2 * t], s1 = bh[2 * t + 1];
    u32 tsum = s0 + s1;
    ts[t] = tsum; __syncthreads();
    for (int d = 1; d < 256; d <<= 1) {
        u32 v = (t >= d) ? ts[t - d] : 0;
        __syncthreads();
        ts[t] += v;
        __syncthreads();
    }
    u32 excl = ts[t] - tsum;
    boff[2 * t] = excl; boff[2 * t + 1] = excl + s0;
    bcur[2 * t] = excl; bcur[2 * t + 1] = excl + s0;
    __syncthreads();
    if (t < NB && bh[t]) bbs[t] = bsc[t] + atomicAdd(&gcur[t], bh[t]);
    if (t + 256 < NB && bh[t + 256]) bbs[t + 256] = bsc[t + 256] + atomicAdd(&gcur[t + 256], bh[t + 256]);
    __syncthreads();
#pragma unroll
    for (int j = 0; j < CHUNK / 256; j++) {
        int e = base + j * 256 + t;
        if (e < ETOT) {
            int src, dst;
            edge_decode(ei, is64, e, src, dst);
            u32 pos = atomicAdd(&bcur[dst >> 8], 1u);
            stage[pos] = (u64)src | ((u64)dst << 32);
        }
    }
    __syncthreads();
    for (int i = t; i < chunk_n; i += 256) {
        u64 pr = stage[i];
        u32 b = (u32)(pr >> 32) >> 8;
        pairs[(size_t)bbs[b] + (i - boff[b])] = pr;
    }
}

// sort within bucket + CSR offs + degree histogram; bucket bounds from local scan
__global__ __launch_bounds__(256) void sort_pass_kernel(
    const u64* __restrict__ pairs, const u32* __restrict__ gbucket,
    int* __restrict__ srcs, int* __restrict__ offs, u32* __restrict__ dcnt)
{
    __shared__ u32 nh[256];
    __shared__ u32 ns[256];
    __shared__ u32 ncur[256];
    __shared__ u32 dh[64];
    __shared__ u32 bsc[512];
    int t = threadIdx.x;
    int b = blockIdx.x;

    // local exclusive scan of gbucket
    {
        u32 g0v = (2 * t     < NB) ? gbucket[2 * t]     : 0;
        u32 g1v = (2 * t + 1 < NB) ? gbucket[2 * t + 1] : 0;
        u32 ps = g0v + g1v;
        ns[t] = ps; __syncthreads();
        for (int d = 1; d < 256; d <<= 1) {
            u32 v = (t >= d) ? ns[t - d] : 0;
            __syncthreads();
            ns[t] += v;
            __syncthreads();
        }
        u32 ex = ns[t] - ps;
        bsc[2 * t] = ex; bsc[2 * t + 1] = ex + g0v;
    }
    __syncthreads();
    u32 beg = bsc[b], endp = bsc[b + 1];

    nh[t] = 0;
    if (t < 64) dh[t] = 0;
    __syncthreads();
    for (u32 i = beg + t; i < endp; i += 256) {
        u32 dst = (u32)(pairs[i] >> 32);
        atomicAdd(&nh[dst & 255], 1u);
    }
    __syncthreads();
    u32 cnt = nh[t];
    ns[t] = cnt; __syncthreads();
    for (int d = 1; d < 256; d <<= 1) {
        u32 v = (t >= d) ? ns[t - d] : 0;
        __syncthreads();
        ns[t] += v;
        __syncthreads();
    }
    u32 excl = ns[t] - cnt;
    int id = b * 256 + t;
    if (id <= NN) offs[id] = (int)(beg + excl);
    if (id < NN) atomicAdd(&dh[cnt < 63u ? cnt : 63u], 1u);
    ncur[t] = excl;
    __syncthreads();
    if (t < 64 && dh[t]) atomicAdd(&dcnt[t], dh[t]);
    for (u32 i = beg + t; i < endp; i += 256) {
        u64 pr = pairs[i];
        u32 loc = ((u32)(pr >> 32)) & 255;
        u32 p = atomicAdd(&ncur[loc], 1u);
        srcs[beg + p] = (int)(u32)pr;
    }
}

// ---------------- degree-balance permutation (scan fused, dcur zero-init) ----------------
// Heaviest degree first: waves see 4 near-equal-degree dsts -> max(deg)~deg.
__global__ __launch_bounds__(256) void deg_perm_kernel(
    const int* __restrict__ offs, const u32* __restrict__ dcnt,
    u32* __restrict__ dcur, int* __restrict__ perm)
{
    __shared__ u32 cnt[64];
    __shared__ u32 base[64];
    __shared__ u32 sb[64];
    int t = threadIdx.x;
    if (t < 64) {
        // in-wave suffix scan of dcnt (descending-degree layout)
        u32 v = dcnt[t];
        u32 x = v;
#pragma unroll
        for (int off = 1; off < 64; off <<= 1) {
            u32 y = __shfl_down(x, off);
            if (t + off < 64) x += y;
        }
        sb[t] = x - v;   // exclusive suffix sum = global base of bucket t
        cnt[t] = 0;
    }
    __syncthreads();
    int i = blockIdx.x * 256 + t;
    int d = 0; u32 r = 0;
    bool ok = (i < NN);
    if (ok) {
        d = offs[i + 1] - offs[i];
        if (d > 63) d = 63;
        r = atomicAdd(&cnt[d], 1u);
    }
    __syncthreads();
    if (t < 64 && cnt[t]) base[t] = sb[t] + atomicAdd(&dcur[t], cnt[t]);
    __syncthreads();
    if (ok) perm[base[d] + r] = i;
}

// ---------------- MFMA GEMM (generic; used for proj & final) ----------------
__global__ __launch_bounds__(256) void mfma_gemm(
    const u16* __restrict__ A, int lda,
    const u16* __restrict__ Bt, int ldb,
    const float* __restrict__ bias,
    int nrows, int ksteps, int ncols,
    float* __restrict__ outF, u16* __restrict__ outB, u16* __restrict__ outB2, int ldo,
    int mode, const int* __restrict__ flags)
{
    int lane = threadIdx.x & 63;
    int wv = threadIdx.x >> 6;
    int wx = wv & 1, wy = wv >> 1;
    int l16 = lane & 15, quad = lane >> 4;
    int r0 = blockIdx.x * 128 + wx * 64;
    int n0 = wy * 64;

    Bt += (size_t)blockIdx.y * 128 * ldb;
    if (blockIdx.y) outB = outB2;

    f32x4 acc[4][4];
#pragma unroll
    for (int m = 0; m < 4; m++)
#pragma unroll
        for (int n = 0; n < 4; n++) acc[m][n] = (f32x4){0.f, 0.f, 0.f, 0.f};

    const u16* Ap = A + (size_t)(r0 + l16) * lda + quad * 8;
    const u16* Bp = Bt + (size_t)(n0 + l16) * ldb + quad * 8;

    for (int k = 0; k < ksteps; ++k) {
        bf16x8 af[4], bfr[4];
#pragma unroll
        for (int m = 0; m < 4; m++)
            af[m] = *(const bf16x8*)(Ap + (size_t)m * 16 * lda + k * 32);
#pragma unroll
        for (int n = 0; n < 4; n++)
            bfr[n] = *(const bf16x8*)(Bp + (size_t)n * 16 * ldb + k * 32);
#pragma unroll
        for (int m = 0; m < 4; m++)
#pragma unroll
            for (int n = 0; n < 4; n++)
                acc[m][n] = __builtin_amdgcn_mfma_f32_16x16x32_bf16(af[m], bfr[n], acc[m][n], 0, 0, 0);
    }

    int mk = mode;
    if (mk < 0) mk = flags[1] ? 2 : 1;

#pragma unroll
    for (int m = 0; m < 4; m++) {
#pragma unroll
        for (int n = 0; n < 4; n++) {
            int col = n0 + n * 16 + l16;
            float bb = (bias != nullptr && col < ncols) ? bias[col] : 0.f;
#pragma unroll
            for (int reg = 0; reg < 4; reg++) {
                int row = r0 + m * 16 + quad * 4 + reg;
                if (row < nrows && col < ncols) {
                    float v = acc[m][n][reg] + bb;
                    if (mk & 1) outF[(size_t)row * ldo + col] = v;
                    if (mk & 2) outB[(size_t)row * ldo + col] = f2bf(v);
                }
            }
        }
    }
}

// ---------------- layer GEMM: A LDS-staged (swizzled), hl||hr in one pass ----------------
// Tile 64 rows x 256 cols. 4 waves; wave w owns cols w*64 (w<2 -> outL, else outR).
// A tile (64x128 bf16, 16KB, contiguous since lda=128) staged via global_load_lds
// with XOR-swizzled source (P = L ^ ((row&7)<<4)); fragments read with same XOR
// -> 2-way bank aliasing only (free). B read direct from global (L2-resident 64KB).
__global__ __launch_bounds__(256) void gemm_layer(
    const u16* __restrict__ A,      // [NN+64][128] bf16
    const u16* __restrict__ Bt,     // [256][128] bf16 (Wl || Wr, n-major)
    u16* __restrict__ outL, u16* __restrict__ outR)
{
    __shared__ u16 Atile[64 * 128];   // 16KB, physically swizzled
    int t = threadIdx.x;
    int wv = t >> 6, lane = t & 63;
    int l16 = lane & 15, quad = lane >> 4;
    int r0 = blockIdx.x * 64;

    // stage A rows r0..r0+63 (one contiguous 16KB region)
    {
        const char* Ab = (const char*)(A + (size_t)r0 * 128);
        char* Lb = (char*)Atile + wv * 4096;
        u32 baseP = (u32)(wv * 4096) + (u32)lane * 16;
#pragma unroll
        for (int j = 0; j < 4; j++) {
            u32 P = baseP + (u32)(j * 1024);
            u32 row = P >> 8;
            u32 L = P ^ ((row & 7u) << 4);
            gload_lds16(Ab + L, Lb + j * 1024);
        }
    }

    f32x4 acc[4][4];
#pragma unroll
    for (int m = 0; m < 4; m++)
#pragma unroll
        for (int n = 0; n < 4; n++) acc[m][n] = (f32x4){0.f, 0.f, 0.f, 0.f};

    int n0 = wv * 64;
    const u16* Bp = Bt + (size_t)(n0 + l16) * 128 + quad * 8;
    const char* At = (const char*)Atile;

    __syncthreads();   // global_load_lds drained by compiler's vmcnt before barrier

#pragma unroll
    for (int k = 0; k < 4; k++) {
        bf16x8 af[4], bfr[4];
#pragma unroll
        for (int n = 0; n < 4; n++)
            bfr[n] = *(const bf16x8*)(Bp + (size_t)n * 16 * 128 + k * 32);
#pragma unroll
        for (int m = 0; m < 4; m++) {
            u32 arow = (u32)(m * 16 + l16);
            u32 Lb = arow * 256 + (u32)(quad * 16 + k * 64);
            u32 Pb = Lb ^ ((arow & 7u) << 4);
            af[m] = *(const bf16x8*)(At + Pb);
        }
#pragma unroll
        for (int m = 0; m < 4; m++)
#pragma unroll
            for (int n = 0; n < 4; n++)
                acc[m][n] = __builtin_amdgcn_mfma_f32_16x16x32_bf16(af[m], bfr[n], acc[m][n], 0, 0, 0);
    }

    u16* outp = (wv < 2) ? outL : outR;
    int nb = n0 & 127;
#pragma unroll
    for (int m = 0; m < 4; m++) {
#pragma unroll
        for (int n = 0; n < 4; n++) {
            int col = nb + n * 16 + l16;
#pragma unroll
            for (int reg = 0; reg < 4; reg++) {
                int row = r0 + m * 16 + quad * 4 + reg;
                if (row < NN)
                    outp[(size_t)row * 128 + col] = f2bf(acc[m][n][reg]);
            }
        }
    }
}

// ---------------- fused GATv2 agg + bias + GELU + residual + LayerNorm ----------------
// 4 dst per wave (sub = lane>>4), lane r = lane&15 owns ch r*8..r*8+7.
// dsts via degree-sorted perm (wave's 4 dsts near-equal degree -> max(deg)~deg).
// Distance-1 prefetch (proven 44-VGPR body). att pre-scaled by log2(e) so
// exp is a bare v_exp_f32; hl gathers via u32 byte offsets.
__global__ __launch_bounds__(256) void gat_agg_kernel(
    const u16* __restrict__ hl, const u16* __restrict__ hr, const u16* __restrict__ hresb,
    const float* __restrict__ att, const float* __restrict__ bias,
    const float* __restrict__ gamma, const float* __restrict__ beta,
    const int* __restrict__ offs, const int* __restrict__ srcs,
    const int* __restrict__ perm,
    u16* __restrict__ outb)
{
    int lane = threadIdx.x & 63;
    int sub = lane >> 4;
    int r = lane & 15;
    int c0 = r * 8;
    u32 cb = (u32)(r << 4);              // byte offset of this lane's 8 ch (16 B)
    int id = (blockIdx.x * 4 + (threadIdx.x >> 6)) * 4 + sub;   // grid = NN/16 blocks
    int dst = perm[id];

    int start = offs[dst];
    int deg = offs[dst + 1] - start;    // >= 1 (self loop)
    int dm = deg - 1;
    const char* hlc = (const char*)hl;

    f32x2 hr2[4], av2[4];
    {
        uint4 q = *(const uint4*)((const char*)hr + ((u32)dst << 8) + cb);
        hr2[0] = unpk(q.x); hr2[1] = unpk(q.y); hr2[2] = unpk(q.z); hr2[3] = unpk(q.w);
        const float L2E = 1.4426950408889634f;   // logits scaled so exp(x) = exp2(x*L2E)
        float4 a0 = *(const float4*)&att[c0];
        float4 a1 = *(const float4*)&att[c0 + 4];
        av2[0] = (f32x2){L2E * a0.x, L2E * a0.y}; av2[1] = (f32x2){L2E * a0.z, L2E * a0.w};
        av2[2] = (f32x2){L2E * a1.x, L2E * a1.y}; av2[3] = (f32x2){L2E * a1.z, L2E * a1.w};
    }

    // wave-uniform iteration bound = max deg over the 4 sub-groups (~deg after perm)
    int md = deg;
    md = max(md, __shfl_xor(md, 16));
    md = max(md, __shfl_xor(md, 32));

    f32x2 acc2[4];
#pragma unroll
    for (int i = 0; i < 4; i++) acc2[i] = (f32x2){0.f, 0.f};
    float s = 0.f;

    // prefetch: edges 0,1 rows; srcs for edges 2,3
    int sa = srcs[start];
    int sb = srcs[start + (1 < dm ? 1 : dm)];
    uint4 qa = *(const uint4*)(hlc + ((u32)sa << 8) + cb);
    uint4 qb = *(const uint4*)(hlc + ((u32)sb << 8) + cb);
    int sna = srcs[start + (2 < dm ? 2 : dm)];
    int snb = srcs[start + (3 < dm ? 3 : dm)];

    int mi = (md + 1) >> 1;
    for (int j = 0; j < mi; ++j) {
        // srcs for iteration j+2 (edges 2j+4, 2j+5)
        int e4 = 2 * j + 4, e5 = 2 * j + 5;
        int sna2 = srcs[start + min(e4, dm)];
        int snb2 = srcs[start + min(e5, dm)];
        // rows for iteration j+1
        uint4 qna = *(const uint4*)(hlc + ((u32)sna << 8) + cb);
        uint4 qnb = *(const uint4*)(hlc + ((u32)snb << 8) + cb);

        f32x2 ha[4], hb[4];
        ha[0] = unpk(qa.x); ha[1] = unpk(qa.y); ha[2] = unpk(qa.z); ha[3] = unpk(qa.w);
        hb[0] = unpk(qb.x); hb[1] = unpk(qb.y); hb[2] = unpk(qb.z); hb[3] = unpk(qb.w);
        f32x2 pa2 = (f32x2){0.f, 0.f};
        f32x2 pb2 = (f32x2){0.f, 0.f};
#pragma unroll
        for (int i = 0; i < 4; i++) {
            f32x2 za = ha[i] + hr2[i];
            f32x2 zb = hb[i] + hr2[i];
            f32x2 la = __builtin_elementwise_max(za, za * 0.2f);
            f32x2 lb = __builtin_elementwise_max(zb, zb * 0.2f);
            pa2 = __builtin_elementwise_fma(av2[i], la, pa2);
            pb2 = __builtin_elementwise_fma(av2[i], lb, pb2);
        }
        float pa = pa2.x + pa2.y;
        float pb = pb2.x + pb2.y;
        pa += __shfl_xor(pa, 1); pb += __shfl_xor(pb, 1);
        pa += __shfl_xor(pa, 2); pb += __shfl_xor(pb, 2);
        int e0 = 2 * j, e1 = 2 * j + 1;
        float wa = (e0 < deg) ? exp2_hw(pa) : 0.f;
        float wb = (e1 < deg) ? exp2_hw(pb) : 0.f;
        s += wa + wb;
        f32x2 wa2 = (f32x2){wa, wa};
        f32x2 wb2 = (f32x2){wb, wb};
#pragma unroll
        for (int i = 0; i < 4; i++)
            acc2[i] = __builtin_elementwise_fma(wa2, ha[i],
                      __builtin_elementwise_fma(wb2, hb[i], acc2[i]));

        qa = qna; qb = qnb; sna = sna2; snb = snb2;
    }

    float inv = 1.f / s;
    float v[8];
    {
        float4 b0 = *(const float4*)&bias[c0];
        float4 b1 = *(const float4*)&bias[c0 + 4];
        float bb[8] = {b0.x,b0.y,b0.z,b0.w,b1.x,b1.y,b1.z,b1.w};
        uint4 qr = *(const uint4*)((const char*)hresb + ((u32)dst << 8) + cb);
        f32x2 rr2[4] = {unpk(qr.x), unpk(qr.y), unpk(qr.z), unpk(qr.w)};
#pragma unroll
        for (int i = 0; i < 4; i++) {
            float t0 = fmaf(acc2[i].x, inv, bb[2*i]);
            float t1 = fmaf(acc2[i].y, inv, bb[2*i+1]);
            v[2*i]   = gelu_t(t0) + rr2[i].x;
            v[2*i+1] = gelu_t(t1) + rr2[i].y;
        }
    }

    // LayerNorm over 128 ch = 16 lanes of this sub-group (offsets 1..8 stay in-group)
    float s1 = 0.f, s2 = 0.f;
#pragma unroll
    for (int k = 0; k < 8; k++) { s1 += v[k]; s2 = fmaf(v[k], v[k], s2); }
#pragma unroll
    for (int off = 1; off < 16; off <<= 1) {
        s1 += __shfl_xor(s1, off);
        s2 += __shfl_xor(s2, off);
    }
    float mu  = s1 * (1.f / 128.f);
    float var = s2 * (1.f / 128.f) - mu * mu;
    float rstd = rsqrtf(var + 1e-5f);

    float4 g0 = *(const float4*)&gamma[c0];
    float4 g1 = *(const float4*)&gamma[c0 + 4];
    float4 be0 = *(const float4*)&beta[c0];
    float4 be1 = *(const float4*)&beta[c0 + 4];
    float gg[8] = {g0.x,g0.y,g0.z,g0.w,g1.x,g1.y,g1.z,g1.w};
    float eb[8] = {be0.x,be0.y,be0.z,be0.w,be1.x,be1.y,be1.z,be1.w};
    float o[8];
#pragma unroll
    for (int k = 0; k < 8; k++) o[k] = fmaf((v[k] - mu) * rstd, gg[k], eb[k]);
    uint4 pk;
    pk.x = (u32)f2bf(o[0]) | ((u32)f2bf(o[1]) << 16);
    pk.y = (u32)f2bf(o[2]) | ((u32)f2bf(o[3]) << 16);
    pk.z = (u32)f2bf(o[4]) | ((u32)f2bf(o[5]) << 16);
    pk.w = (u32)f2bf(o[6]) | ((u32)f2bf(o[7]) << 16);
    *(uint4*)((char*)outb + ((u32)dst << 8) + cb) = pk;
}

// ---------------- launch ----------------
extern "C" void kernel_launch(void* const* d_in, const int* in_sizes, int n_in,
                              void* d_out, int out_size, void* d_ws, size_t ws_size,
                              hipStream_t stream) {
    const void* x  = d_in[0];
    const int*  ei = (const int*)d_in[1];

    char* ws = (char*)d_ws;
    size_t off = 0;
    auto alloc = [&](size_t bytes) -> void* {
        void* p = ws + off;
        off = (off + bytes + 511) & ~(size_t)511;
        return p;
    };
    u16*   xb      = (u16*)  alloc(((size_t)NN * MM + 8192) * 2);
    float* wv      = (float*)alloc((size_t)VTOT * 4);
    u16*   wbf     = (u16*)  alloc((size_t)BTOT * 2);
    u16*   h0b     = (u16*)  alloc((size_t)(NN + 64) * HID * 2);
    u16*   h1b     = (u16*)  alloc((size_t)(NN + 64) * HID * 2);
    u16*   hlb     = (u16*)  alloc((size_t)(NN + 64) * HID * 2);
    u16*   hrb     = (u16*)  alloc((size_t)(NN + 64) * HID * 2);
    int*   offs    = (int*)  alloc((size_t)(NN + 1) * 4);
    u32*   gbucket = (u32*)  alloc(512 * 4);
    u32*   gcur    = (u32*)  alloc(512 * 4);
    int*   flags   = (int*)  alloc(512);
    int*   srcs    = (int*)  alloc(((size_t)ETOT + 64) * 4);
    u64*   pairs   = (u64*)  alloc((size_t)ETOT * 8);
    u32*   dcnt    = (u32*)  alloc(64 * 4);
    u32*   dcur    = (u32*)  alloc(64 * 4);
    int*   perm    = (int*)  alloc((size_t)NN * 4);

    // fused prep: sniff + zero(gbucket,gcur,dcnt,dcur) + normx + norm_vec + norm_wt
    prep_kernel<<<1 + NXB + NVB + NWB, 256, 0, stream>>>(
        x, (const u32*)ei,
        d_in[3], d_in[6], d_in[7], d_in[12], d_in[13], d_in[10], d_in[11], d_in[14], d_in[15], d_in[17],
        d_in[2], d_in[4], d_in[5], d_in[8], d_in[9], d_in[16],
        xb, wv, wbf, flags, gbucket, dcnt, gcur, dcur);

    const int EB = (ETOT + CHUNK - 1) / CHUNK;  // 416
    bucket_hist_kernel<<<EB, 256, 0, stream>>>(ei, flags, gbucket);
    bin_pass_kernel<<<EB, 256, 0, stream>>>(ei, flags, gbucket, gcur, pairs);
    sort_pass_kernel<<<NB, 256, 0, stream>>>(pairs, gbucket, srcs, offs, dcnt);

    // degree-balance permutation (scan fused; heaviest degree first)
    deg_perm_kernel<<<NB, 256, 0, stream>>>(offs, dcnt, dcur, perm);

    const int GB = (NN + 127) / 128;  // 782
    const int LB = (NN + 63) / 64;    // 1563 (64-row tiles, layer gemm)
    const int AB = NN / 16;           // 6250 blocks, 4 dst/wave x 4 waves

    // proj: h0b = bf16(x @ Wp + bp)   (K=40 padded to 64)
    mfma_gemm<<<dim3(GB, 1), 256, 0, stream>>>(xb, MM, wbf + BWp, 64, wv + Vbp,
                                               NN, 2, HID, nullptr, h0b, nullptr, HID, 2, flags);

    // layer 1: hl/hr in one LDS-staged dispatch
    gemm_layer<<<LB, 256, 0, stream>>>(h0b, wbf + BW1l, hlb, hrb);
    gat_agg_kernel<<<AB, 256, 0, stream>>>(hlb, hrb, h0b, wv + Vatt1, wv + Vb1,
                                           wv + Vg1, wv + Vbe1, offs, srcs, perm, h1b);

    // layer 2
    gemm_layer<<<LB, 256, 0, stream>>>(h1b, wbf + BW2l, hlb, hrb);
    gat_agg_kernel<<<AB, 256, 0, stream>>>(hlb, hrb, h1b, wv + Vatt2, wv + Vb2,
                                           wv + Vg2, wv + Vbe2, offs, srcs, perm, h0b);

    // final: out = h @ Wo + bo (dtype per flags)
    mfma_gemm<<<dim3(GB, 1), 256, 0, stream>>>(h0b, HID, wbf + BWo, HID, wv + Vbo,
                                               NN, 4, LAT, (float*)d_out, (u16*)d_out, nullptr, LAT, -1, flags);
}

// Round 8
// 401.380 us; speedup vs baseline: 1.2779x; 1.0444x over previous
//
#include <hip/hip_runtime.h>
#include <hip/hip_bf16.h>
#include <math.h>

#define NN   100000
#define EE   1600000
#define ETOT 1700000   // EE + NN self loops
#define MM   40
#define HID  128
#define LAT  64
#define NB   391       // ceil(NN/256) buckets of 256 nodes
#define CHUNK 4096     // edges per bin_pass block

typedef unsigned short u16;
typedef unsigned int   u32;
typedef unsigned long long u64;

typedef __attribute__((ext_vector_type(8))) short bf16x8;
typedef __attribute__((ext_vector_type(4))) float f32x4;
typedef __attribute__((ext_vector_type(2))) float f32x2;

__device__ __forceinline__ float bf2f(u16 a) {
    return __uint_as_float(((u32)a) << 16);
}
__device__ __forceinline__ u16 f2bf(float f) {
    u32 u = __float_as_uint(f);
    u32 r = (u + 0x7fffu + ((u >> 16) & 1u)) >> 16;
    return (u16)r;
}
__device__ __forceinline__ f32x2 unpk(u32 u) {
    f32x2 r;
    r.x = __uint_as_float(u << 16);
    r.y = __uint_as_float(u & 0xffff0000u);
    return r;
}
// bare v_exp_f32: D = 2^S0 (input pre-scaled by log2(e) where e^x is wanted)
__device__ __forceinline__ float exp2_hw(float x) {
    float d;
    asm("v_exp_f32 %0, %1" : "=v"(d) : "v"(x));
    return d;
}
// async global->LDS, 16B per lane (dest = wave-uniform base + lane*16)
__device__ __forceinline__ void gload_lds16(const void* g, void* l) {
    __builtin_amdgcn_global_load_lds(
        (const __attribute__((address_space(1))) void*)g,
        (__attribute__((address_space(3))) void*)l, 16, 0, 0);
}
// tanh-form GELU via sigmoid: x * sigmoid(1.595769x + 0.0713548x^3); |err vs exact| <= ~3e-4
__device__ __forceinline__ float gelu_t(float x) {
    float x2 = x * x;
    float y = x * fmaf(0.0713548162726f, x2, 1.59576912161f);
    return x / (1.f + __expf(-y));
}

// f32 vector pack offsets (floats)
#define Vbp   0
#define Vatt1 128
#define Vb1   256
#define Vg1   384
#define Vbe1  512
#define Vatt2 640
#define Vb2   768
#define Vg2   896
#define Vbe2  1024
#define Vbo   1152
#define VTOT  1216

// bf16 transposed weight pack offsets (u16 elements)
#define BWp   0        // [128][64]  (K=40 zero-padded to 64)
#define BW1l  8192     // [128][128]
#define BW1r  24576    // adjacent to BW1l -> [256][128] panel for gemm_layer
#define BW2l  40960
#define BW2r  57344
#define BWo   73728    // [128][128] n-major; rows 64..127 zero
#define BTOT  90112

// prep_kernel block-range sizes
#define XROWS 100096   // NN rounded up to 128 (proj tile reach)
#define NXB   25000    // NN*64/256 exactly (padded-x blocks)
#define NVB   5        // ceil(VTOT/256)
#define NWB   352      // BTOT/256 exactly

// per-wave bf16-ness sniff (identical predicate to original sniff_kernel)
__device__ __forceinline__ int sniff_bf_wave(const u32* __restrict__ x_raw) {
    int lane = threadIdx.x & 63;
    u32 w = x_raw[lane];              // first 64 u32 of x
    u16 lo = (u16)(w & 0xffffu);
    int e = (lo >> 7) & 0xFF;
    int ok = (e >= 118 && e <= 133) ? 1 : 0;
    u64 b = __ballot(ok);
    return (__popcll(b) >= 48) ? 1 : 0;
}

__device__ __forceinline__ void edge_decode(const int* __restrict__ ei, int is64, int e,
                                            int& src, int& dst) {
    if (e < EE) {
        src = is64 ? ei[2 * e] : ei[e];
        int idx = EE + e;
        dst = is64 ? ei[2 * idx] : ei[idx];
    } else {
        src = e - EE; dst = src;
    }
}

// ---------------- fused prep: sniff + zero + normx(pad64) + norm_vec + norm_wt ----------------
__global__ __launch_bounds__(256) void prep_kernel(
    const void* __restrict__ x, const u32* __restrict__ ei_raw,
    const void* p0, const void* p1, const void* p2, const void* p3, const void* p4,
    const void* p5, const void* p6, const void* p7, const void* p8, const void* p9,
    const void* w0, const void* w1, const void* w2, const void* w3, const void* w4,
    const void* w5,
    u16* __restrict__ xb, float* __restrict__ wv, u16* __restrict__ wbf,
    int* __restrict__ flags, u32* __restrict__ gbucket, u32* __restrict__ dcnt,
    u32* __restrict__ gcur, u32* __restrict__ dcur)
{
    const u32* x_raw = (const u32*)x;
    int isbf = sniff_bf_wave(x_raw);
    int t = threadIdx.x;
    int b = blockIdx.x;

    if (b == 0) {
        // is64 sniff: all odd u32 in [1,255] zero -> int64 edge index
        if (t < 64) {
            u32 a = ei_raw[2 * t + 1] | ei_raw[129 + 2 * t];
            u64 nz = __ballot(a != 0u);
            if (t == 0) { flags[0] = (nz == 0uLL) ? 1 : 0; flags[1] = isbf; }
        }
        gbucket[t] = 0; gbucket[t + 256] = 0;
        gcur[t] = 0;    gcur[t + 256] = 0;
        if (t < 64) { dcnt[t] = 0; dcur[t] = 0; }
        return;
    }
    if (b <= NXB) {
        // normx: x[NN][40] -> xb[NN][64] bf16 (zeros k>=40; contiguous 128B rows)
        int i = (b - 1) * 256 + t;   // i < NN*64 exactly
        int row = i >> 6, k = i & 63;
        u16 v = 0;
        if (k < MM) {
            int src = row * MM + k;
            v = isbf ? ((const u16*)x)[src] : f2bf(((const float*)x)[src]);
        }
        xb[i] = v;
        return;
    }
    if (b <= NXB + NVB) {
        int i = (b - 1 - NXB) * 256 + t;
        if (i >= VTOT) return;
        const int offs[11] = {Vbp, Vatt1, Vb1, Vg1, Vbe1, Vatt2, Vb2, Vg2, Vbe2, Vbo, VTOT};
        const void* ps[10] = {p0,p1,p2,p3,p4,p5,p6,p7,p8,p9};
        int s = 0;
#pragma unroll
        for (int k = 1; k < 10; k++) s += (i >= offs[k]) ? 1 : 0;
        int j = i - offs[s];
        const void* p = ps[s];
        wv[i] = isbf ? bf2f(((const u16*)p)[j]) : ((const float*)p)[j];
        return;
    }
    {
        int i = (b - 1 - NXB - NVB) * 256 + t;   // grid sized exactly: i < BTOT
        const int offs[7] = {BWp, BW1l, BW1r, BW2l, BW2r, BWo, BTOT};
        const int Ks[6]   = {40, 128, 128, 128, 128, 128};
        const int Ncs[6]  = {128, 128, 128, 128, 128, 64};
        const int Kps[6]  = {64, 128, 128, 128, 128, 128};
        const void* ps[6] = {w0,w1,w2,w3,w4,w5};
        int s = 0;
#pragma unroll
        for (int k = 1; k < 6; k++) s += (i >= offs[k]) ? 1 : 0;
        int j = i - offs[s];
        int Kp = Kps[s];
        int n = j / Kp, k = j % Kp;
        u16 v = 0;
        if (k < Ks[s] && n < Ncs[s]) {
            const void* p = ps[s];
            int src = k * Ncs[s] + n;
            v = isbf ? ((const u16*)p)[src] : f2bf(((const float*)p)[src]);
        }
        wbf[i] = v;
    }
}

// ---------------- CSR build: 2-pass LDS-binned counting sort ----------------
__global__ __launch_bounds__(256) void bucket_hist_kernel(
    const int* __restrict__ ei, const int* __restrict__ flags, u32* __restrict__ gbucket)
{
    __shared__ u32 h[512];
    int t = threadIdx.x;
    h[t] = 0; h[t + 256] = 0;
    __syncthreads();
    int is64 = flags[0];
    int base = blockIdx.x * CHUNK;
#pragma unroll
    for (int j = 0; j < CHUNK / 256; j++) {
        int e = base + j * 256 + t;
        if (e < ETOT) {
            int src, dst;
            edge_decode(ei, is64, e, src, dst);
            atomicAdd(&h[dst >> 8], 1u);
        }
    }
    __syncthreads();
    if (h[t])       atomicAdd(&gbucket[t], h[t]);
    if (h[t + 256]) atomicAdd(&gbucket[t + 256], h[t + 256]);
}

// bin_pass: local gbucket scan; edges decoded ONCE into registers and reused.
__global__ __launch_bounds__(256) void bin_pass_kernel(
    const int* __restrict__ ei, const int* __restrict__ flags,
    const u32* __restrict__ gbucket, u32* __restrict__ gcur, u64* __restrict__ pairs)
{
    __shared__ u32 bh[512];
    __shared__ u32 boff[512];
    __shared__ u32 bbs[512];
    __shared__ u32 bcur[512];
    __shared__ u32 bsc[512];
    __shared__ u64 stage[CHUNK];
    __shared__ u32 ts[256];

    int t = threadIdx.x;
    bh[t] = 0; bh[t + 256] = 0;
    __syncthreads();
    int is64 = flags[0];
    int base = blockIdx.x * CHUNK;
    int chunk_n = ETOT - base; if (chunk_n > CHUNK) chunk_n = CHUNK;

    u64 epk[CHUNK / 256];   // decoded edges cached in registers
#pragma unroll
    for (int j = 0; j < CHUNK / 256; j++) {
        int e = base + j * 256 + t;
        if (e < ETOT) {
            int src, dst;
            edge_decode(ei, is64, e, src, dst);
            epk[j] = (u64)(u32)src | ((u64)(u32)dst << 32);
            atomicAdd(&bh[dst >> 8], 1u);
        }
    }
    __syncthreads();

    // local exclusive scan of gbucket -> bsc (replaces global bucket_scan)
    {
        u32 g0v = (2 * t     < NB) ? gbucket[2 * t]     : 0;
        u32 g1v = (2 * t + 1 < NB) ? gbucket[2 * t + 1] : 0;
        u32 ps = g0v + g1v;
        ts[t] = ps; __syncthreads();
        for (int d = 1; d < 256; d <<= 1) {
            u32 v = (t >= d) ? ts[t - d] : 0;
            __syncthreads();
            ts[t] += v;
            __syncthreads();
        }
        u32 ex = ts[t] - ps;
        bsc[2 * t] = ex; bsc[2 * t + 1] = ex + g0v;
    }
    __syncthreads();

    // local scan of block histogram
    u32 s0 = bh[2 * t], s1 = bh[2 * t + 1];
    u32 tsum = s0 + s1;
    ts[t] = tsum; __syncthreads();
    for (int d = 1; d < 256; d <<= 1) {
        u32 v = (t >= d) ? ts[t - d] : 0;
        __syncthreads();
        ts[t] += v;
        __syncthreads();
    }
    u32 excl = ts[t] - tsum;
    boff[2 * t] = excl; boff[2 * t + 1] = excl + s0;
    bcur[2 * t] = excl; bcur[2 * t + 1] = excl + s0;
    __syncthreads();
    if (t < NB && bh[t]) bbs[t] = bsc[t] + atomicAdd(&gcur[t], bh[t]);
    if (t + 256 < NB && bh[t + 256]) bbs[t + 256] = bsc[t + 256] + atomicAdd(&gcur[t + 256], bh[t + 256]);
    __syncthreads();
#pragma unroll
    for (int j = 0; j < CHUNK / 256; j++) {
        int e = base + j * 256 + t;
        if (e < ETOT) {
            u64 pr = epk[j];
            u32 pos = atomicAdd(&bcur[(u32)(pr >> 32) >> 8], 1u);
            stage[pos] = pr;
        }
    }
    __syncthreads();
    for (int i = t; i < chunk_n; i += 256) {
        u64 pr = stage[i];
        u32 b = (u32)(pr >> 32) >> 8;
        pairs[(size_t)bbs[b] + (i - boff[b])] = pr;
    }
}

// sort within bucket + CSR offs + degree histogram; bucket bounds from local scan
__global__ __launch_bounds__(256) void sort_pass_kernel(
    const u64* __restrict__ pairs, const u32* __restrict__ gbucket,
    int* __restrict__ srcs, int* __restrict__ offs, u32* __restrict__ dcnt)
{
    __shared__ u32 nh[256];
    __shared__ u32 ns[256];
    __shared__ u32 ncur[256];
    __shared__ u32 dh[64];
    __shared__ u32 bsc[512];
    int t = threadIdx.x;
    int b = blockIdx.x;

    // local exclusive scan of gbucket
    {
        u32 g0v = (2 * t     < NB) ? gbucket[2 * t]     : 0;
        u32 g1v = (2 * t + 1 < NB) ? gbucket[2 * t + 1] : 0;
        u32 ps = g0v + g1v;
        ns[t] = ps; __syncthreads();
        for (int d = 1; d < 256; d <<= 1) {
            u32 v = (t >= d) ? ns[t - d] : 0;
            __syncthreads();
            ns[t] += v;
            __syncthreads();
        }
        u32 ex = ns[t] - ps;
        bsc[2 * t] = ex; bsc[2 * t + 1] = ex + g0v;
    }
    __syncthreads();
    u32 beg = bsc[b], endp = bsc[b + 1];

    nh[t] = 0;
    if (t < 64) dh[t] = 0;
    __syncthreads();
    for (u32 i = beg + t; i < endp; i += 256) {
        u32 dst = (u32)(pairs[i] >> 32);
        atomicAdd(&nh[dst & 255], 1u);
    }
    __syncthreads();
    u32 cnt = nh[t];
    ns[t] = cnt; __syncthreads();
    for (int d = 1; d < 256; d <<= 1) {
        u32 v = (t >= d) ? ns[t - d] : 0;
        __syncthreads();
        ns[t] += v;
        __syncthreads();
    }
    u32 excl = ns[t] - cnt;
    int id = b * 256 + t;
    if (id <= NN) offs[id] = (int)(beg + excl);
    if (id < NN) atomicAdd(&dh[cnt < 63u ? cnt : 63u], 1u);
    ncur[t] = excl;
    __syncthreads();
    if (t < 64 && dh[t]) atomicAdd(&dcnt[t], dh[t]);
    for (u32 i = beg + t; i < endp; i += 256) {
        u64 pr = pairs[i];
        u32 loc = ((u32)(pr >> 32)) & 255;
        u32 p = atomicAdd(&ncur[loc], 1u);
        srcs[beg + p] = (int)(u32)pr;
    }
}

// ---------------- degree-balance permutation (scan fused, dcur zero-init) ----------------
// Heaviest degree first: waves see 4 near-equal-degree dsts -> max(deg)~deg.
__global__ __launch_bounds__(256) void deg_perm_kernel(
    const int* __restrict__ offs, const u32* __restrict__ dcnt,
    u32* __restrict__ dcur, int* __restrict__ perm)
{
    __shared__ u32 cnt[64];
    __shared__ u32 base[64];
    __shared__ u32 sb[64];
    int t = threadIdx.x;
    if (t < 64) {
        // in-wave suffix scan of dcnt (descending-degree layout)
        u32 v = dcnt[t];
        u32 x = v;
#pragma unroll
        for (int off = 1; off < 64; off <<= 1) {
            u32 y = __shfl_down(x, off);
            if (t + off < 64) x += y;
        }
        sb[t] = x - v;   // exclusive suffix sum = global base of bucket t
        cnt[t] = 0;
    }
    __syncthreads();
    int i = blockIdx.x * 256 + t;
    int d = 0; u32 r = 0;
    bool ok = (i < NN);
    if (ok) {
        d = offs[i + 1] - offs[i];
        if (d > 63) d = 63;
        r = atomicAdd(&cnt[d], 1u);
    }
    __syncthreads();
    if (t < 64 && cnt[t]) base[t] = sb[t] + atomicAdd(&dcur[t], cnt[t]);
    __syncthreads();
    if (ok) perm[base[d] + r] = i;
}

// ---------------- proj GEMM: xb[NN][64] @ Wp -> h0b[NN][128], LDS-staged A ----------------
// Tile 128 rows x 128 cols; 4 waves (wx=row half, wy=col half). A tile 16KB,
// swizzle P^((row&7)<<4) with row=P>>7 (128B rows). K=2 (zeros pre-padded).
__global__ __launch_bounds__(256) void gemm_proj(
    const u16* __restrict__ A,      // [XROWS][64] bf16
    const u16* __restrict__ Bt,     // [128][64] bf16
    const float* __restrict__ bias, // [128]
    u16* __restrict__ outB)         // [NN][128] bf16
{
    __shared__ u16 Atile[128 * 64];   // 16KB swizzled
    int t = threadIdx.x;
    int wv = t >> 6, lane = t & 63;
    int wx = wv & 1, wy = wv >> 1;
    int l16 = lane & 15, quad = lane >> 4;
    int r0 = blockIdx.x * 128;

    {
        const char* Ab = (const char*)(A + (size_t)r0 * 64);
        char* Lb = (char*)Atile + wv * 4096;
        u32 baseP = (u32)(wv * 4096) + (u32)lane * 16;
#pragma unroll
        for (int j = 0; j < 4; j++) {
            u32 P = baseP + (u32)(j * 1024);
            u32 row = P >> 7;
            u32 L = P ^ ((row & 7u) << 4);
            gload_lds16(Ab + L, Lb + j * 1024);
        }
    }

    f32x4 acc[4][4];
#pragma unroll
    for (int m = 0; m < 4; m++)
#pragma unroll
        for (int n = 0; n < 4; n++) acc[m][n] = (f32x4){0.f, 0.f, 0.f, 0.f};

    int n0 = wy * 64;
    const u16* Bp = Bt + (size_t)(n0 + l16) * 64 + quad * 8;
    const char* At = (const char*)Atile;

    __syncthreads();

#pragma unroll
    for (int k = 0; k < 2; k++) {
        bf16x8 af[4], bfr[4];
#pragma unroll
        for (int n = 0; n < 4; n++)
            bfr[n] = *(const bf16x8*)(Bp + (size_t)n * 16 * 64 + k * 32);
#pragma unroll
        for (int m = 0; m < 4; m++) {
            u32 arow = (u32)(wx * 64 + m * 16 + l16);
            u32 Lb = arow * 128 + (u32)(quad * 16 + k * 64);
            u32 Pb = Lb ^ ((arow & 7u) << 4);
            af[m] = *(const bf16x8*)(At + Pb);
        }
#pragma unroll
        for (int m = 0; m < 4; m++)
#pragma unroll
            for (int n = 0; n < 4; n++)
                acc[m][n] = __builtin_amdgcn_mfma_f32_16x16x32_bf16(af[m], bfr[n], acc[m][n], 0, 0, 0);
    }

#pragma unroll
    for (int m = 0; m < 4; m++) {
#pragma unroll
        for (int n = 0; n < 4; n++) {
            int col = n0 + n * 16 + l16;
            float bb = bias[col];
#pragma unroll
            for (int reg = 0; reg < 4; reg++) {
                int row = r0 + wx * 64 + m * 16 + quad * 4 + reg;
                if (row < NN)
                    outB[(size_t)row * 128 + col] = f2bf(acc[m][n][reg] + bb);
            }
        }
    }
}

// ---------------- layer GEMM: A LDS-staged (swizzled), hl||hr in one pass ----------------
// Tile 64 rows x 256 cols. 4 waves; wave w owns cols w*64 (w<2 -> outL, else outR).
__global__ __launch_bounds__(256) void gemm_layer(
    const u16* __restrict__ A,      // [NN+128][128] bf16
    const u16* __restrict__ Bt,     // [256][128] bf16 (Wl || Wr, n-major)
    u16* __restrict__ outL, u16* __restrict__ outR)
{
    __shared__ u16 Atile[64 * 128];   // 16KB, physically swizzled
    int t = threadIdx.x;
    int wv = t >> 6, lane = t & 63;
    int l16 = lane & 15, quad = lane >> 4;
    int r0 = blockIdx.x * 64;

    // stage A rows r0..r0+63 (one contiguous 16KB region)
    {
        const char* Ab = (const char*)(A + (size_t)r0 * 128);
        char* Lb = (char*)Atile + wv * 4096;
        u32 baseP = (u32)(wv * 4096) + (u32)lane * 16;
#pragma unroll
        for (int j = 0; j < 4; j++) {
            u32 P = baseP + (u32)(j * 1024);
            u32 row = P >> 8;
            u32 L = P ^ ((row & 7u) << 4);
            gload_lds16(Ab + L, Lb + j * 1024);
        }
    }

    f32x4 acc[4][4];
#pragma unroll
    for (int m = 0; m < 4; m++)
#pragma unroll
        for (int n = 0; n < 4; n++) acc[m][n] = (f32x4){0.f, 0.f, 0.f, 0.f};

    int n0 = wv * 64;
    const u16* Bp = Bt + (size_t)(n0 + l16) * 128 + quad * 8;
    const char* At = (const char*)Atile;

    __syncthreads();

#pragma unroll
    for (int k = 0; k < 4; k++) {
        bf16x8 af[4], bfr[4];
#pragma unroll
        for (int n = 0; n < 4; n++)
            bfr[n] = *(const bf16x8*)(Bp + (size_t)n * 16 * 128 + k * 32);
#pragma unroll
        for (int m = 0; m < 4; m++) {
            u32 arow = (u32)(m * 16 + l16);
            u32 Lb = arow * 256 + (u32)(quad * 16 + k * 64);
            u32 Pb = Lb ^ ((arow & 7u) << 4);
            af[m] = *(const bf16x8*)(At + Pb);
        }
#pragma unroll
        for (int m = 0; m < 4; m++)
#pragma unroll
            for (int n = 0; n < 4; n++)
                acc[m][n] = __builtin_amdgcn_mfma_f32_16x16x32_bf16(af[m], bfr[n], acc[m][n], 0, 0, 0);
    }

    u16* outp = (wv < 2) ? outL : outR;
    int nb = n0 & 127;
#pragma unroll
    for (int m = 0; m < 4; m++) {
#pragma unroll
        for (int n = 0; n < 4; n++) {
            int col = nb + n * 16 + l16;
#pragma unroll
            for (int reg = 0; reg < 4; reg++) {
                int row = r0 + m * 16 + quad * 4 + reg;
                if (row < NN)
                    outp[(size_t)row * 128 + col] = f2bf(acc[m][n][reg]);
            }
        }
    }
}

// ---------------- final GEMM: h[NN][128] @ Wo -> out[NN][64], LDS-staged A ----------------
// Tile 128 rows x 64 cols; 4 waves: wx=row half (64), wy=col half (32). A tile 32KB.
__global__ __launch_bounds__(256) void gemm_final(
    const u16* __restrict__ A,      // [NN+128][128] bf16
    const u16* __restrict__ Bt,     // [128][128] bf16 (rows 64+ zero)
    const float* __restrict__ bias, // [64]
    float* __restrict__ outF, u16* __restrict__ outB,
    const int* __restrict__ flags)
{
    __shared__ u16 Atile[128 * 128];  // 32KB swizzled
    int t = threadIdx.x;
    int wv = t >> 6, lane = t & 63;
    int wx = wv & 1, wy = wv >> 1;
    int l16 = lane & 15, quad = lane >> 4;
    int r0 = blockIdx.x * 128;

    {
        const char* Ab = (const char*)(A + (size_t)r0 * 128);
        char* Lb = (char*)Atile + wv * 8192;
        u32 baseP = (u32)(wv * 8192) + (u32)lane * 16;
#pragma unroll
        for (int j = 0; j < 8; j++) {
            u32 P = baseP + (u32)(j * 1024);
            u32 row = P >> 8;
            u32 L = P ^ ((row & 7u) << 4);
            gload_lds16(Ab + L, Lb + j * 1024);
        }
    }

    f32x4 acc[4][2];
#pragma unroll
    for (int m = 0; m < 4; m++)
#pragma unroll
        for (int n = 0; n < 2; n++) acc[m][n] = (f32x4){0.f, 0.f, 0.f, 0.f};

    int n0 = wy * 32;
    const u16* Bp = Bt + (size_t)(n0 + l16) * 128 + quad * 8;
    const char* At = (const char*)Atile;

    __syncthreads();

#pragma unroll
    for (int k = 0; k < 4; k++) {
        bf16x8 af[4], bfr[2];
#pragma unroll
        for (int n = 0; n < 2; n++)
            bfr[n] = *(const bf16x8*)(Bp + (size_t)n * 16 * 128 + k * 32);
#pragma unroll
        for (int m = 0; m < 4; m++) {
            u32 arow = (u32)(wx * 64 + m * 16 + l16);
            u32 Lb = arow * 256 + (u32)(quad * 16 + k * 64);
            u32 Pb = Lb ^ ((arow & 7u) << 4);
            af[m] = *(const bf16x8*)(At + Pb);
        }
#pragma unroll
        for (int m = 0; m < 4; m++)
#pragma unroll
            for (int n = 0; n < 2; n++)
                acc[m][n] = __builtin_amdgcn_mfma_f32_16x16x32_bf16(af[m], bfr[n], acc[m][n], 0, 0, 0);
    }

    int mk = flags[1] ? 2 : 1;
#pragma unroll
    for (int m = 0; m < 4; m++) {
#pragma unroll
        for (int n = 0; n < 2; n++) {
            int col = n0 + n * 16 + l16;
            float bb = bias[col];
#pragma unroll
            for (int reg = 0; reg < 4; reg++) {
                int row = r0 + wx * 64 + m * 16 + quad * 4 + reg;
                if (row < NN) {
                    float v = acc[m][n][reg] + bb;
                    if (mk & 1) outF[(size_t)row * 64 + col] = v;
                    if (mk & 2) outB[(size_t)row * 64 + col] = f2bf(v);
                }
            }
        }
    }
}

// ---------------- fused GATv2 agg + bias + GELU + residual + LayerNorm ----------------
// 4 dst per wave (sub = lane>>4), lane r = lane&15 owns ch r*8..r*8+7.
// dsts via degree-sorted perm (wave's 4 dsts near-equal degree -> max(deg)~deg).
// Distance-1 prefetch (proven 44-VGPR body). att pre-scaled by log2(e) so
// exp is a bare v_exp_f32; hl gathers via u32 byte offsets.
__global__ __launch_bounds__(256) void gat_agg_kernel(
    const u16* __restrict__ hl, const u16* __restrict__ hr, const u16* __restrict__ hresb,
    const float* __restrict__ att, const float* __restrict__ bias,
    const float* __restrict__ gamma, const float* __restrict__ beta,
    const int* __restrict__ offs, const int* __restrict__ srcs,
    const int* __restrict__ perm,
    u16* __restrict__ outb)
{
    int lane = threadIdx.x & 63;
    int sub = lane >> 4;
    int r = lane & 15;
    int c0 = r * 8;
    u32 cb = (u32)(r << 4);              // byte offset of this lane's 8 ch (16 B)
    int id = (blockIdx.x * 4 + (threadIdx.x >> 6)) * 4 + sub;   // grid = NN/16 blocks
    int dst = perm[id];

    int start = offs[dst];
    int deg = offs[dst + 1] - start;    // >= 1 (self loop)
    int dm = deg - 1;
    const char* hlc = (const char*)hl;

    f32x2 hr2[4], av2[4];
    {
        uint4 q = *(const uint4*)((const char*)hr + ((u32)dst << 8) + cb);
        hr2[0] = unpk(q.x); hr2[1] = unpk(q.y); hr2[2] = unpk(q.z); hr2[3] = unpk(q.w);
        const float L2E = 1.4426950408889634f;   // logits scaled so exp(x) = exp2(x*L2E)
        float4 a0 = *(const float4*)&att[c0];
        float4 a1 = *(const float4*)&att[c0 + 4];
        av2[0] = (f32x2){L2E * a0.x, L2E * a0.y}; av2[1] = (f32x2){L2E * a0.z, L2E * a0.w};
        av2[2] = (f32x2){L2E * a1.x, L2E * a1.y}; av2[3] = (f32x2){L2E * a1.z, L2E * a1.w};
    }

    // wave-uniform iteration bound = max deg over the 4 sub-groups (~deg after perm)
    int md = deg;
    md = max(md, __shfl_xor(md, 16));
    md = max(md, __shfl_xor(md, 32));

    f32x2 acc2[4];
#pragma unroll
    for (int i = 0; i < 4; i++) acc2[i] = (f32x2){0.f, 0.f};
    float s = 0.f;

    // prefetch: edges 0,1 rows; srcs for edges 2,3
    int sa = srcs[start];
    int sb = srcs[start + (1 < dm ? 1 : dm)];
    uint4 qa = *(const uint4*)(hlc + ((u32)sa << 8) + cb);
    uint4 qb = *(const uint4*)(hlc + ((u32)sb << 8) + cb);
    int sna = srcs[start + (2 < dm ? 2 : dm)];
    int snb = srcs[start + (3 < dm ? 3 : dm)];

    int mi = (md + 1) >> 1;
    for (int j = 0; j < mi; ++j) {
        // srcs for iteration j+2 (edges 2j+4, 2j+5)
        int e4 = 2 * j + 4, e5 = 2 * j + 5;
        int sna2 = srcs[start + min(e4, dm)];
        int snb2 = srcs[start + min(e5, dm)];
        // rows for iteration j+1
        uint4 qna = *(const uint4*)(hlc + ((u32)sna << 8) + cb);
        uint4 qnb = *(const uint4*)(hlc + ((u32)snb << 8) + cb);

        f32x2 ha[4], hb[4];
        ha[0] = unpk(qa.x); ha[1] = unpk(qa.y); ha[2] = unpk(qa.z); ha[3] = unpk(qa.w);
        hb[0] = unpk(qb.x); hb[1] = unpk(qb.y); hb[2] = unpk(qb.z); hb[3] = unpk(qb.w);
        f32x2 pa2 = (f32x2){0.f, 0.f};
        f32x2 pb2 = (f32x2){0.f, 0.f};
#pragma unroll
        for (int i = 0; i < 4; i++) {
            f32x2 za = ha[i] + hr2[i];
            f32x2 zb = hb[i] + hr2[i];
            f32x2 la = __builtin_elementwise_max(za, za * 0.2f);
            f32x2 lb = __builtin_elementwise_max(zb, zb * 0.2f);
            pa2 = __builtin_elementwise_fma(av2[i], la, pa2);
            pb2 = __builtin_elementwise_fma(av2[i], lb, pb2);
        }
        float pa = pa2.x + pa2.y;
        float pb = pb2.x + pb2.y;
        pa += __shfl_xor(pa, 1); pb += __shfl_xor(pb, 1);
        pa += __shfl_xor(pa, 2); pb += __shfl_xor(pb, 2);
        int e0 = 2 * j, e1 = 2 * j + 1;
        float wa = (e0 < deg) ? exp2_hw(pa) : 0.f;
        float wb = (e1 < deg) ? exp2_hw(pb) : 0.f;
        s += wa + wb;
        f32x2 wa2 = (f32x2){wa, wa};
        f32x2 wb2 = (f32x2){wb, wb};
#pragma unroll
        for (int i = 0; i < 4; i++)
            acc2[i] = __builtin_elementwise_fma(wa2, ha[i],
                      __builtin_elementwise_fma(wb2, hb[i], acc2[i]));

        qa = qna; qb = qnb; sna = sna2; snb = snb2;
    }

    float inv = 1.f / s;
    float v[8];
    {
        float4 b0 = *(const float4*)&bias[c0];
        float4 b1 = *(const float4*)&bias[c0 + 4];
        float bb[8] = {b0.x,b0.y,b0.z,b0.w,b1.x,b1.y,b1.z,b1.w};
        uint4 qr = *(const uint4*)((const char*)hresb + ((u32)dst << 8) + cb);
        f32x2 rr2[4] = {unpk(qr.x), unpk(qr.y), unpk(qr.z), unpk(qr.w)};
#pragma unroll
        for (int i = 0; i < 4; i++) {
            float t0 = fmaf(acc2[i].x, inv, bb[2*i]);
            float t1 = fmaf(acc2[i].y, inv, bb[2*i+1]);
            v[2*i]   = gelu_t(t0) + rr2[i].x;
            v[2*i+1] = gelu_t(t1) + rr2[i].y;
        }
    }

    // LayerNorm over 128 ch = 16 lanes of this sub-group (offsets 1..8 stay in-group)
    float s1 = 0.f, s2 = 0.f;
#pragma unroll
    for (int k = 0; k < 8; k++) { s1 += v[k]; s2 = fmaf(v[k], v[k], s2); }
#pragma unroll
    for (int off = 1; off < 16; off <<= 1) {
        s1 += __shfl_xor(s1, off);
        s2 += __shfl_xor(s2, off);
    }
    float mu  = s1 * (1.f / 128.f);
    float var = s2 * (1.f / 128.f) - mu * mu;
    float rstd = rsqrtf(var + 1e-5f);

    float4 g0 = *(const float4*)&gamma[c0];
    float4 g1 = *(const float4*)&gamma[c0 + 4];
    float4 be0 = *(const float4*)&beta[c0];
    float4 be1 = *(const float4*)&beta[c0 + 4];
    float gg[8] = {g0.x,g0.y,g0.z,g0.w,g1.x,g1.y,g1.z,g1.w};
    float eb[8] = {be0.x,be0.y,be0.z,be0.w,be1.x,be1.y,be1.z,be1.w};
    float o[8];
#pragma unroll
    for (int k = 0; k < 8; k++) o[k] = fmaf((v[k] - mu) * rstd, gg[k], eb[k]);
    uint4 pk;
    pk.x = (u32)f2bf(o[0]) | ((u32)f2bf(o[1]) << 16);
    pk.y = (u32)f2bf(o[2]) | ((u32)f2bf(o[3]) << 16);
    pk.z = (u32)f2bf(o[4]) | ((u32)f2bf(o[5]) << 16);
    pk.w = (u32)f2bf(o[6]) | ((u32)f2bf(o[7]) << 16);
    *(uint4*)((char*)outb + ((u32)dst << 8) + cb) = pk;
}

// ---------------- launch ----------------
extern "C" void kernel_launch(void* const* d_in, const int* in_sizes, int n_in,
                              void* d_out, int out_size, void* d_ws, size_t ws_size,
                              hipStream_t stream) {
    const void* x  = d_in[0];
    const int*  ei = (const int*)d_in[1];

    char* ws = (char*)d_ws;
    size_t off = 0;
    auto alloc = [&](size_t bytes) -> void* {
        void* p = ws + off;
        off = (off + bytes + 511) & ~(size_t)511;
        return p;
    };
    u16*   xb      = (u16*)  alloc((size_t)XROWS * 64 * 2);
    float* wv      = (float*)alloc((size_t)VTOT * 4);
    u16*   wbf     = (u16*)  alloc((size_t)BTOT * 2);
    u16*   h0b     = (u16*)  alloc((size_t)(NN + 128) * HID * 2);
    u16*   h1b     = (u16*)  alloc((size_t)(NN + 128) * HID * 2);
    u16*   hlb     = (u16*)  alloc((size_t)(NN + 128) * HID * 2);
    u16*   hrb     = (u16*)  alloc((size_t)(NN + 128) * HID * 2);
    int*   offs    = (int*)  alloc((size_t)(NN + 1) * 4);
    u32*   gbucket = (u32*)  alloc(512 * 4);
    u32*   gcur    = (u32*)  alloc(512 * 4);
    int*   flags   = (int*)  alloc(512);
    int*   srcs    = (int*)  alloc(((size_t)ETOT + 64) * 4);
    u64*   pairs   = (u64*)  alloc((size_t)ETOT * 8);
    u32*   dcnt    = (u32*)  alloc(64 * 4);
    u32*   dcur    = (u32*)  alloc(64 * 4);
    int*   perm    = (int*)  alloc((size_t)NN * 4);

    // fused prep: sniff + zero(gbucket,gcur,dcnt,dcur) + normx(pad64) + norm_vec + norm_wt
    prep_kernel<<<1 + NXB + NVB + NWB, 256, 0, stream>>>(
        x, (const u32*)ei,
        d_in[3], d_in[6], d_in[7], d_in[12], d_in[13], d_in[10], d_in[11], d_in[14], d_in[15], d_in[17],
        d_in[2], d_in[4], d_in[5], d_in[8], d_in[9], d_in[16],
        xb, wv, wbf, flags, gbucket, dcnt, gcur, dcur);

    const int EB = (ETOT + CHUNK - 1) / CHUNK;  // 416
    bucket_hist_kernel<<<EB, 256, 0, stream>>>(ei, flags, gbucket);
    bin_pass_kernel<<<EB, 256, 0, stream>>>(ei, flags, gbucket, gcur, pairs);
    sort_pass_kernel<<<NB, 256, 0, stream>>>(pairs, gbucket, srcs, offs, dcnt);

    // degree-balance permutation (scan fused; heaviest degree first)
    deg_perm_kernel<<<NB, 256, 0, stream>>>(offs, dcnt, dcur, perm);

    const int GB = (NN + 127) / 128;  // 782 (128-row tiles, proj/final)
    const int LB = (NN + 63) / 64;    // 1563 (64-row tiles, layer gemm)
    const int AB = NN / 16;           // 6250 blocks, 4 dst/wave x 4 waves

    // proj: h0b = bf16(x @ Wp + bp)
    gemm_proj<<<GB, 256, 0, stream>>>(xb, wbf + BWp, wv + Vbp, h0b);

    // layer 1: hl/hr in one LDS-staged dispatch
    gemm_layer<<<LB, 256, 0, stream>>>(h0b, wbf + BW1l, hlb, hrb);
    gat_agg_kernel<<<AB, 256, 0, stream>>>(hlb, hrb, h0b, wv + Vatt1, wv + Vb1,
                                           wv + Vg1, wv + Vbe1, offs, srcs, perm, h1b);

    // layer 2
    gemm_layer<<<LB, 256, 0, stream>>>(h1b, wbf + BW2l, hlb, hrb);
    gat_agg_kernel<<<AB, 256, 0, stream>>>(hlb, hrb, h1b, wv + Vatt2, wv + Vb2,
                                           wv + Vg2, wv + Vbe2, offs, srcs, perm, h0b);

    // final: out = h @ Wo + bo (dtype per flags)
    gemm_final<<<GB, 256, 0, stream>>>(h0b, wbf + BWo, wv + Vbo,
                                       (float*)d_out, (u16*)d_out, flags);
}

// Round 9
// 384.718 us; speedup vs baseline: 1.3332x; 1.0433x over previous
//
#include <hip/hip_runtime.h>
#include <hip/hip_bf16.h>
#include <math.h>

#define NN   100000
#define EE   1600000
#define ETOT 1700000   // EE + NN self loops
#define MM   40
#define HID  128
#define LAT  64
#define NB   391       // ceil(NN/256) buckets of 256 nodes
#define CHUNK 4096     // edges per bin_pass block

typedef unsigned short u16;
typedef unsigned int   u32;
typedef unsigned long long u64;

typedef __attribute__((ext_vector_type(8))) short bf16x8;
typedef __attribute__((ext_vector_type(4))) float f32x4;
typedef __attribute__((ext_vector_type(2))) float f32x2;

__device__ __forceinline__ float bf2f(u16 a) {
    return __uint_as_float(((u32)a) << 16);
}
__device__ __forceinline__ u16 f2bf(float f) {
    u32 u = __float_as_uint(f);
    u32 r = (u + 0x7fffu + ((u >> 16) & 1u)) >> 16;
    return (u16)r;
}
__device__ __forceinline__ f32x2 unpk(u32 u) {
    f32x2 r;
    r.x = __uint_as_float(u << 16);
    r.y = __uint_as_float(u & 0xffff0000u);
    return r;
}
// bare v_exp_f32: D = 2^S0 (input pre-scaled by log2(e) where e^x is wanted)
__device__ __forceinline__ float exp2_hw(float x) {
    float d;
    asm("v_exp_f32 %0, %1" : "=v"(d) : "v"(x));
    return d;
}
// async global->LDS, 16B per lane (dest = wave-uniform base + lane*16)
__device__ __forceinline__ void gload_lds16(const void* g, void* l) {
    __builtin_amdgcn_global_load_lds(
        (const __attribute__((address_space(1))) void*)g,
        (__attribute__((address_space(3))) void*)l, 16, 0, 0);
}
// tanh-form GELU via sigmoid: x * sigmoid(1.595769x + 0.0713548x^3); |err vs exact| <= ~3e-4
__device__ __forceinline__ float gelu_t(float x) {
    float x2 = x * x;
    float y = x * fmaf(0.0713548162726f, x2, 1.59576912161f);
    return x / (1.f + __expf(-y));
}

// f32 vector pack offsets (floats)
#define Vbp   0
#define Vatt1 128
#define Vb1   256
#define Vg1   384
#define Vbe1  512
#define Vatt2 640
#define Vb2   768
#define Vg2   896
#define Vbe2  1024
#define Vbo   1152
#define VTOT  1216

// bf16 transposed weight pack offsets (u16 elements)
#define BWp   0        // [128][64]  (K=40 zero-padded to 64)
#define BW1l  8192     // [128][128]
#define BW1r  24576    // adjacent to BW1l -> [256][128] panel for gemm_layer
#define BW2l  40960
#define BW2r  57344
#define BWo   73728    // [128][128] n-major; rows 64..127 zero
#define BTOT  90112

// prep_kernel block-range sizes
#define XROWS 100096   // NN rounded up to 128 (proj tile reach)
#define NXB   25000    // NN*64/256 exactly (padded-x blocks)
#define NVB   5        // ceil(VTOT/256)
#define NWB   352      // BTOT/256 exactly

// per-wave bf16-ness sniff (identical predicate to original sniff_kernel)
__device__ __forceinline__ int sniff_bf_wave(const u32* __restrict__ x_raw) {
    int lane = threadIdx.x & 63;
    u32 w = x_raw[lane];              // first 64 u32 of x
    u16 lo = (u16)(w & 0xffffu);
    int e = (lo >> 7) & 0xFF;
    int ok = (e >= 118 && e <= 133) ? 1 : 0;
    u64 b = __ballot(ok);
    return (__popcll(b) >= 48) ? 1 : 0;
}

__device__ __forceinline__ void edge_decode(const int* __restrict__ ei, int is64, int e,
                                            int& src, int& dst) {
    if (e < EE) {
        src = is64 ? ei[2 * e] : ei[e];
        int idx = EE + e;
        dst = is64 ? ei[2 * idx] : ei[idx];
    } else {
        src = e - EE; dst = src;
    }
}

// ---------------- fused prep: sniff + zero + normx(pad64) + norm_vec + norm_wt ----------------
__global__ __launch_bounds__(256) void prep_kernel(
    const void* __restrict__ x, const u32* __restrict__ ei_raw,
    const void* p0, const void* p1, const void* p2, const void* p3, const void* p4,
    const void* p5, const void* p6, const void* p7, const void* p8, const void* p9,
    const void* w0, const void* w1, const void* w2, const void* w3, const void* w4,
    const void* w5,
    u16* __restrict__ xb, float* __restrict__ wv, u16* __restrict__ wbf,
    int* __restrict__ flags, u32* __restrict__ gbucket, u32* __restrict__ dcnt,
    u32* __restrict__ gcur, u32* __restrict__ dcur)
{
    const u32* x_raw = (const u32*)x;
    int isbf = sniff_bf_wave(x_raw);
    int t = threadIdx.x;
    int b = blockIdx.x;

    if (b == 0) {
        // is64 sniff: all odd u32 in [1,255] zero -> int64 edge index
        if (t < 64) {
            u32 a = ei_raw[2 * t + 1] | ei_raw[129 + 2 * t];
            u64 nz = __ballot(a != 0u);
            if (t == 0) { flags[0] = (nz == 0uLL) ? 1 : 0; flags[1] = isbf; }
        }
        gbucket[t] = 0; gbucket[t + 256] = 0;
        gcur[t] = 0;    gcur[t + 256] = 0;
        if (t < 64) { dcnt[t] = 0; dcur[t] = 0; }
        return;
    }
    if (b <= NXB) {
        // normx: x[NN][40] -> xb[NN][64] bf16 (zeros k>=40; contiguous 128B rows)
        int i = (b - 1) * 256 + t;   // i < NN*64 exactly
        int row = i >> 6, k = i & 63;
        u16 v = 0;
        if (k < MM) {
            int src = row * MM + k;
            v = isbf ? ((const u16*)x)[src] : f2bf(((const float*)x)[src]);
        }
        xb[i] = v;
        return;
    }
    if (b <= NXB + NVB) {
        int i = (b - 1 - NXB) * 256 + t;
        if (i >= VTOT) return;
        const int offs[11] = {Vbp, Vatt1, Vb1, Vg1, Vbe1, Vatt2, Vb2, Vg2, Vbe2, Vbo, VTOT};
        const void* ps[10] = {p0,p1,p2,p3,p4,p5,p6,p7,p8,p9};
        int s = 0;
#pragma unroll
        for (int k = 1; k < 10; k++) s += (i >= offs[k]) ? 1 : 0;
        int j = i - offs[s];
        const void* p = ps[s];
        wv[i] = isbf ? bf2f(((const u16*)p)[j]) : ((const float*)p)[j];
        return;
    }
    {
        int i = (b - 1 - NXB - NVB) * 256 + t;   // grid sized exactly: i < BTOT
        const int offs[7] = {BWp, BW1l, BW1r, BW2l, BW2r, BWo, BTOT};
        const int Ks[6]   = {40, 128, 128, 128, 128, 128};
        const int Ncs[6]  = {128, 128, 128, 128, 128, 64};
        const int Kps[6]  = {64, 128, 128, 128, 128, 128};
        const void* ps[6] = {w0,w1,w2,w3,w4,w5};
        int s = 0;
#pragma unroll
        for (int k = 1; k < 6; k++) s += (i >= offs[k]) ? 1 : 0;
        int j = i - offs[s];
        int Kp = Kps[s];
        int n = j / Kp, k = j % Kp;
        u16 v = 0;
        if (k < Ks[s] && n < Ncs[s]) {
            const void* p = ps[s];
            int src = k * Ncs[s] + n;
            v = isbf ? ((const u16*)p)[src] : f2bf(((const float*)p)[src]);
        }
        wbf[i] = v;
    }
}

// ---------------- CSR build: 2-pass LDS-binned counting sort ----------------
__global__ __launch_bounds__(256) void bucket_hist_kernel(
    const int* __restrict__ ei, const int* __restrict__ flags, u32* __restrict__ gbucket)
{
    __shared__ u32 h[512];
    int t = threadIdx.x;
    h[t] = 0; h[t + 256] = 0;
    __syncthreads();
    int is64 = flags[0];
    int base = blockIdx.x * CHUNK;
#pragma unroll
    for (int j = 0; j < CHUNK / 256; j++) {
        int e = base + j * 256 + t;
        if (e < ETOT) {
            int src, dst;
            edge_decode(ei, is64, e, src, dst);
            atomicAdd(&h[dst >> 8], 1u);
        }
    }
    __syncthreads();
    if (h[t])       atomicAdd(&gbucket[t], h[t]);
    if (h[t + 256]) atomicAdd(&gbucket[t + 256], h[t + 256]);
}

// bin_pass: local gbucket scan; edges decoded ONCE into registers and reused.
__global__ __launch_bounds__(256) void bin_pass_kernel(
    const int* __restrict__ ei, const int* __restrict__ flags,
    const u32* __restrict__ gbucket, u32* __restrict__ gcur, u64* __restrict__ pairs)
{
    __shared__ u32 bh[512];
    __shared__ u32 boff[512];
    __shared__ u32 bbs[512];
    __shared__ u32 bcur[512];
    __shared__ u32 bsc[512];
    __shared__ u64 stage[CHUNK];
    __shared__ u32 ts[256];

    int t = threadIdx.x;
    bh[t] = 0; bh[t + 256] = 0;
    __syncthreads();
    int is64 = flags[0];
    int base = blockIdx.x * CHUNK;
    int chunk_n = ETOT - base; if (chunk_n > CHUNK) chunk_n = CHUNK;

    u64 epk[CHUNK / 256];   // decoded edges cached in registers
#pragma unroll
    for (int j = 0; j < CHUNK / 256; j++) {
        int e = base + j * 256 + t;
        if (e < ETOT) {
            int src, dst;
            edge_decode(ei, is64, e, src, dst);
            epk[j] = (u64)(u32)src | ((u64)(u32)dst << 32);
            atomicAdd(&bh[dst >> 8], 1u);
        }
    }
    __syncthreads();

    // local exclusive scan of gbucket -> bsc (replaces global bucket_scan)
    {
        u32 g0v = (2 * t     < NB) ? gbucket[2 * t]     : 0;
        u32 g1v = (2 * t + 1 < NB) ? gbucket[2 * t + 1] : 0;
        u32 ps = g0v + g1v;
        ts[t] = ps; __syncthreads();
        for (int d = 1; d < 256; d <<= 1) {
            u32 v = (t >= d) ? ts[t - d] : 0;
            __syncthreads();
            ts[t] += v;
            __syncthreads();
        }
        u32 ex = ts[t] - ps;
        bsc[2 * t] = ex; bsc[2 * t + 1] = ex + g0v;
    }
    __syncthreads();

    // local scan of block histogram
    u32 s0 = bh[2 * t], s1 = bh[2 * t + 1];
    u32 tsum = s0 + s1;
    ts[t] = tsum; __syncthreads();
    for (int d = 1; d < 256; d <<= 1) {
        u32 v = (t >= d) ? ts[t - d] : 0;
        __syncthreads();
        ts[t] += v;
        __syncthreads();
    }
    u32 excl = ts[t] - tsum;
    boff[2 * t] = excl; boff[2 * t + 1] = excl + s0;
    bcur[2 * t] = excl; bcur[2 * t + 1] = excl + s0;
    __syncthreads();
    if (t < NB && bh[t]) bbs[t] = bsc[t] + atomicAdd(&gcur[t], bh[t]);
    if (t + 256 < NB && bh[t + 256]) bbs[t + 256] = bsc[t + 256] + atomicAdd(&gcur[t + 256], bh[t + 256]);
    __syncthreads();
#pragma unroll
    for (int j = 0; j < CHUNK / 256; j++) {
        int e = base + j * 256 + t;
        if (e < ETOT) {
            u64 pr = epk[j];
            u32 pos = atomicAdd(&bcur[(u32)(pr >> 32) >> 8], 1u);
            stage[pos] = pr;
        }
    }
    __syncthreads();
    for (int i = t; i < chunk_n; i += 256) {
        u64 pr = stage[i];
        u32 b = (u32)(pr >> 32) >> 8;
        pairs[(size_t)bbs[b] + (i - boff[b])] = pr;
    }
}

// sort within bucket + CSR offs + degree histogram; bucket bounds from local scan
__global__ __launch_bounds__(256) void sort_pass_kernel(
    const u64* __restrict__ pairs, const u32* __restrict__ gbucket,
    int* __restrict__ srcs, int* __restrict__ offs, u32* __restrict__ dcnt)
{
    __shared__ u32 nh[256];
    __shared__ u32 ns[256];
    __shared__ u32 ncur[256];
    __shared__ u32 dh[64];
    __shared__ u32 bsc[512];
    int t = threadIdx.x;
    int b = blockIdx.x;

    // local exclusive scan of gbucket
    {
        u32 g0v = (2 * t     < NB) ? gbucket[2 * t]     : 0;
        u32 g1v = (2 * t + 1 < NB) ? gbucket[2 * t + 1] : 0;
        u32 ps = g0v + g1v;
        ns[t] = ps; __syncthreads();
        for (int d = 1; d < 256; d <<= 1) {
            u32 v = (t >= d) ? ns[t - d] : 0;
            __syncthreads();
            ns[t] += v;
            __syncthreads();
        }
        u32 ex = ns[t] - ps;
        bsc[2 * t] = ex; bsc[2 * t + 1] = ex + g0v;
    }
    __syncthreads();
    u32 beg = bsc[b], endp = bsc[b + 1];

    nh[t] = 0;
    if (t < 64) dh[t] = 0;
    __syncthreads();
    for (u32 i = beg + t; i < endp; i += 256) {
        u32 dst = (u32)(pairs[i] >> 32);
        atomicAdd(&nh[dst & 255], 1u);
    }
    __syncthreads();
    u32 cnt = nh[t];
    ns[t] = cnt; __syncthreads();
    for (int d = 1; d < 256; d <<= 1) {
        u32 v = (t >= d) ? ns[t - d] : 0;
        __syncthreads();
        ns[t] += v;
        __syncthreads();
    }
    u32 excl = ns[t] - cnt;
    int id = b * 256 + t;
    if (id <= NN) offs[id] = (int)(beg + excl);
    if (id < NN) atomicAdd(&dh[cnt < 63u ? cnt : 63u], 1u);
    ncur[t] = excl;
    __syncthreads();
    if (t < 64 && dh[t]) atomicAdd(&dcnt[t], dh[t]);
    for (u32 i = beg + t; i < endp; i += 256) {
        u64 pr = pairs[i];
        u32 loc = ((u32)(pr >> 32)) & 255;
        u32 p = atomicAdd(&ncur[loc], 1u);
        srcs[beg + p] = (int)(u32)pr;
    }
}

// ---------------- degree-balance permutation (scan fused, dcur zero-init) ----------------
// Heaviest degree first: waves see 4 near-equal-degree dsts -> max(deg)~deg.
__global__ __launch_bounds__(256) void deg_perm_kernel(
    const int* __restrict__ offs, const u32* __restrict__ dcnt,
    u32* __restrict__ dcur, int* __restrict__ perm)
{
    __shared__ u32 cnt[64];
    __shared__ u32 base[64];
    __shared__ u32 sb[64];
    int t = threadIdx.x;
    if (t < 64) {
        // in-wave suffix scan of dcnt (descending-degree layout)
        u32 v = dcnt[t];
        u32 x = v;
#pragma unroll
        for (int off = 1; off < 64; off <<= 1) {
            u32 y = __shfl_down(x, off);
            if (t + off < 64) x += y;
        }
        sb[t] = x - v;   // exclusive suffix sum = global base of bucket t
        cnt[t] = 0;
    }
    __syncthreads();
    int i = blockIdx.x * 256 + t;
    int d = 0; u32 r = 0;
    bool ok = (i < NN);
    if (ok) {
        d = offs[i + 1] - offs[i];
        if (d > 63) d = 63;
        r = atomicAdd(&cnt[d], 1u);
    }
    __syncthreads();
    if (t < 64 && cnt[t]) base[t] = sb[t] + atomicAdd(&dcur[t], cnt[t]);
    __syncthreads();
    if (ok) perm[base[d] + r] = i;
}

// ---------------- proj GEMM: xb[NN][64] @ Wp -> h0b[NN][128], LDS-staged A ----------------
// Tile 128 rows x 128 cols; 4 waves (wx=row half, wy=col half). A tile 16KB swizzled.
// Epilogue: LDS bounce -> coalesced uint4 stores.
__global__ __launch_bounds__(256) void gemm_proj(
    const u16* __restrict__ A,      // [XROWS][64] bf16
    const u16* __restrict__ Bt,     // [128][64] bf16
    const float* __restrict__ bias, // [128]
    u16* __restrict__ outB)         // [NN][128] bf16
{
    __shared__ u16 Atile[128 * 64];   // 16KB swizzled
    __shared__ u16 Ctile[128 * 136];  // 34KB (row pad +8 u16)
    int t = threadIdx.x;
    int wv = t >> 6, lane = t & 63;
    int wx = wv & 1, wy = wv >> 1;
    int l16 = lane & 15, quad = lane >> 4;
    int r0 = blockIdx.x * 128;

    {
        const char* Ab = (const char*)(A + (size_t)r0 * 64);
        char* Lb = (char*)Atile + wv * 4096;
        u32 baseP = (u32)(wv * 4096) + (u32)lane * 16;
#pragma unroll
        for (int j = 0; j < 4; j++) {
            u32 P = baseP + (u32)(j * 1024);
            u32 row = P >> 7;
            u32 L = P ^ ((row & 7u) << 4);
            gload_lds16(Ab + L, Lb + j * 1024);
        }
    }

    f32x4 acc[4][4];
#pragma unroll
    for (int m = 0; m < 4; m++)
#pragma unroll
        for (int n = 0; n < 4; n++) acc[m][n] = (f32x4){0.f, 0.f, 0.f, 0.f};

    int n0 = wy * 64;
    const u16* Bp = Bt + (size_t)(n0 + l16) * 64 + quad * 8;
    const char* At = (const char*)Atile;

    __syncthreads();

#pragma unroll
    for (int k = 0; k < 2; k++) {
        bf16x8 af[4], bfr[4];
#pragma unroll
        for (int n = 0; n < 4; n++)
            bfr[n] = *(const bf16x8*)(Bp + (size_t)n * 16 * 64 + k * 32);
#pragma unroll
        for (int m = 0; m < 4; m++) {
            u32 arow = (u32)(wx * 64 + m * 16 + l16);
            u32 Lb = arow * 128 + (u32)(quad * 16 + k * 64);
            u32 Pb = Lb ^ ((arow & 7u) << 4);
            af[m] = *(const bf16x8*)(At + Pb);
        }
#pragma unroll
        for (int m = 0; m < 4; m++)
#pragma unroll
            for (int n = 0; n < 4; n++)
                acc[m][n] = __builtin_amdgcn_mfma_f32_16x16x32_bf16(af[m], bfr[n], acc[m][n], 0, 0, 0);
    }

    // epilogue: bias + bf16 into LDS, then coalesced stores
#pragma unroll
    for (int m = 0; m < 4; m++) {
#pragma unroll
        for (int n = 0; n < 4; n++) {
            int col = n0 + n * 16 + l16;
            float bb = bias[col];
#pragma unroll
            for (int reg = 0; reg < 4; reg++) {
                int row = wx * 64 + m * 16 + quad * 4 + reg;
                Ctile[row * 136 + col] = f2bf(acc[m][n][reg] + bb);
            }
        }
    }
    __syncthreads();
#pragma unroll
    for (int c = 0; c < 8; c++) {
        int e = (c * 256 + t) * 8;       // u16 element index in 128x128
        int row = e >> 7, col = e & 127;
        int grow = r0 + row;
        if (grow < NN) {
            uint4 v = *(const uint4*)&Ctile[row * 136 + col];
            *(uint4*)&outB[(size_t)grow * 128 + col] = v;
        }
    }
}

// ---------------- layer GEMM: A LDS-staged (swizzled), hl||hr in one pass ----------------
// Tile 64 rows x 256 cols. 4 waves; wave w owns cols w*64 (w<2 -> outL, else outR).
// Epilogue: LDS bounce -> coalesced uint4 stores.
__global__ __launch_bounds__(256) void gemm_layer(
    const u16* __restrict__ A,      // [NN+128][128] bf16
    const u16* __restrict__ Bt,     // [256][128] bf16 (Wl || Wr, n-major)
    u16* __restrict__ outL, u16* __restrict__ outR)
{
    __shared__ u16 Atile[64 * 128];   // 16KB, physically swizzled
    __shared__ u16 Ctile[64 * 264];   // 33KB (row pad +8 u16)
    int t = threadIdx.x;
    int wv = t >> 6, lane = t & 63;
    int l16 = lane & 15, quad = lane >> 4;
    int r0 = blockIdx.x * 64;

    // stage A rows r0..r0+63 (one contiguous 16KB region)
    {
        const char* Ab = (const char*)(A + (size_t)r0 * 128);
        char* Lb = (char*)Atile + wv * 4096;
        u32 baseP = (u32)(wv * 4096) + (u32)lane * 16;
#pragma unroll
        for (int j = 0; j < 4; j++) {
            u32 P = baseP + (u32)(j * 1024);
            u32 row = P >> 8;
            u32 L = P ^ ((row & 7u) << 4);
            gload_lds16(Ab + L, Lb + j * 1024);
        }
    }

    f32x4 acc[4][4];
#pragma unroll
    for (int m = 0; m < 4; m++)
#pragma unroll
        for (int n = 0; n < 4; n++) acc[m][n] = (f32x4){0.f, 0.f, 0.f, 0.f};

    int n0 = wv * 64;
    const u16* Bp = Bt + (size_t)(n0 + l16) * 128 + quad * 8;
    const char* At = (const char*)Atile;

    __syncthreads();

#pragma unroll
    for (int k = 0; k < 4; k++) {
        bf16x8 af[4], bfr[4];
#pragma unroll
        for (int n = 0; n < 4; n++)
            bfr[n] = *(const bf16x8*)(Bp + (size_t)n * 16 * 128 + k * 32);
#pragma unroll
        for (int m = 0; m < 4; m++) {
            u32 arow = (u32)(m * 16 + l16);
            u32 Lb = arow * 256 + (u32)(quad * 16 + k * 64);
            u32 Pb = Lb ^ ((arow & 7u) << 4);
            af[m] = *(const bf16x8*)(At + Pb);
        }
#pragma unroll
        for (int m = 0; m < 4; m++)
#pragma unroll
            for (int n = 0; n < 4; n++)
                acc[m][n] = __builtin_amdgcn_mfma_f32_16x16x32_bf16(af[m], bfr[n], acc[m][n], 0, 0, 0);
    }

    // epilogue: bf16 into LDS, then coalesced split stores
#pragma unroll
    for (int m = 0; m < 4; m++) {
#pragma unroll
        for (int n = 0; n < 4; n++) {
            int col = n0 + n * 16 + l16;
#pragma unroll
            for (int reg = 0; reg < 4; reg++) {
                int row = m * 16 + quad * 4 + reg;
                Ctile[row * 264 + col] = f2bf(acc[m][n][reg]);
            }
        }
    }
    __syncthreads();
#pragma unroll
    for (int c = 0; c < 8; c++) {
        int e = (c * 256 + t) * 8;       // u16 element index in 64x256
        int row = e >> 8, col = e & 255;
        int grow = r0 + row;
        if (grow < NN) {
            uint4 v = *(const uint4*)&Ctile[row * 264 + col];
            if (col < 128) *(uint4*)&outL[(size_t)grow * 128 + col] = v;
            else           *(uint4*)&outR[(size_t)grow * 128 + (col - 128)] = v;
        }
    }
}

// ---------------- final GEMM: h[NN][128] @ Wo -> out[NN][64], LDS-staged A ----------------
// Tile 128 rows x 64 cols; 4 waves: wx=row half (64), wy=col half (32).
// Epilogue: f32 LDS bounce -> coalesced stores (f32x4 or packed bf16).
__global__ __launch_bounds__(256) void gemm_final(
    const u16* __restrict__ A,      // [NN+128][128] bf16
    const u16* __restrict__ Bt,     // [128][128] bf16 (rows 64+ zero)
    const float* __restrict__ bias, // [64]
    float* __restrict__ outF, u16* __restrict__ outB,
    const int* __restrict__ flags)
{
    __shared__ u16 Atile[128 * 128];  // 32KB swizzled
    __shared__ float Cf[128 * 68];    // 34KB (row pad +4 f32)
    int t = threadIdx.x;
    int wv = t >> 6, lane = t & 63;
    int wx = wv & 1, wy = wv >> 1;
    int l16 = lane & 15, quad = lane >> 4;
    int r0 = blockIdx.x * 128;

    {
        const char* Ab = (const char*)(A + (size_t)r0 * 128);
        char* Lb = (char*)Atile + wv * 8192;
        u32 baseP = (u32)(wv * 8192) + (u32)lane * 16;
#pragma unroll
        for (int j = 0; j < 8; j++) {
            u32 P = baseP + (u32)(j * 1024);
            u32 row = P >> 8;
            u32 L = P ^ ((row & 7u) << 4);
            gload_lds16(Ab + L, Lb + j * 1024);
        }
    }

    f32x4 acc[4][2];
#pragma unroll
    for (int m = 0; m < 4; m++)
#pragma unroll
        for (int n = 0; n < 2; n++) acc[m][n] = (f32x4){0.f, 0.f, 0.f, 0.f};

    int n0 = wy * 32;
    const u16* Bp = Bt + (size_t)(n0 + l16) * 128 + quad * 8;
    const char* At = (const char*)Atile;

    __syncthreads();

#pragma unroll
    for (int k = 0; k < 4; k++) {
        bf16x8 af[4], bfr[2];
#pragma unroll
        for (int n = 0; n < 2; n++)
            bfr[n] = *(const bf16x8*)(Bp + (size_t)n * 16 * 128 + k * 32);
#pragma unroll
        for (int m = 0; m < 4; m++) {
            u32 arow = (u32)(wx * 64 + m * 16 + l16);
            u32 Lb = arow * 256 + (u32)(quad * 16 + k * 64);
            u32 Pb = Lb ^ ((arow & 7u) << 4);
            af[m] = *(const bf16x8*)(At + Pb);
        }
#pragma unroll
        for (int m = 0; m < 4; m++)
#pragma unroll
            for (int n = 0; n < 2; n++)
                acc[m][n] = __builtin_amdgcn_mfma_f32_16x16x32_bf16(af[m], bfr[n], acc[m][n], 0, 0, 0);
    }

    // epilogue: bias + f32 into LDS, then coalesced stores per dtype
#pragma unroll
    for (int m = 0; m < 4; m++) {
#pragma unroll
        for (int n = 0; n < 2; n++) {
            int col = n0 + n * 16 + l16;
            float bb = bias[col];
#pragma unroll
            for (int reg = 0; reg < 4; reg++) {
                int row = wx * 64 + m * 16 + quad * 4 + reg;
                Cf[row * 68 + col] = acc[m][n][reg] + bb;
            }
        }
    }
    __syncthreads();
    int mk = flags[1] ? 2 : 1;
#pragma unroll
    for (int c = 0; c < 8; c++) {
        int e = (c * 256 + t) * 4;       // f32 element index in 128x64
        int row = e >> 6, col = e & 63;
        int grow = r0 + row;
        if (grow < NN) {
            f32x4 v = *(const f32x4*)&Cf[row * 68 + col];
            if (mk & 1) {
                *(f32x4*)&outF[(size_t)grow * 64 + col] = v;
            } else {
                uint2 pk;
                pk.x = (u32)f2bf(v.x) | ((u32)f2bf(v.y) << 16);
                pk.y = (u32)f2bf(v.z) | ((u32)f2bf(v.w) << 16);
                *(uint2*)&outB[(size_t)grow * 64 + col] = pk;
            }
        }
    }
}

// ---------------- fused GATv2 agg + bias + GELU + residual + LayerNorm ----------------
// 4 dst per wave (sub = lane>>4), lane r = lane&15 owns ch r*8..r*8+7.
// dsts via degree-sorted perm (wave's 4 dsts near-equal degree -> max(deg)~deg).
// Distance-1 prefetch (proven 44-VGPR body). att pre-scaled by log2(e) so
// exp is a bare v_exp_f32; hl gathers via u32 byte offsets.
__global__ __launch_bounds__(256) void gat_agg_kernel(
    const u16* __restrict__ hl, const u16* __restrict__ hr, const u16* __restrict__ hresb,
    const float* __restrict__ att, const float* __restrict__ bias,
    const float* __restrict__ gamma, const float* __restrict__ beta,
    const int* __restrict__ offs, const int* __restrict__ srcs,
    const int* __restrict__ perm,
    u16* __restrict__ outb)
{
    int lane = threadIdx.x & 63;
    int sub = lane >> 4;
    int r = lane & 15;
    int c0 = r * 8;
    u32 cb = (u32)(r << 4);              // byte offset of this lane's 8 ch (16 B)
    int id = (blockIdx.x * 4 + (threadIdx.x >> 6)) * 4 + sub;   // grid = NN/16 blocks
    int dst = perm[id];

    int start = offs[dst];
    int deg = offs[dst + 1] - start;    // >= 1 (self loop)
    int dm = deg - 1;
    const char* hlc = (const char*)hl;

    f32x2 hr2[4], av2[4];
    {
        uint4 q = *(const uint4*)((const char*)hr + ((u32)dst << 8) + cb);
        hr2[0] = unpk(q.x); hr2[1] = unpk(q.y); hr2[2] = unpk(q.z); hr2[3] = unpk(q.w);
        const float L2E = 1.4426950408889634f;   // logits scaled so exp(x) = exp2(x*L2E)
        float4 a0 = *(const float4*)&att[c0];
        float4 a1 = *(const float4*)&att[c0 + 4];
        av2[0] = (f32x2){L2E * a0.x, L2E * a0.y}; av2[1] = (f32x2){L2E * a0.z, L2E * a0.w};
        av2[2] = (f32x2){L2E * a1.x, L2E * a1.y}; av2[3] = (f32x2){L2E * a1.z, L2E * a1.w};
    }

    // wave-uniform iteration bound = max deg over the 4 sub-groups (~deg after perm)
    int md = deg;
    md = max(md, __shfl_xor(md, 16));
    md = max(md, __shfl_xor(md, 32));

    f32x2 acc2[4];
#pragma unroll
    for (int i = 0; i < 4; i++) acc2[i] = (f32x2){0.f, 0.f};
    float s = 0.f;

    // prefetch: edges 0,1 rows; srcs for edges 2,3
    int sa = srcs[start];
    int sb = srcs[start + (1 < dm ? 1 : dm)];
    uint4 qa = *(const uint4*)(hlc + ((u32)sa << 8) + cb);
    uint4 qb = *(const uint4*)(hlc + ((u32)sb << 8) + cb);
    int sna = srcs[start + (2 < dm ? 2 : dm)];
    int snb = srcs[start + (3 < dm ? 3 : dm)];

    int mi = (md + 1) >> 1;
    for (int j = 0; j < mi; ++j) {
        // srcs for iteration j+2 (edges 2j+4, 2j+5)
        int e4 = 2 * j + 4, e5 = 2 * j + 5;
        int sna2 = srcs[start + min(e4, dm)];
        int snb2 = srcs[start + min(e5, dm)];
        // rows for iteration j+1
        uint4 qna = *(const uint4*)(hlc + ((u32)sna << 8) + cb);
        uint4 qnb = *(const uint4*)(hlc + ((u32)snb << 8) + cb);

        f32x2 ha[4], hb[4];
        ha[0] = unpk(qa.x); ha[1] = unpk(qa.y); ha[2] = unpk(qa.z); ha[3] = unpk(qa.w);
        hb[0] = unpk(qb.x); hb[1] = unpk(qb.y); hb[2] = unpk(qb.z); hb[3] = unpk(qb.w);
        f32x2 pa2 = (f32x2){0.f, 0.f};
        f32x2 pb2 = (f32x2){0.f, 0.f};
#pragma unroll
        for (int i = 0; i < 4; i++) {
            f32x2 za = ha[i] + hr2[i];
            f32x2 zb = hb[i] + hr2[i];
            f32x2 la = __builtin_elementwise_max(za, za * 0.2f);
            f32x2 lb = __builtin_elementwise_max(zb, zb * 0.2f);
            pa2 = __builtin_elementwise_fma(av2[i], la, pa2);
            pb2 = __builtin_elementwise_fma(av2[i], lb, pb2);
        }
        float pa = pa2.x + pa2.y;
        float pb = pb2.x + pb2.y;
        pa += __shfl_xor(pa, 1); pb += __shfl_xor(pb, 1);
        pa += __shfl_xor(pa, 2); pb += __shfl_xor(pb, 2);
        int e0 = 2 * j, e1 = 2 * j + 1;
        float wa = (e0 < deg) ? exp2_hw(pa) : 0.f;
        float wb = (e1 < deg) ? exp2_hw(pb) : 0.f;
        s += wa + wb;
        f32x2 wa2 = (f32x2){wa, wa};
        f32x2 wb2 = (f32x2){wb, wb};
#pragma unroll
        for (int i = 0; i < 4; i++)
            acc2[i] = __builtin_elementwise_fma(wa2, ha[i],
                      __builtin_elementwise_fma(wb2, hb[i], acc2[i]));

        qa = qna; qb = qnb; sna = sna2; snb = snb2;
    }

    float inv = 1.f / s;
    float v[8];
    {
        float4 b0 = *(const float4*)&bias[c0];
        float4 b1 = *(const float4*)&bias[c0 + 4];
        float bb[8] = {b0.x,b0.y,b0.z,b0.w,b1.x,b1.y,b1.z,b1.w};
        uint4 qr = *(const uint4*)((const char*)hresb + ((u32)dst << 8) + cb);
        f32x2 rr2[4] = {unpk(qr.x), unpk(qr.y), unpk(qr.z), unpk(qr.w)};
#pragma unroll
        for (int i = 0; i < 4; i++) {
            float t0 = fmaf(acc2[i].x, inv, bb[2*i]);
            float t1 = fmaf(acc2[i].y, inv, bb[2*i+1]);
            v[2*i]   = gelu_t(t0) + rr2[i].x;
            v[2*i+1] = gelu_t(t1) + rr2[i].y;
        }
    }

    // LayerNorm over 128 ch = 16 lanes of this sub-group (offsets 1..8 stay in-group)
    float s1 = 0.f, s2 = 0.f;
#pragma unroll
    for (int k = 0; k < 8; k++) { s1 += v[k]; s2 = fmaf(v[k], v[k], s2); }
#pragma unroll
    for (int off = 1; off < 16; off <<= 1) {
        s1 += __shfl_xor(s1, off);
        s2 += __shfl_xor(s2, off);
    }
    float mu  = s1 * (1.f / 128.f);
    float var = s2 * (1.f / 128.f) - mu * mu;
    float rstd = rsqrtf(var + 1e-5f);

    float4 g0 = *(const float4*)&gamma[c0];
    float4 g1 = *(const float4*)&gamma[c0 + 4];
    float4 be0 = *(const float4*)&beta[c0];
    float4 be1 = *(const float4*)&beta[c0 + 4];
    float gg[8] = {g0.x,g0.y,g0.z,g0.w,g1.x,g1.y,g1.z,g1.w};
    float eb[8] = {be0.x,be0.y,be0.z,be0.w,be1.x,be1.y,be1.z,be1.w};
    float o[8];
#pragma unroll
    for (int k = 0; k < 8; k++) o[k] = fmaf((v[k] - mu) * rstd, gg[k], eb[k]);
    uint4 pk;
    pk.x = (u32)f2bf(o[0]) | ((u32)f2bf(o[1]) << 16);
    pk.y = (u32)f2bf(o[2]) | ((u32)f2bf(o[3]) << 16);
    pk.z = (u32)f2bf(o[4]) | ((u32)f2bf(o[5]) << 16);
    pk.w = (u32)f2bf(o[6]) | ((u32)f2bf(o[7]) << 16);
    *(uint4*)((char*)outb + ((u32)dst << 8) + cb) = pk;
}

// ---------------- launch ----------------
extern "C" void kernel_launch(void* const* d_in, const int* in_sizes, int n_in,
                              void* d_out, int out_size, void* d_ws, size_t ws_size,
                              hipStream_t stream) {
    const void* x  = d_in[0];
    const int*  ei = (const int*)d_in[1];

    char* ws = (char*)d_ws;
    size_t off = 0;
    auto alloc = [&](size_t bytes) -> void* {
        void* p = ws + off;
        off = (off + bytes + 511) & ~(size_t)511;
        return p;
    };
    u16*   xb      = (u16*)  alloc((size_t)XROWS * 64 * 2);
    float* wv      = (float*)alloc((size_t)VTOT * 4);
    u16*   wbf     = (u16*)  alloc((size_t)BTOT * 2);
    u16*   h0b     = (u16*)  alloc((size_t)(NN + 128) * HID * 2);
    u16*   h1b     = (u16*)  alloc((size_t)(NN + 128) * HID * 2);
    u16*   hlb     = (u16*)  alloc((size_t)(NN + 128) * HID * 2);
    u16*   hrb     = (u16*)  alloc((size_t)(NN + 128) * HID * 2);
    int*   offs    = (int*)  alloc((size_t)(NN + 1) * 4);
    u32*   gbucket = (u32*)  alloc(512 * 4);
    u32*   gcur    = (u32*)  alloc(512 * 4);
    int*   flags   = (int*)  alloc(512);
    int*   srcs    = (int*)  alloc(((size_t)ETOT + 64) * 4);
    u64*   pairs   = (u64*)  alloc((size_t)ETOT * 8);
    u32*   dcnt    = (u32*)  alloc(64 * 4);
    u32*   dcur    = (u32*)  alloc(64 * 4);
    int*   perm    = (int*)  alloc((size_t)NN * 4);

    // fused prep: sniff + zero(gbucket,gcur,dcnt,dcur) + normx(pad64) + norm_vec + norm_wt
    prep_kernel<<<1 + NXB + NVB + NWB, 256, 0, stream>>>(
        x, (const u32*)ei,
        d_in[3], d_in[6], d_in[7], d_in[12], d_in[13], d_in[10], d_in[11], d_in[14], d_in[15], d_in[17],
        d_in[2], d_in[4], d_in[5], d_in[8], d_in[9], d_in[16],
        xb, wv, wbf, flags, gbucket, dcnt, gcur, dcur);

    const int EB = (ETOT + CHUNK - 1) / CHUNK;  // 416
    bucket_hist_kernel<<<EB, 256, 0, stream>>>(ei, flags, gbucket);
    bin_pass_kernel<<<EB, 256, 0, stream>>>(ei, flags, gbucket, gcur, pairs);
    sort_pass_kernel<<<NB, 256, 0, stream>>>(pairs, gbucket, srcs, offs, dcnt);

    // degree-balance permutation (scan fused; heaviest degree first)
    deg_perm_kernel<<<NB, 256, 0, stream>>>(offs, dcnt, dcur, perm);

    const int GB = (NN + 127) / 128;  // 782 (128-row tiles, proj/final)
    const int LB = (NN + 63) / 64;    // 1563 (64-row tiles, layer gemm)
    const int AB = NN / 16;           // 6250 blocks, 4 dst/wave x 4 waves

    // proj: h0b = bf16(x @ Wp + bp)
    gemm_proj<<<GB, 256, 0, stream>>>(xb, wbf + BWp, wv + Vbp, h0b);

    // layer 1: hl/hr in one LDS-staged dispatch
    gemm_layer<<<LB, 256, 0, stream>>>(h0b, wbf + BW1l, hlb, hrb);
    gat_agg_kernel<<<AB, 256, 0, stream>>>(hlb, hrb, h0b, wv + Vatt1, wv + Vb1,
                                           wv + Vg1, wv + Vbe1, offs, srcs, perm, h1b);

    // layer 2
    gemm_layer<<<LB, 256, 0, stream>>>(h1b, wbf + BW2l, hlb, hrb);
    gat_agg_kernel<<<AB, 256, 0, stream>>>(hlb, hrb, h1b, wv + Vatt2, wv + Vb2,
                                           wv + Vg2, wv + Vbe2, offs, srcs, perm, h0b);

    // final: out = h @ Wo + bo (dtype per flags)
    gemm_final<<<GB, 256, 0, stream>>>(h0b, wbf + BWo, wv + Vbo,
                                       (float*)d_out, (u16*)d_out, flags);
}